// Round 11
// baseline (412.557 us; speedup 1.0000x reference)
//
#include <hip/hip_runtime.h>
#include <math.h>

#define TPB 256
#define EPSBN 1e-5f
#define PW 16

typedef __attribute__((ext_vector_type(8))) short bf8v;   // 8 x bf16 (4 VGPR)
typedef __attribute__((ext_vector_type(4))) float f4v;    // MFMA acc

static __device__ __forceinline__ unsigned short f2bf(float f) {
    union { float f; unsigned u; } v; v.f = f;
    unsigned r = v.u + 0x7fffu + ((v.u >> 16) & 1u);
    return (unsigned short)(r >> 16);
}
// HW packed f32->bf16 convert (RNE, same rounding as f2bf); 1 inst replaces ~8.
static __device__ __forceinline__ unsigned cvt_pk_bf16(float lo, float hi) {
    unsigned r;
    asm("v_cvt_pk_bf16_f32 %0, %1, %2" : "=v"(r) : "v"(lo), "v"(hi));
    return r;
}
// broadcast-from-lane via v_readlane (VALU, ~8cy) instead of ds_bpermute (~120cy)
static __device__ __forceinline__ float rdl(float v, int l) {
    return __int_as_float(__builtin_amdgcn_readlane(__float_as_int(v), l));
}

// ---- workspace layout (float element offsets); total 26,865,664 floats (~107.5 MB) ----
#define WS_WAG      0u
#define WS_FWP      9216u
#define WS_SC1      209920u
#define WS_SH1      209952u
#define WS_SCK      209984u
#define WS_SHK      213120u
#define WS_G        216256u
#define WS_C        232897u
#define WS_WNEW     234187u
#define WS_BN1PART  235520u
#define WS_BN2PART  497664u
#define WS_PHI      1021952u
#define WS_FPART    1550336u
#define WS_GPART    5220352u
#define WS_CPART    7399936u
#define WS_PMAX     7598080u
#define WS_PMINH    20443136u
#define WS_TOTAL    26865664ull

// kWk1: fused weight-pack + BN1-stats (independent input-only kernels; saves a launch).
__global__ __launch_bounds__(TPB) void kWk1(const float* __restrict__ w2,
                                            const float* __restrict__ fw,
                                            const float* __restrict__ x,
                                            unsigned* __restrict__ wAg_u,
                                            unsigned* __restrict__ fwp_u,
                                            float* __restrict__ qpart) {
    __shared__ float xs[900];
    __shared__ float red[4][54];
    if (blockIdx.x < 820) {
        int e = blockIdx.x * TPB + threadIdx.x;
        if (e < 9216) {
            int jj = e & 3, lane = (e >> 2) & 63, mt = (e >> 8) & 3, t = e >> 10;
            int j0 = jj * 2;
            int co = mt * 16 + (lane & 15);
            int ci = (lane >> 4) * 8 + j0;
            unsigned h0 = f2bf(w2[(co * 32 + ci) * 9 + t]);
            unsigned h1 = f2bf(w2[(co * 32 + ci + 1) * 9 + t]);
            wAg_u[e] = h0 | (h1 << 16);
        } else if (e < 9216 + 200704) {
            int f = e - 9216;
            int kk = (f & 15) * 2, n = (f >> 4) & 127, g = f >> 11;
            unsigned h0 = f2bf(fw[n * 3136 + g * 32 + kk]);
            unsigned h1 = f2bf(fw[n * 3136 + g * 32 + kk + 1]);
            fwp_u[f] = h0 | (h1 << 16);
        }
        return;
    }
    int bid = blockIdx.x - 820;
    int tid = threadIdx.x;
    float acc[54];
#pragma unroll
    for (int i = 0; i < 54; ++i) acc[i] = 0.f;
    for (int img = 0; img < 16; ++img) {
        int n = bid * 16 + img;
        for (int i = tid; i < 900; i += TPB) xs[i] = 0.f;
        __syncthreads();
        for (int i = tid; i < 784; i += TPB) {
            int r = i / 28, c = i % 28;
            xs[(r + 1) * 30 + (c + 1)] = x[n * 784 + i];
        }
        __syncthreads();
        for (int p = tid; p < 784; p += TPB) {
            int oy = p / 28, ox = p % 28;
            float v[9];
#pragma unroll
            for (int t = 0; t < 9; ++t) v[t] = xs[(oy + t / 3) * 30 + ox + (t % 3)];
            int qi = 9;
#pragma unroll
            for (int t = 0; t < 9; ++t) {
                acc[t] += v[t];
#pragma unroll
                for (int u = t; u < 9; ++u) acc[qi++] += v[t] * v[u];
            }
        }
        __syncthreads();
    }
    int wv = tid >> 6, lane = tid & 63;
#pragma unroll
    for (int i = 0; i < 54; ++i) {
        float s = acc[i];
        for (int d = 1; d < 64; d <<= 1) s += __shfl_xor(s, d);
        if (lane == 0) red[wv][i] = s;
    }
    __syncthreads();
    if (tid < 54)
        qpart[bid * 54 + tid] = red[0][tid] + red[1][tid] + red[2][tid] + red[3][tid];
}

// k2: reduce qpart -> S,Q; per-channel mean/var from 9x9 moments (bias cancels in BN)
__global__ __launch_bounds__(64) void k2_bn1_final(const float* __restrict__ qpart,
                                                   const float* __restrict__ w1,
                                                   const float* __restrict__ g1,
                                                   const float* __restrict__ be1,
                                                   float* __restrict__ sc1,
                                                   float* __restrict__ sh1) {
    __shared__ float T[54];
    int tid = threadIdx.x;
    if (tid < 54) {
        float s = 0.f;
#pragma unroll 8
        for (int b = 0; b < 256; ++b) s += qpart[b * 54 + tid];
        T[tid] = s;
    }
    __syncthreads();
    if (tid < 32) {
        const float inv = 1.f / (4096.f * 784.f);
        float w[9];
#pragma unroll
        for (int t = 0; t < 9; ++t) w[t] = w1[tid * 9 + t];
        float mean = 0.f;
#pragma unroll
        for (int t = 0; t < 9; ++t) mean += w[t] * T[t];
        mean *= inv;
        float ex2 = 0.f;
        int qi = 9;
#pragma unroll
        for (int t = 0; t < 9; ++t)
#pragma unroll
            for (int u = t; u < 9; ++u) {
                float c = w[t] * w[u] * T[qi++];
                ex2 += (u == t) ? c : 2.f * c;
            }
        ex2 *= inv;
        float var = ex2 - mean * mean;
        float a = g1[tid] * rsqrtf(var + EPSBN);
        sc1[tid] = a;
        sh1[tid] = be1[tid] - a * mean;
    }
}

// k34: per image: conv1+BN1+ReLU+pool -> LDS bf16 -> conv2 via MFMA -> stats + pooled max
// r22: REVERT to the round-9 structure (best total 355.2: 32-channel slab, 4
// barriers, 3 blocks/CU) + keep ONLY r21's h1 stride 80->88B padding.
// r21 post-mortem: occupancy 31->42% and conflicts 8.7M->2.06M both landed as
// predicted, yet dur 124->165 — the slab-halving's +4 barriers dominated
// (VALUBusy 48->37): for this kernel BARRIER COUNT beats occupancy. The h1
// padding is the separable good piece (bhi b128 lane-stride 88B: gcd(22,32)=2
// -> 16 banks vs 8). LDS 50.9KB -> still 3 blocks/CU; no barrier change.
__global__ __launch_bounds__(TPB) void k34_conv2_mfma(const float* __restrict__ x,
                                                      const float* __restrict__ w1,
                                                      const float* __restrict__ sc1,
                                                      const float* __restrict__ sh1,
                                                      const unsigned short* __restrict__ wAg,
                                                      const float* __restrict__ b2,
                                                      float* __restrict__ pmax,
                                                      float* __restrict__ bn2part) {
    // LDS layout (ushort units): slab fp32[32][204] @0 (xs aliases), h1 @13056
    // (256 paddr x 88B), wred fp32[512] @24320, b2l fp32[64] @25344.
    __shared__ __align__(16) unsigned short SH[25472];
    float* slab = (float*)SH;
    float* xs   = (float*)SH;                     // alias slab (dead then)
    unsigned* H1u = (unsigned*)(SH + 13056);
    const char* h1hiB = (const char*)(SH + 13056);
    float* wred = (float*)(SH + 24320);
    float* b2l  = (float*)(SH + 25344);

    int tid = threadIdx.x;
    int n   = blockIdx.x;
    int lane = tid & 63, wv = tid >> 6, quad = lane >> 4, l15 = lane & 15;

    for (int i = tid; i < 5632; i += TPB) H1u[i] = 0u;
    for (int i = tid; i < 900; i += TPB) xs[i] = 0.f;
    if (tid < 64) b2l[tid] = b2[tid];
    __syncthreads();
    for (int i = tid; i < 784; i += TPB) {
        int r = i / 28, c = i % 28;
        xs[(r + 1) * 30 + (c + 1)] = x[n * 784 + i];
    }
    __syncthreads();

    if (tid < 196) {
        int py = tid / 14, px = tid % 14;
        int paddr = (py + 1) * 16 + (px + 1);
        float patch[4][4];
#pragma unroll
        for (int r = 0; r < 4; ++r)
#pragma unroll
            for (int c = 0; c < 4; ++c) patch[r][c] = xs[(2 * py + r) * 30 + 2 * px + c];
        unsigned hw0 = 0;
#pragma unroll
        for (int cp = 0; cp < 16; ++cp) {           // channel pair (2cp, 2cp+1)
            float mx0 = -1e30f, mx1 = -1e30f;
#pragma unroll
            for (int sy = 0; sy < 2; ++sy)
#pragma unroll
                for (int sx = 0; sx < 2; ++sx) {
                    float v0 = 0.f, v1 = 0.f;
#pragma unroll
                    for (int t = 0; t < 9; ++t) {
                        float pv = patch[sy + t / 3][sx + t % 3];
                        v0 += pv * w1[(2 * cp) * 9 + t];
                        v1 += pv * w1[(2 * cp + 1) * 9 + t];
                    }
                    mx0 = fmaxf(mx0, v0);
                    mx1 = fmaxf(mx1, v1);
                }
            float r0 = fmaxf(sc1[2 * cp] * mx0 + sh1[2 * cp], 0.f);
            float r1 = fmaxf(sc1[2 * cp + 1] * mx1 + sh1[2 * cp + 1], 0.f);
            unsigned hp = cvt_pk_bf16(r0, r1);      // lo = ch 2cp, hi = ch 2cp+1
            if ((cp & 1) == 0) hw0 = hp;
            else *(uint2*)(H1u + paddr * 22 + (cp - 1)) = make_uint2(hw0, hp);
        }
    }
    __syncthreads();

    int baseB[4];
    float vmsk[4];
    int pvals[4];
#pragma unroll
    for (int i = 0; i < 4; ++i) {
        int nt = wv + 4 * i;
        int p  = nt * 16 + l15;
        vmsk[i]  = (nt <= 12 && p < 196) ? 1.f : 0.f;
        pvals[i] = p;
        int pc = p < 196 ? p : 195;
        int py = pc / 14, px = pc - py * 14;
        baseB[i] = ((py + 1) * 16 + (px + 1)) * 88 + quad * 16;
    }

    // pool decomposition: 32 channels, 8 threads/channel, 7 iters (r9 config)
    int pk = tid >> 3, pj = tid & 7;

#pragma unroll
    for (int c2 = 0; c2 < 2; ++c2) {
        // --- MFMA for channel half c2 (mt = c2*2 + mtl), acc = 32 regs ---
        f4v acc2[4][2];
#pragma unroll
        for (int i = 0; i < 4; ++i)
#pragma unroll
            for (int mtl = 0; mtl < 2; ++mtl) acc2[i][mtl] = (f4v){0.f, 0.f, 0.f, 0.f};
#pragma unroll
        for (int t = 0; t < 9; ++t) {
            const int toff = ((t / 3) - 1) * 1408 + ((t % 3) - 1) * 88;
            bf8v wa0 = *(const bf8v*)(wAg + ((t * 4 + c2 * 2 + 0) * 64 + lane) * 8);
            bf8v wa1 = *(const bf8v*)(wAg + ((t * 4 + c2 * 2 + 1) * 64 + lane) * 8);
#pragma unroll
            for (int i = 0; i < 4; ++i) {
                if (wv + 4 * i > 12) continue;
                bf8v bhi = *(const bf8v*)(h1hiB + baseB[i] + toff);
                acc2[i][0] = __builtin_amdgcn_mfma_f32_16x16x32_bf16(wa0, bhi, acc2[i][0], 0, 0, 0);
                acc2[i][1] = __builtin_amdgcn_mfma_f32_16x16x32_bf16(wa1, bhi, acc2[i][1], 0, 0, 0);
            }
        }
        // --- bias ---
#pragma unroll
        for (int mtl = 0; mtl < 2; ++mtl) {
            float bb[4];
#pragma unroll
            for (int r = 0; r < 4; ++r) bb[r] = b2l[(c2 * 2 + mtl) * 16 + quad * 4 + r];
#pragma unroll
            for (int i = 0; i < 4; ++i)
#pragma unroll
                for (int r = 0; r < 4; ++r) acc2[i][mtl][r] += bb[r];
        }
        // --- stats for this half ---
        float ss[2][4], qq[2][4];
#pragma unroll
        for (int mtl = 0; mtl < 2; ++mtl)
#pragma unroll
            for (int r = 0; r < 4; ++r) { ss[mtl][r] = 0.f; qq[mtl][r] = 0.f; }
#pragma unroll
        for (int i = 0; i < 4; ++i) {
            if (wv + 4 * i > 12) continue;
#pragma unroll
            for (int mtl = 0; mtl < 2; ++mtl)
#pragma unroll
                for (int r = 0; r < 4; ++r) {
                    float v = acc2[i][mtl][r] * vmsk[i];
                    ss[mtl][r] += v;
                    qq[mtl][r] += v * v;
                }
        }
#pragma unroll
        for (int d = 1; d < 16; d <<= 1)
#pragma unroll
            for (int mtl = 0; mtl < 2; ++mtl)
#pragma unroll
                for (int r = 0; r < 4; ++r) {
                    ss[mtl][r] += __shfl_xor(ss[mtl][r], d);
                    qq[mtl][r] += __shfl_xor(qq[mtl][r], d);
                }
        if (l15 == 0) {
#pragma unroll
            for (int mtl = 0; mtl < 2; ++mtl)
#pragma unroll
                for (int r = 0; r < 4; ++r) {
                    int co = (c2 * 2 + mtl) * 16 + quad * 4 + r;
                    wred[wv * 64 + co]       = ss[mtl][r];
                    wred[256 + wv * 64 + co] = qq[mtl][r];
                }
        }
        // --- slab write (both mtl; 32 channels; h1 stays intact across halves) ---
#pragma unroll
        for (int mtl = 0; mtl < 2; ++mtl) {
#pragma unroll
            for (int i = 0; i < 4; ++i) {
                if (wv + 4 * i > 12) continue;
                if (vmsk[i] > 0.f) {
#pragma unroll
                    for (int r = 0; r < 4; ++r)
                        slab[(mtl * 16 + quad * 4 + r) * 204 + pvals[i]] = acc2[i][mtl][r];
                }
            }
        }
        __syncthreads();
        // --- pool for this half (division-free decomposition) ---
        {
            int j7 = (pj >= 7) ? 1 : 0;
            int qy = j7, qx = pj - 7 * j7;
            size_t obase = (size_t)n * 3136 + (c2 * 32 + pk) * 49;
            const float* srow = slab + pk * 204;
#pragma unroll
            for (int it = 0; it < 7; ++it) {
                int pp = pj + (it << 3);
                if (pp < 49) {
                    int p0 = qy * 28 + qx * 2;
                    float2 a01 = *(const float2*)(srow + p0);
                    float2 a23 = *(const float2*)(srow + p0 + 14);
                    float mx = fmaxf(fmaxf(a01.x, a01.y), fmaxf(a23.x, a23.y));
                    pmax[obase + pp] = mx;
                }
                qx += 1; qy += 1;
                if (qx >= 7) { qx -= 7; qy += 1; }
            }
        }
        __syncthreads();   // slab reuse + wred visibility for the final read
    }
    // --- bn2part from wred (all 64 co written across both halves) ---
    if (tid < 64) {
        float s = wred[tid] + wred[64 + tid] + wred[128 + tid] + wred[192 + tid];
        float q = wred[256 + tid] + wred[320 + tid] + wred[384 + tid] + wred[448 + tid];
        bn2part[(n * 64 + tid) * 2 + 0] = s;
        bn2part[(n * 64 + tid) * 2 + 1] = q;
    }
}

// k5: finalize bn2 -> expanded per-fc1-k scale/shift arrays (3136 each)
__global__ __launch_bounds__(TPB) void k5_bn2_final(const float* __restrict__ bn2part,
                                                    const float* __restrict__ g2,
                                                    const float* __restrict__ be2,
                                                    float* __restrict__ sck,
                                                    float* __restrict__ shk) {
    __shared__ float red[TPB][2];
    __shared__ float sAC[2];
    int tid = threadIdx.x, co = blockIdx.x;
    float s = 0.f, q = 0.f;
    for (int i = tid; i < 4096; i += TPB) {
        s += bn2part[(i * 64 + co) * 2 + 0];
        q += bn2part[(i * 64 + co) * 2 + 1];
    }
    red[tid][0] = s; red[tid][1] = q;
    __syncthreads();
    for (int off = TPB / 2; off; off >>= 1) {
        if (tid < off) { red[tid][0] += red[tid + off][0]; red[tid][1] += red[tid + off][1]; }
        __syncthreads();
    }
    if (tid == 0) {
        const float count = 4096.f * 196.f;
        float mean = red[0][0] / count;
        float var  = red[0][1] / count - mean * mean;
        float a    = g2[co] * rsqrtf(var + EPSBN);
        sAC[0] = a;
        sAC[1] = be2[co] - a * mean;
    }
    __syncthreads();
    if (tid < 49) {
        sck[co * 49 + tid] = sAC[0];
        shk[co * 49 + tid] = sAC[1];
    }
}

// k7: fc1 via MFMA, single-bf16 activations. BN2+ReLU fused into A-staging.
__global__ __launch_bounds__(TPB) void k7_fc1_mfma(const float* __restrict__ pmax,
                                                   const float* __restrict__ sck,
                                                   const float* __restrict__ shk,
                                                   const unsigned short* __restrict__ fwp,
                                                   float* __restrict__ fpart) {
    __shared__ __align__(16) unsigned short K7S[7680];   // Ahi[64*40] Bsl[128*40]
    unsigned short* Ahi = K7S;
    unsigned short* Bsl = K7S + 2560;
    int tid = threadIdx.x;
    int mt = blockIdx.x & 63, ks = blockIdx.x >> 6;
    int m0 = mt * 64;
    int lane = tid & 63, wv = tid >> 6, quad = lane >> 4, l15 = lane & 15;
    f4v acc[8];
#pragma unroll
    for (int i = 0; i < 8; ++i) acc[i] = (f4v){0.f, 0.f, 0.f, 0.f};

    for (int it = 0; it < 14; ++it) {
        int g  = ks * 14 + it;
        int k0 = g * 32;
#pragma unroll
        for (int i = 0; i < 8; ++i) {
            int e  = tid + i * TPB;
            int r  = e >> 5, kk = e & 31;
            int k  = k0 + kk;
            float a = sck[k], c = shk[k];
            size_t src = (size_t)(m0 + r) * 3136 + k;
            float v = fmaxf(a * pmax[src] + c, 0.f);
            Ahi[r * 40 + kk] = f2bf(v);
        }
        {
            const uint4* src = (const uint4*)(fwp + (size_t)g * 4096 + tid * 16);
            uint4 w0 = src[0], w1 = src[1];
            int n = tid >> 1, kk0 = (tid & 1) * 16;
            *(uint4*)(Bsl + n * 40 + kk0)     = w0;
            *(uint4*)(Bsl + n * 40 + kk0 + 8) = w1;
        }
        __syncthreads();
        bf8v ahi = *(const bf8v*)(Ahi + (wv * 16 + l15) * 40 + quad * 8);
#pragma unroll
        for (int nt = 0; nt < 8; ++nt) {
            bf8v b = *(const bf8v*)(Bsl + (nt * 16 + l15) * 40 + quad * 8);
            acc[nt] = __builtin_amdgcn_mfma_f32_16x16x32_bf16(ahi, b, acc[nt], 0, 0, 0);
        }
        __syncthreads();
    }
#pragma unroll
    for (int nt = 0; nt < 8; ++nt)
#pragma unroll
        for (int r = 0; r < 4; ++r) {
            int m = m0 + wv * 16 + quad * 4 + r;
            int nn = nt * 16 + l15;
            fpart[(size_t)ks * 524288 + m * 128 + nn] = acc[nt][r];
        }
}

// k7b: reduce 7 K-split partials + bias + ReLU -> Phi [4096][129]
__global__ __launch_bounds__(TPB) void k7b_relu(const float* __restrict__ fpart,
                                                const float* __restrict__ fb,
                                                float* __restrict__ Phi) {
    int e = blockIdx.x * TPB + threadIdx.x;
    int n = e >> 7, f = e & 127;
    float s = fb[f];
#pragma unroll
    for (int c = 0; c < 7; ++c) s += fpart[(size_t)c * 524288 + e];
    Phi[n * 129 + f] = fmaxf(s, 0.f);
    if (f == 0) Phi[n * 129 + 128] = 1.0f;
}

// k8: partial Gram + C, 32-sample chunks
__global__ __launch_bounds__(TPB) void k8_gram(const float* __restrict__ Phi,
                                               const float* __restrict__ y,
                                               float* __restrict__ Gpart,
                                               float* __restrict__ Cpart) {
    __shared__ __align__(16) float ph[32 * 132];
    __shared__ __align__(16) float yl[32 * 12];
    int tid = threadIdx.x;
    int cB  = blockIdx.x;
    int n0  = cB * 32;
    for (int i = tid; i < 32 * 132; i += TPB) ph[i] = 0.f;
    for (int i = tid; i < 32 * 12; i += TPB) yl[i] = 0.f;
    __syncthreads();
    for (int i = tid; i < 32 * 129; i += TPB) {
        int r = i / 129, d = i % 129;
        ph[r * 132 + d] = Phi[(n0 + r) * 129 + d];
    }
    for (int i = tid; i < 320; i += TPB) {
        int r = i / 10, j = i % 10;
        yl[r * 12 + j] = y[(n0 + r) * 10 + j];
    }
    __syncthreads();
    for (int g = tid; g < 129 * 33; g += TPB) {
        int i = g / 33, j0 = (g % 33) * 4;
        float4 s = make_float4(0.f, 0.f, 0.f, 0.f);
        for (int r = 0; r < 32; ++r) {
            float  vi = ph[r * 132 + i];
            float4 vj = *(const float4*)&ph[r * 132 + j0];
            s.x += vi * vj.x; s.y += vi * vj.y; s.z += vi * vj.z; s.w += vi * vj.w;
        }
        *(float4*)&Gpart[(size_t)cB * 17028 + i * 132 + j0] = s;
    }
    for (int g = tid; g < 129 * 3; g += TPB) {
        int i = g / 3, j0 = (g % 3) * 4;
        float4 s = make_float4(0.f, 0.f, 0.f, 0.f);
        for (int r = 0; r < 32; ++r) {
            float  vi = ph[r * 132 + i];
            float4 vj = *(const float4*)&yl[r * 12 + j0];
            s.x += vi * vj.x; s.y += vi * vj.y; s.z += vi * vj.z; s.w += vi * vj.w;
        }
        *(float4*)&Cpart[(size_t)cB * 1548 + i * 12 + j0] = s;
    }
}

// k9: reduce partials -> G [129*129], C [129*10]
__global__ __launch_bounds__(TPB) void k9_reduce(const float* __restrict__ Gpart,
                                                 const float* __restrict__ Cpart,
                                                 float* __restrict__ G,
                                                 float* __restrict__ C) {
    int e = blockIdx.x * TPB + threadIdx.x;
    if (e < 16641) {
        int i = e / 129, j = e % 129;
        float s = 0.f;
        for (int c = 0; c < 128; ++c) s += Gpart[(size_t)c * 17028 + i * 132 + j];
        G[e] = s;
    } else if (e < 16641 + 1290) {
        int e2 = e - 16641;
        int i = e2 / 10, j = e2 % 10;
        float s = 0.f;
        for (int c = 0; c < 128; ++c) s += Cpart[(size_t)c * 1548 + i * 12 + j];
        C[e2] = s;
    }
}

// k10: solve (I+G) W = W0 + C. Gauss-Jordan with fully-diagonalized panels (r16).
// Confirmed win: 145 -> ~60 (inferred from total delta). Do not touch.
__global__ __launch_bounds__(TPB) void k10_solve(const float* __restrict__ G,
                                                 const float* __restrict__ C,
                                                 const float* __restrict__ W0,
                                                 float* __restrict__ Wnew) {
    __shared__ __align__(16) float M[129 * 140];
    __shared__ __align__(16) float LpT[PW * 116];   // [k][compact row], 113 used
    __shared__ float L11s[PW * 16];                 // L11s[m*16+k] = L11[k][m], m<k
    __shared__ float invD[129];
    __shared__ float x128s[10];
    int tid = threadIdx.x;
    int lane = tid & 63, wv = tid >> 6;
    for (int e = tid; e < 129 * 129; e += TPB) {
        int i = e / 129, j = e % 129;
        M[i * 140 + j] = G[e] + (i == j ? 1.f : 0.f);
    }
    for (int i = tid; i < 129; i += TPB) M[i * 140 + 129] = 0.f;
    for (int e = tid; e < 1290; e += TPB) {
        int i = e / 10, c = e % 10;
        M[i * 140 + 130 + c] = W0[e] + C[e];
    }
    __syncthreads();

    for (int k0 = 0; k0 < 128; k0 += PW) {
        const int kend = k0 + PW;
        // --- A: 16x16 LU in registers (wave 0, lanes 0..15), readlane broadcasts ---
        if (wv == 0) {
            bool act = lane < PW;
            int r  = k0 + lane;
            int rc = act ? r : k0;
            float u[PW], Lr[PW];
#pragma unroll
            for (int j = 0; j < PW; ++j) u[j] = M[rc * 140 + k0 + j];
            float dval = u[0];
#pragma unroll
            for (int k = 0; k < PW; ++k) {
                if (lane == k) dval = u[k];
                float piv = rdl(u[k], k);
                float f   = u[k] * __builtin_amdgcn_rcpf(piv);
                float fm  = (act && lane > k) ? f : 0.f;
                Lr[k] = fm;
#pragma unroll
                for (int j = 0; j < PW; ++j)
                    if (j > k) u[j] -= fm * rdl(u[j], k);
            }
            if (act) {
#pragma unroll
                for (int j = 0; j < PW; ++j)
                    if (j >= lane) M[r * 140 + k0 + j] = u[j];   // U11 incl diag
#pragma unroll
                for (int k = 0; k < PW; ++k)
                    if (k < lane) L11s[k * 16 + lane] = Lr[k];   // L11[lane][k]
                invD[r] = __builtin_amdgcn_rcpf(dval);
            }
        }
        __syncthreads();
        if (tid < 128) {
            // --- B (waves 0-1): chain-free coefficients vs diagonalized panel ---
            int cidx = tid;                      // compact off-panel row index
            if (cidx < 113) {
                int r = cidx < k0 ? cidx : cidx + PW;
                float4 a4[4];
#pragma unroll
                for (int q = 0; q < 4; ++q) a4[q] = *(const float4*)&M[r * 140 + k0 + q * 4];
                float a[PW];
#pragma unroll
                for (int q = 0; q < 4; ++q) {
                    a[q * 4 + 0] = a4[q].x; a[q * 4 + 1] = a4[q].y;
                    a[q * 4 + 2] = a4[q].z; a[q * 4 + 3] = a4[q].w;
                }
#pragma unroll
                for (int k = 0; k < PW; ++k)
                    LpT[k * 116 + cidx] = a[k] * invD[k0 + k];
            }
        } else {
            // --- C (waves 2-3): within-panel Jordan on trailing cols (incl RHS) ---
            int j = kend + (tid - 128);
            if (j < 140) {
                float yv[PW];
#pragma unroll
                for (int kk = 0; kk < PW; ++kk) {
                    float v = M[(k0 + kk) * 140 + j];
#pragma unroll
                    for (int m = 0; m < PW; ++m)
                        if (m < kk) v -= L11s[m * 16 + kk] * yv[m];
                    yv[kk] = v;
                }
                float xv[PW];
#pragma unroll
                for (int kk = PW - 1; kk >= 0; --kk) {
                    float v = yv[kk];
#pragma unroll
                    for (int m = 0; m < PW; ++m)
                        if (m > kk) v -= M[(k0 + kk) * 140 + k0 + m] * xv[m];
                    M[(k0 + kk) * 140 + j] = v;       // T = D * A11^{-1} * col
                    xv[kk] = v * invD[k0 + kk];
                }
            }
        }
        __syncthreads();
        // --- D: rank-16 update of ALL 113 off-panel rows, trailing cols ---
        const int Jn = 140 - kend;
        const int nrt = 29, nct = Jn >> 2;       // 113 rows -> 29 4-row tiles
        for (int t = tid; t < nrt * nct; t += TPB) {
            int tr = t % nrt, tc = t / nrt;
            int c0 = tr * 4;
            int j0 = kend + tc * 4;
            float4 s0 = {0, 0, 0, 0}, s1 = {0, 0, 0, 0}, s2 = {0, 0, 0, 0}, s3 = {0, 0, 0, 0};
#pragma unroll
            for (int kk = 0; kk < PW; ++kk) {
                float4 L4 = *(const float4*)&LpT[kk * 116 + c0];
                float4 U4 = *(const float4*)&M[(k0 + kk) * 140 + j0];
                s0.x += L4.x * U4.x; s0.y += L4.x * U4.y; s0.z += L4.x * U4.z; s0.w += L4.x * U4.w;
                s1.x += L4.y * U4.x; s1.y += L4.y * U4.y; s1.z += L4.y * U4.z; s1.w += L4.y * U4.w;
                s2.x += L4.z * U4.x; s2.y += L4.z * U4.y; s2.z += L4.z * U4.z; s2.w += L4.z * U4.w;
                s3.x += L4.w * U4.x; s3.y += L4.w * U4.y; s3.z += L4.w * U4.z; s3.w += L4.w * U4.w;
            }
            float4 sv[4] = {s0, s1, s2, s3};
#pragma unroll
            for (int i = 0; i < 4; ++i) {
                int cidx = c0 + i;
                if (cidx < 113) {
                    int r = cidx < k0 ? cidx : cidx + PW;
                    float4 mv = *(const float4*)&M[r * 140 + j0];
                    mv.x -= sv[i].x; mv.y -= sv[i].y; mv.z -= sv[i].z; mv.w -= sv[i].w;
                    *(float4*)&M[r * 140 + j0] = mv;
                }
            }
        }
        __syncthreads();
    }
    // --- extraction: rows are diagonal + col128 + RHS; no back-substitution ---
    if (tid == 0) {
        float i128 = __builtin_amdgcn_rcpf(M[128 * 140 + 128]);
#pragma unroll
        for (int c = 0; c < 10; ++c) x128s[c] = M[128 * 140 + 130 + c] * i128;
    }
    __syncthreads();
    if (tid < 128) {
        int r = tid;
        float m128 = M[r * 140 + 128];
        float idr  = invD[r];
#pragma unroll
        for (int c = 0; c < 10; ++c)
            Wnew[r * 10 + c] = (M[r * 140 + 130 + c] - m128 * x128s[c]) * idr;
    } else if (tid == 128) {
#pragma unroll
        for (int c = 0; c < 10; ++c) Wnew[1280 + c] = x128s[c];
    }
}

// k11: out = Phi @ Wnew  ([4096][10])
__global__ __launch_bounds__(TPB) void k11_out(const float* __restrict__ Phi,
                                               const float* __restrict__ Wnew,
                                               float* __restrict__ out) {
    __shared__ float Wl[1290];
    int tid = threadIdx.x;
    for (int i = tid; i < 1290; i += TPB) Wl[i] = Wnew[i];
    __syncthreads();
    int idx = blockIdx.x * TPB + tid;
    int n = idx / 10, j = idx % 10;
    float s = 0.f;
    for (int d = 0; d < 129; ++d) s += Phi[n * 129 + d] * Wl[d * 10 + j];
    out[idx] = s;
}

extern "C" void kernel_launch(void* const* d_in, const int* in_sizes, int n_in,
                              void* d_out, int out_size, void* d_ws, size_t ws_size,
                              hipStream_t stream) {
    const float* x   = (const float*)d_in[0];
    const float* y   = (const float*)d_in[1];
    const float* w1  = (const float*)d_in[2];
    const float* g1  = (const float*)d_in[4];
    const float* be1 = (const float*)d_in[5];
    const float* w2  = (const float*)d_in[6];
    const float* b2  = (const float*)d_in[7];
    const float* g2  = (const float*)d_in[8];
    const float* be2 = (const float*)d_in[9];
    const float* fw  = (const float*)d_in[10];
    const float* fb  = (const float*)d_in[11];
    const float* W0  = (const float*)d_in[12];
    float* out = (float*)d_out;
    float* ws  = (float*)d_ws;
    if (ws_size < WS_TOTAL * 4ull) return;

    unsigned* wAg_u = (unsigned*)(ws + WS_WAG);
    unsigned* fwp_u = (unsigned*)(ws + WS_FWP);
    const unsigned short* wAg_h = (const unsigned short*)wAg_u;
    const unsigned short* fwp_h = (const unsigned short*)fwp_u;
    float* sc1     = ws + WS_SC1;
    float* sh1     = ws + WS_SH1;
    float* sck     = ws + WS_SCK;
    float* shk     = ws + WS_SHK;
    float* G       = ws + WS_G;
    float* C       = ws + WS_C;
    float* Wnew    = ws + WS_WNEW;
    float* qpart   = ws + WS_BN1PART;
    float* bn2part = ws + WS_BN2PART;
    float* Phi     = ws + WS_PHI;
    float* fpart   = ws + WS_FPART;
    float* Gpart   = ws + WS_GPART;
    float* Cpart   = ws + WS_CPART;
    float* pmax    = ws + WS_PMAX;

    kWk1<<<1076, TPB, 0, stream>>>(w2, fw, x, wAg_u, fwp_u, qpart);
    k2_bn1_final<<<1, 64, 0, stream>>>(qpart, w1, g1, be1, sc1, sh1);
    k34_conv2_mfma<<<4096, TPB, 0, stream>>>(x, w1, sc1, sh1, wAg_h, b2, pmax, bn2part);
    k5_bn2_final<<<64, TPB, 0, stream>>>(bn2part, g2, be2, sck, shk);
    k7_fc1_mfma<<<448, TPB, 0, stream>>>(pmax, sck, shk, fwp_h, fpart);
    k7b_relu<<<2048, TPB, 0, stream>>>(fpart, fb, Phi);
    k8_gram<<<128, TPB, 0, stream>>>(Phi, y, Gpart, Cpart);
    k9_reduce<<<71, TPB, 0, stream>>>(Gpart, Cpart, G, C);
    k10_solve<<<1, TPB, 0, stream>>>(G, C, W0, Wnew);
    k11_out<<<160, TPB, 0, stream>>>(Phi, Wnew, out);
}

// Round 12
// 354.408 us; speedup vs baseline: 1.1641x; 1.1641x over previous
//
#include <hip/hip_runtime.h>
#include <math.h>

#define TPB 256
#define EPSBN 1e-5f
#define PW 16

typedef __attribute__((ext_vector_type(8))) short bf8v;   // 8 x bf16 (4 VGPR)
typedef __attribute__((ext_vector_type(4))) float f4v;    // MFMA acc

static __device__ __forceinline__ unsigned short f2bf(float f) {
    union { float f; unsigned u; } v; v.f = f;
    unsigned r = v.u + 0x7fffu + ((v.u >> 16) & 1u);
    return (unsigned short)(r >> 16);
}
// HW packed f32->bf16 convert (RNE, same rounding as f2bf); 1 inst replaces ~8.
static __device__ __forceinline__ unsigned cvt_pk_bf16(float lo, float hi) {
    unsigned r;
    asm("v_cvt_pk_bf16_f32 %0, %1, %2" : "=v"(r) : "v"(lo), "v"(hi));
    return r;
}
// broadcast-from-lane via v_readlane (VALU, ~8cy) instead of ds_bpermute (~120cy)
static __device__ __forceinline__ float rdl(float v, int l) {
    return __int_as_float(__builtin_amdgcn_readlane(__float_as_int(v), l));
}

// ---- workspace layout (float element offsets); total 26,865,664 floats (~107.5 MB) ----
#define WS_WAG      0u
#define WS_FWP      9216u
#define WS_SC1      209920u
#define WS_SH1      209952u
#define WS_SCK      209984u
#define WS_SHK      213120u
#define WS_G        216256u
#define WS_C        232897u
#define WS_WNEW     234187u
#define WS_BN1PART  235520u
#define WS_BN2PART  497664u
#define WS_PHI      1021952u
#define WS_FPART    1550336u
#define WS_GPART    5220352u
#define WS_CPART    7399936u
#define WS_PMAX     7598080u
#define WS_PMINH    20443136u
#define WS_TOTAL    26865664ull

// kWk1: fused weight-pack + BN1-stats (independent input-only kernels; saves a launch).
__global__ __launch_bounds__(TPB) void kWk1(const float* __restrict__ w2,
                                            const float* __restrict__ fw,
                                            const float* __restrict__ x,
                                            unsigned* __restrict__ wAg_u,
                                            unsigned* __restrict__ fwp_u,
                                            float* __restrict__ qpart) {
    __shared__ float xs[900];
    __shared__ float red[4][54];
    if (blockIdx.x < 820) {
        int e = blockIdx.x * TPB + threadIdx.x;
        if (e < 9216) {
            int jj = e & 3, lane = (e >> 2) & 63, mt = (e >> 8) & 3, t = e >> 10;
            int j0 = jj * 2;
            int co = mt * 16 + (lane & 15);
            int ci = (lane >> 4) * 8 + j0;
            unsigned h0 = f2bf(w2[(co * 32 + ci) * 9 + t]);
            unsigned h1 = f2bf(w2[(co * 32 + ci + 1) * 9 + t]);
            wAg_u[e] = h0 | (h1 << 16);
        } else if (e < 9216 + 200704) {
            int f = e - 9216;
            int kk = (f & 15) * 2, n = (f >> 4) & 127, g = f >> 11;
            unsigned h0 = f2bf(fw[n * 3136 + g * 32 + kk]);
            unsigned h1 = f2bf(fw[n * 3136 + g * 32 + kk + 1]);
            fwp_u[f] = h0 | (h1 << 16);
        }
        return;
    }
    int bid = blockIdx.x - 820;
    int tid = threadIdx.x;
    float acc[54];
#pragma unroll
    for (int i = 0; i < 54; ++i) acc[i] = 0.f;
    for (int img = 0; img < 16; ++img) {
        int n = bid * 16 + img;
        for (int i = tid; i < 900; i += TPB) xs[i] = 0.f;
        __syncthreads();
        for (int i = tid; i < 784; i += TPB) {
            int r = i / 28, c = i % 28;
            xs[(r + 1) * 30 + (c + 1)] = x[n * 784 + i];
        }
        __syncthreads();
        for (int p = tid; p < 784; p += TPB) {
            int oy = p / 28, ox = p % 28;
            float v[9];
#pragma unroll
            for (int t = 0; t < 9; ++t) v[t] = xs[(oy + t / 3) * 30 + ox + (t % 3)];
            int qi = 9;
#pragma unroll
            for (int t = 0; t < 9; ++t) {
                acc[t] += v[t];
#pragma unroll
                for (int u = t; u < 9; ++u) acc[qi++] += v[t] * v[u];
            }
        }
        __syncthreads();
    }
    int wv = tid >> 6, lane = tid & 63;
#pragma unroll
    for (int i = 0; i < 54; ++i) {
        float s = acc[i];
        for (int d = 1; d < 64; d <<= 1) s += __shfl_xor(s, d);
        if (lane == 0) red[wv][i] = s;
    }
    __syncthreads();
    if (tid < 54)
        qpart[bid * 54 + tid] = red[0][tid] + red[1][tid] + red[2][tid] + red[3][tid];
}

// k2: reduce qpart -> S,Q; per-channel mean/var from 9x9 moments (bias cancels in BN)
__global__ __launch_bounds__(64) void k2_bn1_final(const float* __restrict__ qpart,
                                                   const float* __restrict__ w1,
                                                   const float* __restrict__ g1,
                                                   const float* __restrict__ be1,
                                                   float* __restrict__ sc1,
                                                   float* __restrict__ sh1) {
    __shared__ float T[54];
    int tid = threadIdx.x;
    if (tid < 54) {
        float s = 0.f;
#pragma unroll 8
        for (int b = 0; b < 256; ++b) s += qpart[b * 54 + tid];
        T[tid] = s;
    }
    __syncthreads();
    if (tid < 32) {
        const float inv = 1.f / (4096.f * 784.f);
        float w[9];
#pragma unroll
        for (int t = 0; t < 9; ++t) w[t] = w1[tid * 9 + t];
        float mean = 0.f;
#pragma unroll
        for (int t = 0; t < 9; ++t) mean += w[t] * T[t];
        mean *= inv;
        float ex2 = 0.f;
        int qi = 9;
#pragma unroll
        for (int t = 0; t < 9; ++t)
#pragma unroll
            for (int u = t; u < 9; ++u) {
                float c = w[t] * w[u] * T[qi++];
                ex2 += (u == t) ? c : 2.f * c;
            }
        ex2 *= inv;
        float var = ex2 - mean * mean;
        float a = g1[tid] * rsqrtf(var + EPSBN);
        sc1[tid] = a;
        sh1[tid] = be1[tid] - a * mean;
    }
}

// k34: per image: conv1+BN1+ReLU+pool -> LDS bf16 -> conv2 via MFMA -> stats + pooled max
// r23: EXACT REVERT to the round-9 config (best measured total 355.2 µs).
// k34 lever ledger, all counter-verified:
//  - c2-split (r19): WIN (AGPR residency 2->3 blocks/CU, 132->118).
//  - conv1 float2 + cvt_pk (r20): ~neutral; kept (harmless, fewer insts).
//  - launch_bounds(256,5) (r18): spills acc -> 352MB scratch traffic. Never force.
//  - slab-halving +4 barriers (r21): occupancy 31->42% but dur 124->165 —
//    BARRIER COUNT dominates occupancy for this kernel.
//  - h1 stride 80->88B (r21/r22): conflicts 8.7M->2.06M but dur +35% —
//    88 % 16 != 0 broke ds_read_b128 16B alignment (80=16*5 is aligned; among
//    16-aligned strides bank coverage is gcd-capped at 8, so 80 is optimal).
// Remaining profile: VALU 48%, MFMA 10%, HBM 6%, occupancy 31% — latency-bound;
// no counter-backed lever left at this structure.
__global__ __launch_bounds__(TPB) void k34_conv2_mfma(const float* __restrict__ x,
                                                      const float* __restrict__ w1,
                                                      const float* __restrict__ sc1,
                                                      const float* __restrict__ sh1,
                                                      const unsigned short* __restrict__ wAg,
                                                      const float* __restrict__ b2,
                                                      float* __restrict__ pmax,
                                                      float* __restrict__ bn2part) {
    // LDS layout (ushort units): slab fp32[32][204] @0 (xs aliases), h1 @13056
    // (256 paddr x 80B), wred fp32[512] @23296, b2l fp32[64] @24320.
    __shared__ __align__(16) unsigned short SH[24448];
    float* slab = (float*)SH;
    float* xs   = (float*)SH;                     // alias slab (dead then)
    unsigned* H1u = (unsigned*)(SH + 13056);
    const char* h1hiB = (const char*)(SH + 13056);
    float* wred = (float*)(SH + 23296);
    float* b2l  = (float*)(SH + 24320);

    int tid = threadIdx.x;
    int n   = blockIdx.x;
    int lane = tid & 63, wv = tid >> 6, quad = lane >> 4, l15 = lane & 15;

    for (int i = tid; i < 5120; i += TPB) H1u[i] = 0u;
    for (int i = tid; i < 900; i += TPB) xs[i] = 0.f;
    if (tid < 64) b2l[tid] = b2[tid];
    __syncthreads();
    for (int i = tid; i < 784; i += TPB) {
        int r = i / 28, c = i % 28;
        xs[(r + 1) * 30 + (c + 1)] = x[n * 784 + i];
    }
    __syncthreads();

    if (tid < 196) {
        int py = tid / 14, px = tid % 14;
        int paddr = (py + 1) * 16 + (px + 1);
        float patch[4][4];
#pragma unroll
        for (int r = 0; r < 4; ++r)
#pragma unroll
            for (int c = 0; c < 4; ++c) patch[r][c] = xs[(2 * py + r) * 30 + 2 * px + c];
        unsigned hw0 = 0;
#pragma unroll
        for (int cp = 0; cp < 16; ++cp) {           // channel pair (2cp, 2cp+1)
            float mx0 = -1e30f, mx1 = -1e30f;
#pragma unroll
            for (int sy = 0; sy < 2; ++sy)
#pragma unroll
                for (int sx = 0; sx < 2; ++sx) {
                    float v0 = 0.f, v1 = 0.f;
#pragma unroll
                    for (int t = 0; t < 9; ++t) {
                        float pv = patch[sy + t / 3][sx + t % 3];
                        v0 += pv * w1[(2 * cp) * 9 + t];
                        v1 += pv * w1[(2 * cp + 1) * 9 + t];
                    }
                    mx0 = fmaxf(mx0, v0);
                    mx1 = fmaxf(mx1, v1);
                }
            float r0 = fmaxf(sc1[2 * cp] * mx0 + sh1[2 * cp], 0.f);
            float r1 = fmaxf(sc1[2 * cp + 1] * mx1 + sh1[2 * cp + 1], 0.f);
            unsigned hp = cvt_pk_bf16(r0, r1);      // lo = ch 2cp, hi = ch 2cp+1
            if ((cp & 1) == 0) hw0 = hp;
            else *(uint2*)(H1u + paddr * 20 + (cp - 1)) = make_uint2(hw0, hp);
        }
    }
    __syncthreads();

    int baseB[4];
    float vmsk[4];
    int pvals[4];
#pragma unroll
    for (int i = 0; i < 4; ++i) {
        int nt = wv + 4 * i;
        int p  = nt * 16 + l15;
        vmsk[i]  = (nt <= 12 && p < 196) ? 1.f : 0.f;
        pvals[i] = p;
        int pc = p < 196 ? p : 195;
        int py = pc / 14, px = pc - py * 14;
        baseB[i] = ((py + 1) * 16 + (px + 1)) * 80 + quad * 16;
    }

    int pk = tid >> 3, pj = tid & 7;   // pool decomposition

#pragma unroll
    for (int c2 = 0; c2 < 2; ++c2) {
        // --- MFMA for channel half c2 (mt = c2*2 + mtl), acc = 32 regs ---
        f4v acc2[4][2];
#pragma unroll
        for (int i = 0; i < 4; ++i)
#pragma unroll
            for (int mtl = 0; mtl < 2; ++mtl) acc2[i][mtl] = (f4v){0.f, 0.f, 0.f, 0.f};
#pragma unroll
        for (int t = 0; t < 9; ++t) {
            const int toff = ((t / 3) - 1) * 1280 + ((t % 3) - 1) * 80;
            bf8v wa0 = *(const bf8v*)(wAg + ((t * 4 + c2 * 2 + 0) * 64 + lane) * 8);
            bf8v wa1 = *(const bf8v*)(wAg + ((t * 4 + c2 * 2 + 1) * 64 + lane) * 8);
#pragma unroll
            for (int i = 0; i < 4; ++i) {
                if (wv + 4 * i > 12) continue;
                bf8v bhi = *(const bf8v*)(h1hiB + baseB[i] + toff);
                acc2[i][0] = __builtin_amdgcn_mfma_f32_16x16x32_bf16(wa0, bhi, acc2[i][0], 0, 0, 0);
                acc2[i][1] = __builtin_amdgcn_mfma_f32_16x16x32_bf16(wa1, bhi, acc2[i][1], 0, 0, 0);
            }
        }
        // --- bias ---
#pragma unroll
        for (int mtl = 0; mtl < 2; ++mtl) {
            float bb[4];
#pragma unroll
            for (int r = 0; r < 4; ++r) bb[r] = b2l[(c2 * 2 + mtl) * 16 + quad * 4 + r];
#pragma unroll
            for (int i = 0; i < 4; ++i)
#pragma unroll
                for (int r = 0; r < 4; ++r) acc2[i][mtl][r] += bb[r];
        }
        // --- stats for this half ---
        float ss[2][4], qq[2][4];
#pragma unroll
        for (int mtl = 0; mtl < 2; ++mtl)
#pragma unroll
            for (int r = 0; r < 4; ++r) { ss[mtl][r] = 0.f; qq[mtl][r] = 0.f; }
#pragma unroll
        for (int i = 0; i < 4; ++i) {
            if (wv + 4 * i > 12) continue;
#pragma unroll
            for (int mtl = 0; mtl < 2; ++mtl)
#pragma unroll
                for (int r = 0; r < 4; ++r) {
                    float v = acc2[i][mtl][r] * vmsk[i];
                    ss[mtl][r] += v;
                    qq[mtl][r] += v * v;
                }
        }
#pragma unroll
        for (int d = 1; d < 16; d <<= 1)
#pragma unroll
            for (int mtl = 0; mtl < 2; ++mtl)
#pragma unroll
                for (int r = 0; r < 4; ++r) {
                    ss[mtl][r] += __shfl_xor(ss[mtl][r], d);
                    qq[mtl][r] += __shfl_xor(qq[mtl][r], d);
                }
        if (l15 == 0) {
#pragma unroll
            for (int mtl = 0; mtl < 2; ++mtl)
#pragma unroll
                for (int r = 0; r < 4; ++r) {
                    int co = (c2 * 2 + mtl) * 16 + quad * 4 + r;
                    wred[wv * 64 + co]       = ss[mtl][r];
                    wred[256 + wv * 64 + co] = qq[mtl][r];
                }
        }
        // --- slab write (separate LDS region; h1 stays intact for next half) ---
#pragma unroll
        for (int mtl = 0; mtl < 2; ++mtl) {
#pragma unroll
            for (int i = 0; i < 4; ++i) {
                if (wv + 4 * i > 12) continue;
                if (vmsk[i] > 0.f) {
#pragma unroll
                    for (int r = 0; r < 4; ++r)
                        slab[(mtl * 16 + quad * 4 + r) * 204 + pvals[i]] = acc2[i][mtl][r];
                }
            }
        }
        __syncthreads();
        // --- pool for this half (division-free decomposition) ---
        {
            int j7 = (pj >= 7) ? 1 : 0;
            int qy = j7, qx = pj - 7 * j7;
            size_t obase = (size_t)n * 3136 + (c2 * 32 + pk) * 49;
            const float* srow = slab + pk * 204;
#pragma unroll
            for (int it = 0; it < 7; ++it) {
                int pp = pj + (it << 3);
                if (pp < 49) {
                    int p0 = qy * 28 + qx * 2;
                    float2 a01 = *(const float2*)(srow + p0);
                    float2 a23 = *(const float2*)(srow + p0 + 14);
                    float mx = fmaxf(fmaxf(a01.x, a01.y), fmaxf(a23.x, a23.y));
                    pmax[obase + pp] = mx;
                }
                qx += 1; qy += 1;
                if (qx >= 7) { qx -= 7; qy += 1; }
            }
        }
        __syncthreads();   // slab reuse + wred visibility for the final read
    }
    // --- bn2part from wred (all 64 co written across both halves) ---
    if (tid < 64) {
        float s = wred[tid] + wred[64 + tid] + wred[128 + tid] + wred[192 + tid];
        float q = wred[256 + tid] + wred[320 + tid] + wred[384 + tid] + wred[448 + tid];
        bn2part[(n * 64 + tid) * 2 + 0] = s;
        bn2part[(n * 64 + tid) * 2 + 1] = q;
    }
}

// k5: finalize bn2 -> expanded per-fc1-k scale/shift arrays (3136 each)
__global__ __launch_bounds__(TPB) void k5_bn2_final(const float* __restrict__ bn2part,
                                                    const float* __restrict__ g2,
                                                    const float* __restrict__ be2,
                                                    float* __restrict__ sck,
                                                    float* __restrict__ shk) {
    __shared__ float red[TPB][2];
    __shared__ float sAC[2];
    int tid = threadIdx.x, co = blockIdx.x;
    float s = 0.f, q = 0.f;
    for (int i = tid; i < 4096; i += TPB) {
        s += bn2part[(i * 64 + co) * 2 + 0];
        q += bn2part[(i * 64 + co) * 2 + 1];
    }
    red[tid][0] = s; red[tid][1] = q;
    __syncthreads();
    for (int off = TPB / 2; off; off >>= 1) {
        if (tid < off) { red[tid][0] += red[tid + off][0]; red[tid][1] += red[tid + off][1]; }
        __syncthreads();
    }
    if (tid == 0) {
        const float count = 4096.f * 196.f;
        float mean = red[0][0] / count;
        float var  = red[0][1] / count - mean * mean;
        float a    = g2[co] * rsqrtf(var + EPSBN);
        sAC[0] = a;
        sAC[1] = be2[co] - a * mean;
    }
    __syncthreads();
    if (tid < 49) {
        sck[co * 49 + tid] = sAC[0];
        shk[co * 49 + tid] = sAC[1];
    }
}

// k7: fc1 via MFMA, single-bf16 activations. BN2+ReLU fused into A-staging.
__global__ __launch_bounds__(TPB) void k7_fc1_mfma(const float* __restrict__ pmax,
                                                   const float* __restrict__ sck,
                                                   const float* __restrict__ shk,
                                                   const unsigned short* __restrict__ fwp,
                                                   float* __restrict__ fpart) {
    __shared__ __align__(16) unsigned short K7S[7680];   // Ahi[64*40] Bsl[128*40]
    unsigned short* Ahi = K7S;
    unsigned short* Bsl = K7S + 2560;
    int tid = threadIdx.x;
    int mt = blockIdx.x & 63, ks = blockIdx.x >> 6;
    int m0 = mt * 64;
    int lane = tid & 63, wv = tid >> 6, quad = lane >> 4, l15 = lane & 15;
    f4v acc[8];
#pragma unroll
    for (int i = 0; i < 8; ++i) acc[i] = (f4v){0.f, 0.f, 0.f, 0.f};

    for (int it = 0; it < 14; ++it) {
        int g  = ks * 14 + it;
        int k0 = g * 32;
#pragma unroll
        for (int i = 0; i < 8; ++i) {
            int e  = tid + i * TPB;
            int r  = e >> 5, kk = e & 31;
            int k  = k0 + kk;
            float a = sck[k], c = shk[k];
            size_t src = (size_t)(m0 + r) * 3136 + k;
            float v = fmaxf(a * pmax[src] + c, 0.f);
            Ahi[r * 40 + kk] = f2bf(v);
        }
        {
            const uint4* src = (const uint4*)(fwp + (size_t)g * 4096 + tid * 16);
            uint4 w0 = src[0], w1 = src[1];
            int n = tid >> 1, kk0 = (tid & 1) * 16;
            *(uint4*)(Bsl + n * 40 + kk0)     = w0;
            *(uint4*)(Bsl + n * 40 + kk0 + 8) = w1;
        }
        __syncthreads();
        bf8v ahi = *(const bf8v*)(Ahi + (wv * 16 + l15) * 40 + quad * 8);
#pragma unroll
        for (int nt = 0; nt < 8; ++nt) {
            bf8v b = *(const bf8v*)(Bsl + (nt * 16 + l15) * 40 + quad * 8);
            acc[nt] = __builtin_amdgcn_mfma_f32_16x16x32_bf16(ahi, b, acc[nt], 0, 0, 0);
        }
        __syncthreads();
    }
#pragma unroll
    for (int nt = 0; nt < 8; ++nt)
#pragma unroll
        for (int r = 0; r < 4; ++r) {
            int m = m0 + wv * 16 + quad * 4 + r;
            int nn = nt * 16 + l15;
            fpart[(size_t)ks * 524288 + m * 128 + nn] = acc[nt][r];
        }
}

// k7b: reduce 7 K-split partials + bias + ReLU -> Phi [4096][129]
__global__ __launch_bounds__(TPB) void k7b_relu(const float* __restrict__ fpart,
                                                const float* __restrict__ fb,
                                                float* __restrict__ Phi) {
    int e = blockIdx.x * TPB + threadIdx.x;
    int n = e >> 7, f = e & 127;
    float s = fb[f];
#pragma unroll
    for (int c = 0; c < 7; ++c) s += fpart[(size_t)c * 524288 + e];
    Phi[n * 129 + f] = fmaxf(s, 0.f);
    if (f == 0) Phi[n * 129 + 128] = 1.0f;
}

// k8: partial Gram + C, 32-sample chunks
__global__ __launch_bounds__(TPB) void k8_gram(const float* __restrict__ Phi,
                                               const float* __restrict__ y,
                                               float* __restrict__ Gpart,
                                               float* __restrict__ Cpart) {
    __shared__ __align__(16) float ph[32 * 132];
    __shared__ __align__(16) float yl[32 * 12];
    int tid = threadIdx.x;
    int cB  = blockIdx.x;
    int n0  = cB * 32;
    for (int i = tid; i < 32 * 132; i += TPB) ph[i] = 0.f;
    for (int i = tid; i < 32 * 12; i += TPB) yl[i] = 0.f;
    __syncthreads();
    for (int i = tid; i < 32 * 129; i += TPB) {
        int r = i / 129, d = i % 129;
        ph[r * 132 + d] = Phi[(n0 + r) * 129 + d];
    }
    for (int i = tid; i < 320; i += TPB) {
        int r = i / 10, j = i % 10;
        yl[r * 12 + j] = y[(n0 + r) * 10 + j];
    }
    __syncthreads();
    for (int g = tid; g < 129 * 33; g += TPB) {
        int i = g / 33, j0 = (g % 33) * 4;
        float4 s = make_float4(0.f, 0.f, 0.f, 0.f);
        for (int r = 0; r < 32; ++r) {
            float  vi = ph[r * 132 + i];
            float4 vj = *(const float4*)&ph[r * 132 + j0];
            s.x += vi * vj.x; s.y += vi * vj.y; s.z += vi * vj.z; s.w += vi * vj.w;
        }
        *(float4*)&Gpart[(size_t)cB * 17028 + i * 132 + j0] = s;
    }
    for (int g = tid; g < 129 * 3; g += TPB) {
        int i = g / 3, j0 = (g % 3) * 4;
        float4 s = make_float4(0.f, 0.f, 0.f, 0.f);
        for (int r = 0; r < 32; ++r) {
            float  vi = ph[r * 132 + i];
            float4 vj = *(const float4*)&yl[r * 12 + j0];
            s.x += vi * vj.x; s.y += vi * vj.y; s.z += vi * vj.z; s.w += vi * vj.w;
        }
        *(float4*)&Cpart[(size_t)cB * 1548 + i * 12 + j0] = s;
    }
}

// k9: reduce partials -> G [129*129], C [129*10]
__global__ __launch_bounds__(TPB) void k9_reduce(const float* __restrict__ Gpart,
                                                 const float* __restrict__ Cpart,
                                                 float* __restrict__ G,
                                                 float* __restrict__ C) {
    int e = blockIdx.x * TPB + threadIdx.x;
    if (e < 16641) {
        int i = e / 129, j = e % 129;
        float s = 0.f;
        for (int c = 0; c < 128; ++c) s += Gpart[(size_t)c * 17028 + i * 132 + j];
        G[e] = s;
    } else if (e < 16641 + 1290) {
        int e2 = e - 16641;
        int i = e2 / 10, j = e2 % 10;
        float s = 0.f;
        for (int c = 0; c < 128; ++c) s += Cpart[(size_t)c * 1548 + i * 12 + j];
        C[e2] = s;
    }
}

// k10: solve (I+G) W = W0 + C. Gauss-Jordan with fully-diagonalized panels (r16).
// Confirmed win: 145 -> ~60 (inferred from total delta). Do not touch.
__global__ __launch_bounds__(TPB) void k10_solve(const float* __restrict__ G,
                                                 const float* __restrict__ C,
                                                 const float* __restrict__ W0,
                                                 float* __restrict__ Wnew) {
    __shared__ __align__(16) float M[129 * 140];
    __shared__ __align__(16) float LpT[PW * 116];   // [k][compact row], 113 used
    __shared__ float L11s[PW * 16];                 // L11s[m*16+k] = L11[k][m], m<k
    __shared__ float invD[129];
    __shared__ float x128s[10];
    int tid = threadIdx.x;
    int lane = tid & 63, wv = tid >> 6;
    for (int e = tid; e < 129 * 129; e += TPB) {
        int i = e / 129, j = e % 129;
        M[i * 140 + j] = G[e] + (i == j ? 1.f : 0.f);
    }
    for (int i = tid; i < 129; i += TPB) M[i * 140 + 129] = 0.f;
    for (int e = tid; e < 1290; e += TPB) {
        int i = e / 10, c = e % 10;
        M[i * 140 + 130 + c] = W0[e] + C[e];
    }
    __syncthreads();

    for (int k0 = 0; k0 < 128; k0 += PW) {
        const int kend = k0 + PW;
        // --- A: 16x16 LU in registers (wave 0, lanes 0..15), readlane broadcasts ---
        if (wv == 0) {
            bool act = lane < PW;
            int r  = k0 + lane;
            int rc = act ? r : k0;
            float u[PW], Lr[PW];
#pragma unroll
            for (int j = 0; j < PW; ++j) u[j] = M[rc * 140 + k0 + j];
            float dval = u[0];
#pragma unroll
            for (int k = 0; k < PW; ++k) {
                if (lane == k) dval = u[k];
                float piv = rdl(u[k], k);
                float f   = u[k] * __builtin_amdgcn_rcpf(piv);
                float fm  = (act && lane > k) ? f : 0.f;
                Lr[k] = fm;
#pragma unroll
                for (int j = 0; j < PW; ++j)
                    if (j > k) u[j] -= fm * rdl(u[j], k);
            }
            if (act) {
#pragma unroll
                for (int j = 0; j < PW; ++j)
                    if (j >= lane) M[r * 140 + k0 + j] = u[j];   // U11 incl diag
#pragma unroll
                for (int k = 0; k < PW; ++k)
                    if (k < lane) L11s[k * 16 + lane] = Lr[k];   // L11[lane][k]
                invD[r] = __builtin_amdgcn_rcpf(dval);
            }
        }
        __syncthreads();
        if (tid < 128) {
            // --- B (waves 0-1): chain-free coefficients vs diagonalized panel ---
            int cidx = tid;                      // compact off-panel row index
            if (cidx < 113) {
                int r = cidx < k0 ? cidx : cidx + PW;
                float4 a4[4];
#pragma unroll
                for (int q = 0; q < 4; ++q) a4[q] = *(const float4*)&M[r * 140 + k0 + q * 4];
                float a[PW];
#pragma unroll
                for (int q = 0; q < 4; ++q) {
                    a[q * 4 + 0] = a4[q].x; a[q * 4 + 1] = a4[q].y;
                    a[q * 4 + 2] = a4[q].z; a[q * 4 + 3] = a4[q].w;
                }
#pragma unroll
                for (int k = 0; k < PW; ++k)
                    LpT[k * 116 + cidx] = a[k] * invD[k0 + k];
            }
        } else {
            // --- C (waves 2-3): within-panel Jordan on trailing cols (incl RHS) ---
            int j = kend + (tid - 128);
            if (j < 140) {
                float yv[PW];
#pragma unroll
                for (int kk = 0; kk < PW; ++kk) {
                    float v = M[(k0 + kk) * 140 + j];
#pragma unroll
                    for (int m = 0; m < PW; ++m)
                        if (m < kk) v -= L11s[m * 16 + kk] * yv[m];
                    yv[kk] = v;
                }
                float xv[PW];
#pragma unroll
                for (int kk = PW - 1; kk >= 0; --kk) {
                    float v = yv[kk];
#pragma unroll
                    for (int m = 0; m < PW; ++m)
                        if (m > kk) v -= M[(k0 + kk) * 140 + k0 + m] * xv[m];
                    M[(k0 + kk) * 140 + j] = v;       // T = D * A11^{-1} * col
                    xv[kk] = v * invD[k0 + kk];
                }
            }
        }
        __syncthreads();
        // --- D: rank-16 update of ALL 113 off-panel rows, trailing cols ---
        const int Jn = 140 - kend;
        const int nrt = 29, nct = Jn >> 2;       // 113 rows -> 29 4-row tiles
        for (int t = tid; t < nrt * nct; t += TPB) {
            int tr = t % nrt, tc = t / nrt;
            int c0 = tr * 4;
            int j0 = kend + tc * 4;
            float4 s0 = {0, 0, 0, 0}, s1 = {0, 0, 0, 0}, s2 = {0, 0, 0, 0}, s3 = {0, 0, 0, 0};
#pragma unroll
            for (int kk = 0; kk < PW; ++kk) {
                float4 L4 = *(const float4*)&LpT[kk * 116 + c0];
                float4 U4 = *(const float4*)&M[(k0 + kk) * 140 + j0];
                s0.x += L4.x * U4.x; s0.y += L4.x * U4.y; s0.z += L4.x * U4.z; s0.w += L4.x * U4.w;
                s1.x += L4.y * U4.x; s1.y += L4.y * U4.y; s1.z += L4.y * U4.z; s1.w += L4.y * U4.w;
                s2.x += L4.z * U4.x; s2.y += L4.z * U4.y; s2.z += L4.z * U4.z; s2.w += L4.z * U4.w;
                s3.x += L4.w * U4.x; s3.y += L4.w * U4.y; s3.z += L4.w * U4.z; s3.w += L4.w * U4.w;
            }
            float4 sv[4] = {s0, s1, s2, s3};
#pragma unroll
            for (int i = 0; i < 4; ++i) {
                int cidx = c0 + i;
                if (cidx < 113) {
                    int r = cidx < k0 ? cidx : cidx + PW;
                    float4 mv = *(const float4*)&M[r * 140 + j0];
                    mv.x -= sv[i].x; mv.y -= sv[i].y; mv.z -= sv[i].z; mv.w -= sv[i].w;
                    *(float4*)&M[r * 140 + j0] = mv;
                }
            }
        }
        __syncthreads();
    }
    // --- extraction: rows are diagonal + col128 + RHS; no back-substitution ---
    if (tid == 0) {
        float i128 = __builtin_amdgcn_rcpf(M[128 * 140 + 128]);
#pragma unroll
        for (int c = 0; c < 10; ++c) x128s[c] = M[128 * 140 + 130 + c] * i128;
    }
    __syncthreads();
    if (tid < 128) {
        int r = tid;
        float m128 = M[r * 140 + 128];
        float idr  = invD[r];
#pragma unroll
        for (int c = 0; c < 10; ++c)
            Wnew[r * 10 + c] = (M[r * 140 + 130 + c] - m128 * x128s[c]) * idr;
    } else if (tid == 128) {
#pragma unroll
        for (int c = 0; c < 10; ++c) Wnew[1280 + c] = x128s[c];
    }
}

// k11: out = Phi @ Wnew  ([4096][10])
__global__ __launch_bounds__(TPB) void k11_out(const float* __restrict__ Phi,
                                               const float* __restrict__ Wnew,
                                               float* __restrict__ out) {
    __shared__ float Wl[1290];
    int tid = threadIdx.x;
    for (int i = tid; i < 1290; i += TPB) Wl[i] = Wnew[i];
    __syncthreads();
    int idx = blockIdx.x * TPB + tid;
    int n = idx / 10, j = idx % 10;
    float s = 0.f;
    for (int d = 0; d < 129; ++d) s += Phi[n * 129 + d] * Wl[d * 10 + j];
    out[idx] = s;
}

extern "C" void kernel_launch(void* const* d_in, const int* in_sizes, int n_in,
                              void* d_out, int out_size, void* d_ws, size_t ws_size,
                              hipStream_t stream) {
    const float* x   = (const float*)d_in[0];
    const float* y   = (const float*)d_in[1];
    const float* w1  = (const float*)d_in[2];
    const float* g1  = (const float*)d_in[4];
    const float* be1 = (const float*)d_in[5];
    const float* w2  = (const float*)d_in[6];
    const float* b2  = (const float*)d_in[7];
    const float* g2  = (const float*)d_in[8];
    const float* be2 = (const float*)d_in[9];
    const float* fw  = (const float*)d_in[10];
    const float* fb  = (const float*)d_in[11];
    const float* W0  = (const float*)d_in[12];
    float* out = (float*)d_out;
    float* ws  = (float*)d_ws;
    if (ws_size < WS_TOTAL * 4ull) return;

    unsigned* wAg_u = (unsigned*)(ws + WS_WAG);
    unsigned* fwp_u = (unsigned*)(ws + WS_FWP);
    const unsigned short* wAg_h = (const unsigned short*)wAg_u;
    const unsigned short* fwp_h = (const unsigned short*)fwp_u;
    float* sc1     = ws + WS_SC1;
    float* sh1     = ws + WS_SH1;
    float* sck     = ws + WS_SCK;
    float* shk     = ws + WS_SHK;
    float* G       = ws + WS_G;
    float* C       = ws + WS_C;
    float* Wnew    = ws + WS_WNEW;
    float* qpart   = ws + WS_BN1PART;
    float* bn2part = ws + WS_BN2PART;
    float* Phi     = ws + WS_PHI;
    float* fpart   = ws + WS_FPART;
    float* Gpart   = ws + WS_GPART;
    float* Cpart   = ws + WS_CPART;
    float* pmax    = ws + WS_PMAX;

    kWk1<<<1076, TPB, 0, stream>>>(w2, fw, x, wAg_u, fwp_u, qpart);
    k2_bn1_final<<<1, 64, 0, stream>>>(qpart, w1, g1, be1, sc1, sh1);
    k34_conv2_mfma<<<4096, TPB, 0, stream>>>(x, w1, sc1, sh1, wAg_h, b2, pmax, bn2part);
    k5_bn2_final<<<64, TPB, 0, stream>>>(bn2part, g2, be2, sck, shk);
    k7_fc1_mfma<<<448, TPB, 0, stream>>>(pmax, sck, shk, fwp_h, fpart);
    k7b_relu<<<2048, TPB, 0, stream>>>(fpart, fb, Phi);
    k8_gram<<<128, TPB, 0, stream>>>(Phi, y, Gpart, Cpart);
    k9_reduce<<<71, TPB, 0, stream>>>(Gpart, Cpart, G, C);
    k10_solve<<<1, TPB, 0, stream>>>(G, C, W0, Wnew);
    k11_out<<<160, TPB, 0, stream>>>(Phi, Wnew, out);
}

// Round 13
// 345.744 us; speedup vs baseline: 1.1932x; 1.0251x over previous
//
#include <hip/hip_runtime.h>
#include <math.h>

#define TPB 256
#define EPSBN 1e-5f
#define PW 16

typedef __attribute__((ext_vector_type(8))) short bf8v;   // 8 x bf16 (4 VGPR)
typedef __attribute__((ext_vector_type(4))) float f4v;    // MFMA acc

static __device__ __forceinline__ unsigned short f2bf(float f) {
    union { float f; unsigned u; } v; v.f = f;
    unsigned r = v.u + 0x7fffu + ((v.u >> 16) & 1u);
    return (unsigned short)(r >> 16);
}
// HW packed f32->bf16 convert (RNE, same rounding as f2bf); 1 inst replaces ~8.
static __device__ __forceinline__ unsigned cvt_pk_bf16(float lo, float hi) {
    unsigned r;
    asm("v_cvt_pk_bf16_f32 %0, %1, %2" : "=v"(r) : "v"(lo), "v"(hi));
    return r;
}
static __device__ __forceinline__ unsigned short cvt1_bf16(float v) {
    return (unsigned short)cvt_pk_bf16(v, v);
}
// broadcast-from-lane via v_readlane (VALU, ~8cy) instead of ds_bpermute (~120cy)
static __device__ __forceinline__ float rdl(float v, int l) {
    return __int_as_float(__builtin_amdgcn_readlane(__float_as_int(v), l));
}

// ---- workspace layout (float element offsets); total 26,865,664 floats (~107.5 MB) ----
#define WS_WAG      0u
#define WS_FWP      9216u
#define WS_SC1      209920u
#define WS_SH1      209952u
#define WS_SCK      209984u
#define WS_SHK      213120u
#define WS_G        216256u
#define WS_C        232897u
#define WS_WNEW     234187u
#define WS_BN1PART  235520u
#define WS_BN2PART  497664u
#define WS_PHI      1021952u
#define WS_FPART    1550336u
#define WS_GPART    5220352u
#define WS_CPART    7399936u
#define WS_PMAX     7598080u
#define WS_PMINH    20443136u
#define WS_TOTAL    26865664ull

// kWk1: fused weight-pack + BN1-stats (independent input-only kernels; saves a launch).
__global__ __launch_bounds__(TPB) void kWk1(const float* __restrict__ w2,
                                            const float* __restrict__ fw,
                                            const float* __restrict__ x,
                                            unsigned* __restrict__ wAg_u,
                                            unsigned* __restrict__ fwp_u,
                                            float* __restrict__ qpart) {
    __shared__ float xs[900];
    __shared__ float red[4][54];
    if (blockIdx.x < 820) {
        int e = blockIdx.x * TPB + threadIdx.x;
        if (e < 9216) {
            int jj = e & 3, lane = (e >> 2) & 63, mt = (e >> 8) & 3, t = e >> 10;
            int j0 = jj * 2;
            int co = mt * 16 + (lane & 15);
            int ci = (lane >> 4) * 8 + j0;
            unsigned h0 = f2bf(w2[(co * 32 + ci) * 9 + t]);
            unsigned h1 = f2bf(w2[(co * 32 + ci + 1) * 9 + t]);
            wAg_u[e] = h0 | (h1 << 16);
        } else if (e < 9216 + 200704) {
            int f = e - 9216;
            int kk = (f & 15) * 2, n = (f >> 4) & 127, g = f >> 11;
            unsigned h0 = f2bf(fw[n * 3136 + g * 32 + kk]);
            unsigned h1 = f2bf(fw[n * 3136 + g * 32 + kk + 1]);
            fwp_u[f] = h0 | (h1 << 16);
        }
        return;
    }
    int bid = blockIdx.x - 820;
    int tid = threadIdx.x;
    float acc[54];
#pragma unroll
    for (int i = 0; i < 54; ++i) acc[i] = 0.f;
    for (int img = 0; img < 16; ++img) {
        int n = bid * 16 + img;
        for (int i = tid; i < 900; i += TPB) xs[i] = 0.f;
        __syncthreads();
        for (int i = tid; i < 784; i += TPB) {
            int r = i / 28, c = i % 28;
            xs[(r + 1) * 30 + (c + 1)] = x[n * 784 + i];
        }
        __syncthreads();
        for (int p = tid; p < 784; p += TPB) {
            int oy = p / 28, ox = p % 28;
            float v[9];
#pragma unroll
            for (int t = 0; t < 9; ++t) v[t] = xs[(oy + t / 3) * 30 + ox + (t % 3)];
            int qi = 9;
#pragma unroll
            for (int t = 0; t < 9; ++t) {
                acc[t] += v[t];
#pragma unroll
                for (int u = t; u < 9; ++u) acc[qi++] += v[t] * v[u];
            }
        }
        __syncthreads();
    }
    int wv = tid >> 6, lane = tid & 63;
#pragma unroll
    for (int i = 0; i < 54; ++i) {
        float s = acc[i];
        for (int d = 1; d < 64; d <<= 1) s += __shfl_xor(s, d);
        if (lane == 0) red[wv][i] = s;
    }
    __syncthreads();
    if (tid < 54)
        qpart[bid * 54 + tid] = red[0][tid] + red[1][tid] + red[2][tid] + red[3][tid];
}

// k2: reduce qpart -> S,Q; per-channel mean/var from 9x9 moments (bias cancels in BN)
__global__ __launch_bounds__(64) void k2_bn1_final(const float* __restrict__ qpart,
                                                   const float* __restrict__ w1,
                                                   const float* __restrict__ g1,
                                                   const float* __restrict__ be1,
                                                   float* __restrict__ sc1,
                                                   float* __restrict__ sh1) {
    __shared__ float T[54];
    int tid = threadIdx.x;
    if (tid < 54) {
        float s = 0.f;
#pragma unroll 8
        for (int b = 0; b < 256; ++b) s += qpart[b * 54 + tid];
        T[tid] = s;
    }
    __syncthreads();
    if (tid < 32) {
        const float inv = 1.f / (4096.f * 784.f);
        float w[9];
#pragma unroll
        for (int t = 0; t < 9; ++t) w[t] = w1[tid * 9 + t];
        float mean = 0.f;
#pragma unroll
        for (int t = 0; t < 9; ++t) mean += w[t] * T[t];
        mean *= inv;
        float ex2 = 0.f;
        int qi = 9;
#pragma unroll
        for (int t = 0; t < 9; ++t)
#pragma unroll
            for (int u = t; u < 9; ++u) {
                float c = w[t] * w[u] * T[qi++];
                ex2 += (u == t) ? c : 2.f * c;
            }
        ex2 *= inv;
        float var = ex2 - mean * mean;
        float a = g1[tid] * rsqrtf(var + EPSBN);
        sc1[tid] = a;
        sh1[tid] = be1[tid] - a * mean;
    }
}

// k34: per image: conv1+BN1+ReLU+pool -> LDS bf16 -> conv2 via MFMA -> stats + pooled max
// r24: bf16 SLAB — the one lever not excluded by the ledger: raise occupancy
// WITHOUT extra barriers (r21 failure) and WITHOUT breaking 16B alignment (r22
// failure). Slab stored as bf16 (26.1 -> 13.1 KB): LDS 48 -> 35 KB -> 4
// blocks/CU; regs ~100 < 128 -> 4 waves/SIMD granted. Correctness: RNE is
// monotonic so max(bf16(v)) == bf16(max(v)) — pmax becomes the bf16-quantized
// pooled max (same quantization class as the original accepted pminh path);
// k7 bf16-rounds the activation downstream anyway. absmax headroom 4x.
// Ledger (counter-verified): c2-split WIN; float2+cvt_pk conv1 ~neutral kept;
// launch_bounds(,5) spills (never force); slab-halving +4 barriers LOSS
// (barriers dominate occupancy); h1 stride 88B LOSS (broke b128 alignment;
// 80=16*5 optimal among aligned strides).
__global__ __launch_bounds__(TPB) void k34_conv2_mfma(const float* __restrict__ x,
                                                      const float* __restrict__ w1,
                                                      const float* __restrict__ sc1,
                                                      const float* __restrict__ sh1,
                                                      const unsigned short* __restrict__ wAg,
                                                      const float* __restrict__ b2,
                                                      float* __restrict__ pmax,
                                                      float* __restrict__ bn2part) {
    // LDS layout (ushort units): slab bf16[32][204] @0 (xs aliases), h1 @6528
    // (256 paddr x 80B), wred fp32[512] @16768, b2l fp32[64] @17792.
    __shared__ __align__(16) unsigned short SH[17920];
    unsigned short* slabh = SH;
    float* xs   = (float*)SH;                     // alias slab (dead then)
    unsigned* H1u = (unsigned*)(SH + 6528);
    const char* h1hiB = (const char*)(SH + 6528);
    float* wred = (float*)(SH + 16768);
    float* b2l  = (float*)(SH + 17792);

    int tid = threadIdx.x;
    int n   = blockIdx.x;
    int lane = tid & 63, wv = tid >> 6, quad = lane >> 4, l15 = lane & 15;

    for (int i = tid; i < 5120; i += TPB) H1u[i] = 0u;
    for (int i = tid; i < 900; i += TPB) xs[i] = 0.f;
    if (tid < 64) b2l[tid] = b2[tid];
    __syncthreads();
    for (int i = tid; i < 784; i += TPB) {
        int r = i / 28, c = i % 28;
        xs[(r + 1) * 30 + (c + 1)] = x[n * 784 + i];
    }
    __syncthreads();

    if (tid < 196) {
        int py = tid / 14, px = tid % 14;
        int paddr = (py + 1) * 16 + (px + 1);
        float patch[4][4];
#pragma unroll
        for (int r = 0; r < 4; ++r)
#pragma unroll
            for (int c = 0; c < 4; ++c) patch[r][c] = xs[(2 * py + r) * 30 + 2 * px + c];
        unsigned hw0 = 0;
#pragma unroll
        for (int cp = 0; cp < 16; ++cp) {           // channel pair (2cp, 2cp+1)
            float mx0 = -1e30f, mx1 = -1e30f;
#pragma unroll
            for (int sy = 0; sy < 2; ++sy)
#pragma unroll
                for (int sx = 0; sx < 2; ++sx) {
                    float v0 = 0.f, v1 = 0.f;
#pragma unroll
                    for (int t = 0; t < 9; ++t) {
                        float pv = patch[sy + t / 3][sx + t % 3];
                        v0 += pv * w1[(2 * cp) * 9 + t];
                        v1 += pv * w1[(2 * cp + 1) * 9 + t];
                    }
                    mx0 = fmaxf(mx0, v0);
                    mx1 = fmaxf(mx1, v1);
                }
            float r0 = fmaxf(sc1[2 * cp] * mx0 + sh1[2 * cp], 0.f);
            float r1 = fmaxf(sc1[2 * cp + 1] * mx1 + sh1[2 * cp + 1], 0.f);
            unsigned hp = cvt_pk_bf16(r0, r1);      // lo = ch 2cp, hi = ch 2cp+1
            if ((cp & 1) == 0) hw0 = hp;
            else *(uint2*)(H1u + paddr * 20 + (cp - 1)) = make_uint2(hw0, hp);
        }
    }
    __syncthreads();

    int baseB[4];
    float vmsk[4];
    int pvals[4];
#pragma unroll
    for (int i = 0; i < 4; ++i) {
        int nt = wv + 4 * i;
        int p  = nt * 16 + l15;
        vmsk[i]  = (nt <= 12 && p < 196) ? 1.f : 0.f;
        pvals[i] = p;
        int pc = p < 196 ? p : 195;
        int py = pc / 14, px = pc - py * 14;
        baseB[i] = ((py + 1) * 16 + (px + 1)) * 80 + quad * 16;
    }

    int pk = tid >> 3, pj = tid & 7;   // pool decomposition

#pragma unroll
    for (int c2 = 0; c2 < 2; ++c2) {
        // --- MFMA for channel half c2 (mt = c2*2 + mtl), acc = 32 regs ---
        f4v acc2[4][2];
#pragma unroll
        for (int i = 0; i < 4; ++i)
#pragma unroll
            for (int mtl = 0; mtl < 2; ++mtl) acc2[i][mtl] = (f4v){0.f, 0.f, 0.f, 0.f};
#pragma unroll
        for (int t = 0; t < 9; ++t) {
            const int toff = ((t / 3) - 1) * 1280 + ((t % 3) - 1) * 80;
            bf8v wa0 = *(const bf8v*)(wAg + ((t * 4 + c2 * 2 + 0) * 64 + lane) * 8);
            bf8v wa1 = *(const bf8v*)(wAg + ((t * 4 + c2 * 2 + 1) * 64 + lane) * 8);
#pragma unroll
            for (int i = 0; i < 4; ++i) {
                if (wv + 4 * i > 12) continue;
                bf8v bhi = *(const bf8v*)(h1hiB + baseB[i] + toff);
                acc2[i][0] = __builtin_amdgcn_mfma_f32_16x16x32_bf16(wa0, bhi, acc2[i][0], 0, 0, 0);
                acc2[i][1] = __builtin_amdgcn_mfma_f32_16x16x32_bf16(wa1, bhi, acc2[i][1], 0, 0, 0);
            }
        }
        // --- bias ---
#pragma unroll
        for (int mtl = 0; mtl < 2; ++mtl) {
            float bb[4];
#pragma unroll
            for (int r = 0; r < 4; ++r) bb[r] = b2l[(c2 * 2 + mtl) * 16 + quad * 4 + r];
#pragma unroll
            for (int i = 0; i < 4; ++i)
#pragma unroll
                for (int r = 0; r < 4; ++r) acc2[i][mtl][r] += bb[r];
        }
        // --- stats for this half ---
        float ss[2][4], qq[2][4];
#pragma unroll
        for (int mtl = 0; mtl < 2; ++mtl)
#pragma unroll
            for (int r = 0; r < 4; ++r) { ss[mtl][r] = 0.f; qq[mtl][r] = 0.f; }
#pragma unroll
        for (int i = 0; i < 4; ++i) {
            if (wv + 4 * i > 12) continue;
#pragma unroll
            for (int mtl = 0; mtl < 2; ++mtl)
#pragma unroll
                for (int r = 0; r < 4; ++r) {
                    float v = acc2[i][mtl][r] * vmsk[i];
                    ss[mtl][r] += v;
                    qq[mtl][r] += v * v;
                }
        }
#pragma unroll
        for (int d = 1; d < 16; d <<= 1)
#pragma unroll
            for (int mtl = 0; mtl < 2; ++mtl)
#pragma unroll
                for (int r = 0; r < 4; ++r) {
                    ss[mtl][r] += __shfl_xor(ss[mtl][r], d);
                    qq[mtl][r] += __shfl_xor(qq[mtl][r], d);
                }
        if (l15 == 0) {
#pragma unroll
            for (int mtl = 0; mtl < 2; ++mtl)
#pragma unroll
                for (int r = 0; r < 4; ++r) {
                    int co = (c2 * 2 + mtl) * 16 + quad * 4 + r;
                    wred[wv * 64 + co]       = ss[mtl][r];
                    wred[256 + wv * 64 + co] = qq[mtl][r];
                }
        }
        // --- slab write, bf16 (separate LDS region; h1 intact across halves) ---
#pragma unroll
        for (int mtl = 0; mtl < 2; ++mtl) {
#pragma unroll
            for (int i = 0; i < 4; ++i) {
                if (wv + 4 * i > 12) continue;
                if (vmsk[i] > 0.f) {
#pragma unroll
                    for (int r = 0; r < 4; ++r)
                        slabh[(mtl * 16 + quad * 4 + r) * 204 + pvals[i]] =
                            cvt1_bf16(acc2[i][mtl][r]);
                }
            }
        }
        __syncthreads();
        // --- pool for this half (division-free; bf16 pairs via shift/mask) ---
        {
            int j7 = (pj >= 7) ? 1 : 0;
            int qy = j7, qx = pj - 7 * j7;
            size_t obase = (size_t)n * 3136 + (c2 * 32 + pk) * 49;
            const unsigned short* srow = slabh + pk * 204;
#pragma unroll
            for (int it = 0; it < 7; ++it) {
                int pp = pj + (it << 3);
                if (pp < 49) {
                    int p0 = qy * 28 + qx * 2;           // always even -> 4B aligned
                    unsigned a01 = *(const unsigned*)(srow + p0);
                    unsigned a23 = *(const unsigned*)(srow + p0 + 14);
                    float v00 = __uint_as_float(a01 << 16);
                    float v01 = __uint_as_float(a01 & 0xffff0000u);
                    float v10 = __uint_as_float(a23 << 16);
                    float v11 = __uint_as_float(a23 & 0xffff0000u);
                    float mx = fmaxf(fmaxf(v00, v01), fmaxf(v10, v11));
                    pmax[obase + pp] = mx;
                }
                qx += 1; qy += 1;
                if (qx >= 7) { qx -= 7; qy += 1; }
            }
        }
        __syncthreads();   // slab reuse + wred visibility for the final read
    }
    // --- bn2part from wred (all 64 co written across both halves) ---
    if (tid < 64) {
        float s = wred[tid] + wred[64 + tid] + wred[128 + tid] + wred[192 + tid];
        float q = wred[256 + tid] + wred[320 + tid] + wred[384 + tid] + wred[448 + tid];
        bn2part[(n * 64 + tid) * 2 + 0] = s;
        bn2part[(n * 64 + tid) * 2 + 1] = q;
    }
}

// k5: finalize bn2 -> expanded per-fc1-k scale/shift arrays (3136 each)
__global__ __launch_bounds__(TPB) void k5_bn2_final(const float* __restrict__ bn2part,
                                                    const float* __restrict__ g2,
                                                    const float* __restrict__ be2,
                                                    float* __restrict__ sck,
                                                    float* __restrict__ shk) {
    __shared__ float red[TPB][2];
    __shared__ float sAC[2];
    int tid = threadIdx.x, co = blockIdx.x;
    float s = 0.f, q = 0.f;
    for (int i = tid; i < 4096; i += TPB) {
        s += bn2part[(i * 64 + co) * 2 + 0];
        q += bn2part[(i * 64 + co) * 2 + 1];
    }
    red[tid][0] = s; red[tid][1] = q;
    __syncthreads();
    for (int off = TPB / 2; off; off >>= 1) {
        if (tid < off) { red[tid][0] += red[tid + off][0]; red[tid][1] += red[tid + off][1]; }
        __syncthreads();
    }
    if (tid == 0) {
        const float count = 4096.f * 196.f;
        float mean = red[0][0] / count;
        float var  = red[0][1] / count - mean * mean;
        float a    = g2[co] * rsqrtf(var + EPSBN);
        sAC[0] = a;
        sAC[1] = be2[co] - a * mean;
    }
    __syncthreads();
    if (tid < 49) {
        sck[co * 49 + tid] = sAC[0];
        shk[co * 49 + tid] = sAC[1];
    }
}

// k7: fc1 via MFMA, single-bf16 activations. BN2+ReLU fused into A-staging.
__global__ __launch_bounds__(TPB) void k7_fc1_mfma(const float* __restrict__ pmax,
                                                   const float* __restrict__ sck,
                                                   const float* __restrict__ shk,
                                                   const unsigned short* __restrict__ fwp,
                                                   float* __restrict__ fpart) {
    __shared__ __align__(16) unsigned short K7S[7680];   // Ahi[64*40] Bsl[128*40]
    unsigned short* Ahi = K7S;
    unsigned short* Bsl = K7S + 2560;
    int tid = threadIdx.x;
    int mt = blockIdx.x & 63, ks = blockIdx.x >> 6;
    int m0 = mt * 64;
    int lane = tid & 63, wv = tid >> 6, quad = lane >> 4, l15 = lane & 15;
    f4v acc[8];
#pragma unroll
    for (int i = 0; i < 8; ++i) acc[i] = (f4v){0.f, 0.f, 0.f, 0.f};

    for (int it = 0; it < 14; ++it) {
        int g  = ks * 14 + it;
        int k0 = g * 32;
#pragma unroll
        for (int i = 0; i < 8; ++i) {
            int e  = tid + i * TPB;
            int r  = e >> 5, kk = e & 31;
            int k  = k0 + kk;
            float a = sck[k], c = shk[k];
            size_t src = (size_t)(m0 + r) * 3136 + k;
            float v = fmaxf(a * pmax[src] + c, 0.f);
            Ahi[r * 40 + kk] = f2bf(v);
        }
        {
            const uint4* src = (const uint4*)(fwp + (size_t)g * 4096 + tid * 16);
            uint4 w0 = src[0], w1 = src[1];
            int n = tid >> 1, kk0 = (tid & 1) * 16;
            *(uint4*)(Bsl + n * 40 + kk0)     = w0;
            *(uint4*)(Bsl + n * 40 + kk0 + 8) = w1;
        }
        __syncthreads();
        bf8v ahi = *(const bf8v*)(Ahi + (wv * 16 + l15) * 40 + quad * 8);
#pragma unroll
        for (int nt = 0; nt < 8; ++nt) {
            bf8v b = *(const bf8v*)(Bsl + (nt * 16 + l15) * 40 + quad * 8);
            acc[nt] = __builtin_amdgcn_mfma_f32_16x16x32_bf16(ahi, b, acc[nt], 0, 0, 0);
        }
        __syncthreads();
    }
#pragma unroll
    for (int nt = 0; nt < 8; ++nt)
#pragma unroll
        for (int r = 0; r < 4; ++r) {
            int m = m0 + wv * 16 + quad * 4 + r;
            int nn = nt * 16 + l15;
            fpart[(size_t)ks * 524288 + m * 128 + nn] = acc[nt][r];
        }
}

// k7b: reduce 7 K-split partials + bias + ReLU -> Phi [4096][129]
__global__ __launch_bounds__(TPB) void k7b_relu(const float* __restrict__ fpart,
                                                const float* __restrict__ fb,
                                                float* __restrict__ Phi) {
    int e = blockIdx.x * TPB + threadIdx.x;
    int n = e >> 7, f = e & 127;
    float s = fb[f];
#pragma unroll
    for (int c = 0; c < 7; ++c) s += fpart[(size_t)c * 524288 + e];
    Phi[n * 129 + f] = fmaxf(s, 0.f);
    if (f == 0) Phi[n * 129 + 128] = 1.0f;
}

// k8: partial Gram + C, 32-sample chunks
__global__ __launch_bounds__(TPB) void k8_gram(const float* __restrict__ Phi,
                                               const float* __restrict__ y,
                                               float* __restrict__ Gpart,
                                               float* __restrict__ Cpart) {
    __shared__ __align__(16) float ph[32 * 132];
    __shared__ __align__(16) float yl[32 * 12];
    int tid = threadIdx.x;
    int cB  = blockIdx.x;
    int n0  = cB * 32;
    for (int i = tid; i < 32 * 132; i += TPB) ph[i] = 0.f;
    for (int i = tid; i < 32 * 12; i += TPB) yl[i] = 0.f;
    __syncthreads();
    for (int i = tid; i < 32 * 129; i += TPB) {
        int r = i / 129, d = i % 129;
        ph[r * 132 + d] = Phi[(n0 + r) * 129 + d];
    }
    for (int i = tid; i < 320; i += TPB) {
        int r = i / 10, j = i % 10;
        yl[r * 12 + j] = y[(n0 + r) * 10 + j];
    }
    __syncthreads();
    for (int g = tid; g < 129 * 33; g += TPB) {
        int i = g / 33, j0 = (g % 33) * 4;
        float4 s = make_float4(0.f, 0.f, 0.f, 0.f);
        for (int r = 0; r < 32; ++r) {
            float  vi = ph[r * 132 + i];
            float4 vj = *(const float4*)&ph[r * 132 + j0];
            s.x += vi * vj.x; s.y += vi * vj.y; s.z += vi * vj.z; s.w += vi * vj.w;
        }
        *(float4*)&Gpart[(size_t)cB * 17028 + i * 132 + j0] = s;
    }
    for (int g = tid; g < 129 * 3; g += TPB) {
        int i = g / 3, j0 = (g % 3) * 4;
        float4 s = make_float4(0.f, 0.f, 0.f, 0.f);
        for (int r = 0; r < 32; ++r) {
            float  vi = ph[r * 132 + i];
            float4 vj = *(const float4*)&yl[r * 12 + j0];
            s.x += vi * vj.x; s.y += vi * vj.y; s.z += vi * vj.z; s.w += vi * vj.w;
        }
        *(float4*)&Cpart[(size_t)cB * 1548 + i * 12 + j0] = s;
    }
}

// k9: reduce partials -> G [129*129], C [129*10]
__global__ __launch_bounds__(TPB) void k9_reduce(const float* __restrict__ Gpart,
                                                 const float* __restrict__ Cpart,
                                                 float* __restrict__ G,
                                                 float* __restrict__ C) {
    int e = blockIdx.x * TPB + threadIdx.x;
    if (e < 16641) {
        int i = e / 129, j = e % 129;
        float s = 0.f;
        for (int c = 0; c < 128; ++c) s += Gpart[(size_t)c * 17028 + i * 132 + j];
        G[e] = s;
    } else if (e < 16641 + 1290) {
        int e2 = e - 16641;
        int i = e2 / 10, j = e2 % 10;
        float s = 0.f;
        for (int c = 0; c < 128; ++c) s += Cpart[(size_t)c * 1548 + i * 12 + j];
        C[e2] = s;
    }
}

// k10: solve (I+G) W = W0 + C. Gauss-Jordan with fully-diagonalized panels (r16).
// Confirmed win: 145 -> ~60 (inferred from total delta). Do not touch.
__global__ __launch_bounds__(TPB) void k10_solve(const float* __restrict__ G,
                                                 const float* __restrict__ C,
                                                 const float* __restrict__ W0,
                                                 float* __restrict__ Wnew) {
    __shared__ __align__(16) float M[129 * 140];
    __shared__ __align__(16) float LpT[PW * 116];   // [k][compact row], 113 used
    __shared__ float L11s[PW * 16];                 // L11s[m*16+k] = L11[k][m], m<k
    __shared__ float invD[129];
    __shared__ float x128s[10];
    int tid = threadIdx.x;
    int lane = tid & 63, wv = tid >> 6;
    for (int e = tid; e < 129 * 129; e += TPB) {
        int i = e / 129, j = e % 129;
        M[i * 140 + j] = G[e] + (i == j ? 1.f : 0.f);
    }
    for (int i = tid; i < 129; i += TPB) M[i * 140 + 129] = 0.f;
    for (int e = tid; e < 1290; e += TPB) {
        int i = e / 10, c = e % 10;
        M[i * 140 + 130 + c] = W0[e] + C[e];
    }
    __syncthreads();

    for (int k0 = 0; k0 < 128; k0 += PW) {
        const int kend = k0 + PW;
        // --- A: 16x16 LU in registers (wave 0, lanes 0..15), readlane broadcasts ---
        if (wv == 0) {
            bool act = lane < PW;
            int r  = k0 + lane;
            int rc = act ? r : k0;
            float u[PW], Lr[PW];
#pragma unroll
            for (int j = 0; j < PW; ++j) u[j] = M[rc * 140 + k0 + j];
            float dval = u[0];
#pragma unroll
            for (int k = 0; k < PW; ++k) {
                if (lane == k) dval = u[k];
                float piv = rdl(u[k], k);
                float f   = u[k] * __builtin_amdgcn_rcpf(piv);
                float fm  = (act && lane > k) ? f : 0.f;
                Lr[k] = fm;
#pragma unroll
                for (int j = 0; j < PW; ++j)
                    if (j > k) u[j] -= fm * rdl(u[j], k);
            }
            if (act) {
#pragma unroll
                for (int j = 0; j < PW; ++j)
                    if (j >= lane) M[r * 140 + k0 + j] = u[j];   // U11 incl diag
#pragma unroll
                for (int k = 0; k < PW; ++k)
                    if (k < lane) L11s[k * 16 + lane] = Lr[k];   // L11[lane][k]
                invD[r] = __builtin_amdgcn_rcpf(dval);
            }
        }
        __syncthreads();
        if (tid < 128) {
            // --- B (waves 0-1): chain-free coefficients vs diagonalized panel ---
            int cidx = tid;                      // compact off-panel row index
            if (cidx < 113) {
                int r = cidx < k0 ? cidx : cidx + PW;
                float4 a4[4];
#pragma unroll
                for (int q = 0; q < 4; ++q) a4[q] = *(const float4*)&M[r * 140 + k0 + q * 4];
                float a[PW];
#pragma unroll
                for (int q = 0; q < 4; ++q) {
                    a[q * 4 + 0] = a4[q].x; a[q * 4 + 1] = a4[q].y;
                    a[q * 4 + 2] = a4[q].z; a[q * 4 + 3] = a4[q].w;
                }
#pragma unroll
                for (int k = 0; k < PW; ++k)
                    LpT[k * 116 + cidx] = a[k] * invD[k0 + k];
            }
        } else {
            // --- C (waves 2-3): within-panel Jordan on trailing cols (incl RHS) ---
            int j = kend + (tid - 128);
            if (j < 140) {
                float yv[PW];
#pragma unroll
                for (int kk = 0; kk < PW; ++kk) {
                    float v = M[(k0 + kk) * 140 + j];
#pragma unroll
                    for (int m = 0; m < PW; ++m)
                        if (m < kk) v -= L11s[m * 16 + kk] * yv[m];
                    yv[kk] = v;
                }
                float xv[PW];
#pragma unroll
                for (int kk = PW - 1; kk >= 0; --kk) {
                    float v = yv[kk];
#pragma unroll
                    for (int m = 0; m < PW; ++m)
                        if (m > kk) v -= M[(k0 + kk) * 140 + k0 + m] * xv[m];
                    M[(k0 + kk) * 140 + j] = v;       // T = D * A11^{-1} * col
                    xv[kk] = v * invD[k0 + kk];
                }
            }
        }
        __syncthreads();
        // --- D: rank-16 update of ALL 113 off-panel rows, trailing cols ---
        const int Jn = 140 - kend;
        const int nrt = 29, nct = Jn >> 2;       // 113 rows -> 29 4-row tiles
        for (int t = tid; t < nrt * nct; t += TPB) {
            int tr = t % nrt, tc = t / nrt;
            int c0 = tr * 4;
            int j0 = kend + tc * 4;
            float4 s0 = {0, 0, 0, 0}, s1 = {0, 0, 0, 0}, s2 = {0, 0, 0, 0}, s3 = {0, 0, 0, 0};
#pragma unroll
            for (int kk = 0; kk < PW; ++kk) {
                float4 L4 = *(const float4*)&LpT[kk * 116 + c0];
                float4 U4 = *(const float4*)&M[(k0 + kk) * 140 + j0];
                s0.x += L4.x * U4.x; s0.y += L4.x * U4.y; s0.z += L4.x * U4.z; s0.w += L4.x * U4.w;
                s1.x += L4.y * U4.x; s1.y += L4.y * U4.y; s1.z += L4.y * U4.z; s1.w += L4.y * U4.w;
                s2.x += L4.z * U4.x; s2.y += L4.z * U4.y; s2.z += L4.z * U4.z; s2.w += L4.z * U4.w;
                s3.x += L4.w * U4.x; s3.y += L4.w * U4.y; s3.z += L4.w * U4.z; s3.w += L4.w * U4.w;
            }
            float4 sv[4] = {s0, s1, s2, s3};
#pragma unroll
            for (int i = 0; i < 4; ++i) {
                int cidx = c0 + i;
                if (cidx < 113) {
                    int r = cidx < k0 ? cidx : cidx + PW;
                    float4 mv = *(const float4*)&M[r * 140 + j0];
                    mv.x -= sv[i].x; mv.y -= sv[i].y; mv.z -= sv[i].z; mv.w -= sv[i].w;
                    *(float4*)&M[r * 140 + j0] = mv;
                }
            }
        }
        __syncthreads();
    }
    // --- extraction: rows are diagonal + col128 + RHS; no back-substitution ---
    if (tid == 0) {
        float i128 = __builtin_amdgcn_rcpf(M[128 * 140 + 128]);
#pragma unroll
        for (int c = 0; c < 10; ++c) x128s[c] = M[128 * 140 + 130 + c] * i128;
    }
    __syncthreads();
    if (tid < 128) {
        int r = tid;
        float m128 = M[r * 140 + 128];
        float idr  = invD[r];
#pragma unroll
        for (int c = 0; c < 10; ++c)
            Wnew[r * 10 + c] = (M[r * 140 + 130 + c] - m128 * x128s[c]) * idr;
    } else if (tid == 128) {
#pragma unroll
        for (int c = 0; c < 10; ++c) Wnew[1280 + c] = x128s[c];
    }
}

// k11: out = Phi @ Wnew  ([4096][10])
__global__ __launch_bounds__(TPB) void k11_out(const float* __restrict__ Phi,
                                               const float* __restrict__ Wnew,
                                               float* __restrict__ out) {
    __shared__ float Wl[1290];
    int tid = threadIdx.x;
    for (int i = tid; i < 1290; i += TPB) Wl[i] = Wnew[i];
    __syncthreads();
    int idx = blockIdx.x * TPB + tid;
    int n = idx / 10, j = idx % 10;
    float s = 0.f;
    for (int d = 0; d < 129; ++d) s += Phi[n * 129 + d] * Wl[d * 10 + j];
    out[idx] = s;
}

extern "C" void kernel_launch(void* const* d_in, const int* in_sizes, int n_in,
                              void* d_out, int out_size, void* d_ws, size_t ws_size,
                              hipStream_t stream) {
    const float* x   = (const float*)d_in[0];
    const float* y   = (const float*)d_in[1];
    const float* w1  = (const float*)d_in[2];
    const float* g1  = (const float*)d_in[4];
    const float* be1 = (const float*)d_in[5];
    const float* w2  = (const float*)d_in[6];
    const float* b2  = (const float*)d_in[7];
    const float* g2  = (const float*)d_in[8];
    const float* be2 = (const float*)d_in[9];
    const float* fw  = (const float*)d_in[10];
    const float* fb  = (const float*)d_in[11];
    const float* W0  = (const float*)d_in[12];
    float* out = (float*)d_out;
    float* ws  = (float*)d_ws;
    if (ws_size < WS_TOTAL * 4ull) return;

    unsigned* wAg_u = (unsigned*)(ws + WS_WAG);
    unsigned* fwp_u = (unsigned*)(ws + WS_FWP);
    const unsigned short* wAg_h = (const unsigned short*)wAg_u;
    const unsigned short* fwp_h = (const unsigned short*)fwp_u;
    float* sc1     = ws + WS_SC1;
    float* sh1     = ws + WS_SH1;
    float* sck     = ws + WS_SCK;
    float* shk     = ws + WS_SHK;
    float* G       = ws + WS_G;
    float* C       = ws + WS_C;
    float* Wnew    = ws + WS_WNEW;
    float* qpart   = ws + WS_BN1PART;
    float* bn2part = ws + WS_BN2PART;
    float* Phi     = ws + WS_PHI;
    float* fpart   = ws + WS_FPART;
    float* Gpart   = ws + WS_GPART;
    float* Cpart   = ws + WS_CPART;
    float* pmax    = ws + WS_PMAX;

    kWk1<<<1076, TPB, 0, stream>>>(w2, fw, x, wAg_u, fwp_u, qpart);
    k2_bn1_final<<<1, 64, 0, stream>>>(qpart, w1, g1, be1, sc1, sh1);
    k34_conv2_mfma<<<4096, TPB, 0, stream>>>(x, w1, sc1, sh1, wAg_h, b2, pmax, bn2part);
    k5_bn2_final<<<64, TPB, 0, stream>>>(bn2part, g2, be2, sck, shk);
    k7_fc1_mfma<<<448, TPB, 0, stream>>>(pmax, sck, shk, fwp_h, fpart);
    k7b_relu<<<2048, TPB, 0, stream>>>(fpart, fb, Phi);
    k8_gram<<<128, TPB, 0, stream>>>(Phi, y, Gpart, Cpart);
    k9_reduce<<<71, TPB, 0, stream>>>(Gpart, Cpart, G, C);
    k10_solve<<<1, TPB, 0, stream>>>(G, C, W0, Wnew);
    k11_out<<<160, TPB, 0, stream>>>(Phi, Wnew, out);
}

// Round 14
// 344.351 us; speedup vs baseline: 1.1981x; 1.0040x over previous
//
#include <hip/hip_runtime.h>
#include <math.h>

#define TPB 256
#define EPSBN 1e-5f
#define PW 16

typedef __attribute__((ext_vector_type(8))) short bf8v;   // 8 x bf16 (4 VGPR)
typedef __attribute__((ext_vector_type(4))) float f4v;    // MFMA acc

static __device__ __forceinline__ unsigned short f2bf(float f) {
    union { float f; unsigned u; } v; v.f = f;
    unsigned r = v.u + 0x7fffu + ((v.u >> 16) & 1u);
    return (unsigned short)(r >> 16);
}
// HW packed f32->bf16 convert (RNE, same rounding as f2bf); 1 inst replaces ~8.
static __device__ __forceinline__ unsigned cvt_pk_bf16(float lo, float hi) {
    unsigned r;
    asm("v_cvt_pk_bf16_f32 %0, %1, %2" : "=v"(r) : "v"(lo), "v"(hi));
    return r;
}
static __device__ __forceinline__ unsigned short cvt1_bf16(float v) {
    return (unsigned short)cvt_pk_bf16(v, v);
}
// broadcast-from-lane via v_readlane (VALU, ~8cy) instead of ds_bpermute (~120cy)
static __device__ __forceinline__ float rdl(float v, int l) {
    return __int_as_float(__builtin_amdgcn_readlane(__float_as_int(v), l));
}

// ---- workspace layout (float element offsets); total 26,865,664 floats (~107.5 MB) ----
// r25: ex-pminh region (WS_FPART2, 6.4M floats, unused since r15) now holds the
// second half of k7's 14-way K-split partials (needs 7*524288 = 3.67M).
#define WS_WAG      0u
#define WS_FWP      9216u
#define WS_SC1      209920u
#define WS_SH1      209952u
#define WS_SCK      209984u
#define WS_SHK      213120u
#define WS_G        216256u
#define WS_C        232897u
#define WS_WNEW     234187u
#define WS_BN1PART  235520u
#define WS_BN2PART  497664u
#define WS_PHI      1021952u
#define WS_FPART    1550336u
#define WS_GPART    5220352u
#define WS_CPART    7399936u
#define WS_PMAX     7598080u
#define WS_FPART2   20443136u
#define WS_TOTAL    26865664ull

// kWk1: fused weight-pack + BN1-stats (independent input-only kernels; saves a launch).
__global__ __launch_bounds__(TPB) void kWk1(const float* __restrict__ w2,
                                            const float* __restrict__ fw,
                                            const float* __restrict__ x,
                                            unsigned* __restrict__ wAg_u,
                                            unsigned* __restrict__ fwp_u,
                                            float* __restrict__ qpart) {
    __shared__ float xs[900];
    __shared__ float red[4][54];
    if (blockIdx.x < 820) {
        int e = blockIdx.x * TPB + threadIdx.x;
        if (e < 9216) {
            int jj = e & 3, lane = (e >> 2) & 63, mt = (e >> 8) & 3, t = e >> 10;
            int j0 = jj * 2;
            int co = mt * 16 + (lane & 15);
            int ci = (lane >> 4) * 8 + j0;
            unsigned h0 = f2bf(w2[(co * 32 + ci) * 9 + t]);
            unsigned h1 = f2bf(w2[(co * 32 + ci + 1) * 9 + t]);
            wAg_u[e] = h0 | (h1 << 16);
        } else if (e < 9216 + 200704) {
            int f = e - 9216;
            int kk = (f & 15) * 2, n = (f >> 4) & 127, g = f >> 11;
            unsigned h0 = f2bf(fw[n * 3136 + g * 32 + kk]);
            unsigned h1 = f2bf(fw[n * 3136 + g * 32 + kk + 1]);
            fwp_u[f] = h0 | (h1 << 16);
        }
        return;
    }
    int bid = blockIdx.x - 820;
    int tid = threadIdx.x;
    float acc[54];
#pragma unroll
    for (int i = 0; i < 54; ++i) acc[i] = 0.f;
    for (int img = 0; img < 16; ++img) {
        int n = bid * 16 + img;
        for (int i = tid; i < 900; i += TPB) xs[i] = 0.f;
        __syncthreads();
        for (int i = tid; i < 784; i += TPB) {
            int r = i / 28, c = i % 28;
            xs[(r + 1) * 30 + (c + 1)] = x[n * 784 + i];
        }
        __syncthreads();
        for (int p = tid; p < 784; p += TPB) {
            int oy = p / 28, ox = p % 28;
            float v[9];
#pragma unroll
            for (int t = 0; t < 9; ++t) v[t] = xs[(oy + t / 3) * 30 + ox + (t % 3)];
            int qi = 9;
#pragma unroll
            for (int t = 0; t < 9; ++t) {
                acc[t] += v[t];
#pragma unroll
                for (int u = t; u < 9; ++u) acc[qi++] += v[t] * v[u];
            }
        }
        __syncthreads();
    }
    int wv = tid >> 6, lane = tid & 63;
#pragma unroll
    for (int i = 0; i < 54; ++i) {
        float s = acc[i];
        for (int d = 1; d < 64; d <<= 1) s += __shfl_xor(s, d);
        if (lane == 0) red[wv][i] = s;
    }
    __syncthreads();
    if (tid < 54)
        qpart[bid * 54 + tid] = red[0][tid] + red[1][tid] + red[2][tid] + red[3][tid];
}

// k2: reduce qpart -> S,Q; per-channel mean/var from 9x9 moments (bias cancels in BN)
__global__ __launch_bounds__(64) void k2_bn1_final(const float* __restrict__ qpart,
                                                   const float* __restrict__ w1,
                                                   const float* __restrict__ g1,
                                                   const float* __restrict__ be1,
                                                   float* __restrict__ sc1,
                                                   float* __restrict__ sh1) {
    __shared__ float T[54];
    int tid = threadIdx.x;
    if (tid < 54) {
        float s = 0.f;
#pragma unroll 8
        for (int b = 0; b < 256; ++b) s += qpart[b * 54 + tid];
        T[tid] = s;
    }
    __syncthreads();
    if (tid < 32) {
        const float inv = 1.f / (4096.f * 784.f);
        float w[9];
#pragma unroll
        for (int t = 0; t < 9; ++t) w[t] = w1[tid * 9 + t];
        float mean = 0.f;
#pragma unroll
        for (int t = 0; t < 9; ++t) mean += w[t] * T[t];
        mean *= inv;
        float ex2 = 0.f;
        int qi = 9;
#pragma unroll
        for (int t = 0; t < 9; ++t)
#pragma unroll
            for (int u = t; u < 9; ++u) {
                float c = w[t] * w[u] * T[qi++];
                ex2 += (u == t) ? c : 2.f * c;
            }
        ex2 *= inv;
        float var = ex2 - mean * mean;
        float a = g1[tid] * rsqrtf(var + EPSBN);
        sc1[tid] = a;
        sh1[tid] = be1[tid] - a * mean;
    }
}

// k34: per image: conv1+BN1+ReLU+pool -> LDS bf16 -> conv2 via MFMA -> stats + pooled max
// r24 bf16 slab CONFIRMED: 110 -> 101.7 µs, occupancy 30->38%, absmax bit-equal.
// k34 ledger closed — every remaining lever breaks a verified constraint
// (barrier count r21, 16B alignment r22, spill-free regs r18). Do not touch.
__global__ __launch_bounds__(TPB) void k34_conv2_mfma(const float* __restrict__ x,
                                                      const float* __restrict__ w1,
                                                      const float* __restrict__ sc1,
                                                      const float* __restrict__ sh1,
                                                      const unsigned short* __restrict__ wAg,
                                                      const float* __restrict__ b2,
                                                      float* __restrict__ pmax,
                                                      float* __restrict__ bn2part) {
    // LDS layout (ushort units): slab bf16[32][204] @0 (xs aliases), h1 @6528
    // (256 paddr x 80B), wred fp32[512] @16768, b2l fp32[64] @17792.
    __shared__ __align__(16) unsigned short SH[17920];
    unsigned short* slabh = SH;
    float* xs   = (float*)SH;                     // alias slab (dead then)
    unsigned* H1u = (unsigned*)(SH + 6528);
    const char* h1hiB = (const char*)(SH + 6528);
    float* wred = (float*)(SH + 16768);
    float* b2l  = (float*)(SH + 17792);

    int tid = threadIdx.x;
    int n   = blockIdx.x;
    int lane = tid & 63, wv = tid >> 6, quad = lane >> 4, l15 = lane & 15;

    for (int i = tid; i < 5120; i += TPB) H1u[i] = 0u;
    for (int i = tid; i < 900; i += TPB) xs[i] = 0.f;
    if (tid < 64) b2l[tid] = b2[tid];
    __syncthreads();
    for (int i = tid; i < 784; i += TPB) {
        int r = i / 28, c = i % 28;
        xs[(r + 1) * 30 + (c + 1)] = x[n * 784 + i];
    }
    __syncthreads();

    if (tid < 196) {
        int py = tid / 14, px = tid % 14;
        int paddr = (py + 1) * 16 + (px + 1);
        float patch[4][4];
#pragma unroll
        for (int r = 0; r < 4; ++r)
#pragma unroll
            for (int c = 0; c < 4; ++c) patch[r][c] = xs[(2 * py + r) * 30 + 2 * px + c];
        unsigned hw0 = 0;
#pragma unroll
        for (int cp = 0; cp < 16; ++cp) {           // channel pair (2cp, 2cp+1)
            float mx0 = -1e30f, mx1 = -1e30f;
#pragma unroll
            for (int sy = 0; sy < 2; ++sy)
#pragma unroll
                for (int sx = 0; sx < 2; ++sx) {
                    float v0 = 0.f, v1 = 0.f;
#pragma unroll
                    for (int t = 0; t < 9; ++t) {
                        float pv = patch[sy + t / 3][sx + t % 3];
                        v0 += pv * w1[(2 * cp) * 9 + t];
                        v1 += pv * w1[(2 * cp + 1) * 9 + t];
                    }
                    mx0 = fmaxf(mx0, v0);
                    mx1 = fmaxf(mx1, v1);
                }
            float r0 = fmaxf(sc1[2 * cp] * mx0 + sh1[2 * cp], 0.f);
            float r1 = fmaxf(sc1[2 * cp + 1] * mx1 + sh1[2 * cp + 1], 0.f);
            unsigned hp = cvt_pk_bf16(r0, r1);      // lo = ch 2cp, hi = ch 2cp+1
            if ((cp & 1) == 0) hw0 = hp;
            else *(uint2*)(H1u + paddr * 20 + (cp - 1)) = make_uint2(hw0, hp);
        }
    }
    __syncthreads();

    int baseB[4];
    float vmsk[4];
    int pvals[4];
#pragma unroll
    for (int i = 0; i < 4; ++i) {
        int nt = wv + 4 * i;
        int p  = nt * 16 + l15;
        vmsk[i]  = (nt <= 12 && p < 196) ? 1.f : 0.f;
        pvals[i] = p;
        int pc = p < 196 ? p : 195;
        int py = pc / 14, px = pc - py * 14;
        baseB[i] = ((py + 1) * 16 + (px + 1)) * 80 + quad * 16;
    }

    int pk = tid >> 3, pj = tid & 7;   // pool decomposition

#pragma unroll
    for (int c2 = 0; c2 < 2; ++c2) {
        // --- MFMA for channel half c2 (mt = c2*2 + mtl), acc = 32 regs ---
        f4v acc2[4][2];
#pragma unroll
        for (int i = 0; i < 4; ++i)
#pragma unroll
            for (int mtl = 0; mtl < 2; ++mtl) acc2[i][mtl] = (f4v){0.f, 0.f, 0.f, 0.f};
#pragma unroll
        for (int t = 0; t < 9; ++t) {
            const int toff = ((t / 3) - 1) * 1280 + ((t % 3) - 1) * 80;
            bf8v wa0 = *(const bf8v*)(wAg + ((t * 4 + c2 * 2 + 0) * 64 + lane) * 8);
            bf8v wa1 = *(const bf8v*)(wAg + ((t * 4 + c2 * 2 + 1) * 64 + lane) * 8);
#pragma unroll
            for (int i = 0; i < 4; ++i) {
                if (wv + 4 * i > 12) continue;
                bf8v bhi = *(const bf8v*)(h1hiB + baseB[i] + toff);
                acc2[i][0] = __builtin_amdgcn_mfma_f32_16x16x32_bf16(wa0, bhi, acc2[i][0], 0, 0, 0);
                acc2[i][1] = __builtin_amdgcn_mfma_f32_16x16x32_bf16(wa1, bhi, acc2[i][1], 0, 0, 0);
            }
        }
        // --- bias ---
#pragma unroll
        for (int mtl = 0; mtl < 2; ++mtl) {
            float bb[4];
#pragma unroll
            for (int r = 0; r < 4; ++r) bb[r] = b2l[(c2 * 2 + mtl) * 16 + quad * 4 + r];
#pragma unroll
            for (int i = 0; i < 4; ++i)
#pragma unroll
                for (int r = 0; r < 4; ++r) acc2[i][mtl][r] += bb[r];
        }
        // --- stats for this half ---
        float ss[2][4], qq[2][4];
#pragma unroll
        for (int mtl = 0; mtl < 2; ++mtl)
#pragma unroll
            for (int r = 0; r < 4; ++r) { ss[mtl][r] = 0.f; qq[mtl][r] = 0.f; }
#pragma unroll
        for (int i = 0; i < 4; ++i) {
            if (wv + 4 * i > 12) continue;
#pragma unroll
            for (int mtl = 0; mtl < 2; ++mtl)
#pragma unroll
                for (int r = 0; r < 4; ++r) {
                    float v = acc2[i][mtl][r] * vmsk[i];
                    ss[mtl][r] += v;
                    qq[mtl][r] += v * v;
                }
        }
#pragma unroll
        for (int d = 1; d < 16; d <<= 1)
#pragma unroll
            for (int mtl = 0; mtl < 2; ++mtl)
#pragma unroll
                for (int r = 0; r < 4; ++r) {
                    ss[mtl][r] += __shfl_xor(ss[mtl][r], d);
                    qq[mtl][r] += __shfl_xor(qq[mtl][r], d);
                }
        if (l15 == 0) {
#pragma unroll
            for (int mtl = 0; mtl < 2; ++mtl)
#pragma unroll
                for (int r = 0; r < 4; ++r) {
                    int co = (c2 * 2 + mtl) * 16 + quad * 4 + r;
                    wred[wv * 64 + co]       = ss[mtl][r];
                    wred[256 + wv * 64 + co] = qq[mtl][r];
                }
        }
        // --- slab write, bf16 (separate LDS region; h1 intact across halves) ---
#pragma unroll
        for (int mtl = 0; mtl < 2; ++mtl) {
#pragma unroll
            for (int i = 0; i < 4; ++i) {
                if (wv + 4 * i > 12) continue;
                if (vmsk[i] > 0.f) {
#pragma unroll
                    for (int r = 0; r < 4; ++r)
                        slabh[(mtl * 16 + quad * 4 + r) * 204 + pvals[i]] =
                            cvt1_bf16(acc2[i][mtl][r]);
                }
            }
        }
        __syncthreads();
        // --- pool for this half (division-free; bf16 pairs via shift/mask) ---
        {
            int j7 = (pj >= 7) ? 1 : 0;
            int qy = j7, qx = pj - 7 * j7;
            size_t obase = (size_t)n * 3136 + (c2 * 32 + pk) * 49;
            const unsigned short* srow = slabh + pk * 204;
#pragma unroll
            for (int it = 0; it < 7; ++it) {
                int pp = pj + (it << 3);
                if (pp < 49) {
                    int p0 = qy * 28 + qx * 2;           // always even -> 4B aligned
                    unsigned a01 = *(const unsigned*)(srow + p0);
                    unsigned a23 = *(const unsigned*)(srow + p0 + 14);
                    float v00 = __uint_as_float(a01 << 16);
                    float v01 = __uint_as_float(a01 & 0xffff0000u);
                    float v10 = __uint_as_float(a23 << 16);
                    float v11 = __uint_as_float(a23 & 0xffff0000u);
                    float mx = fmaxf(fmaxf(v00, v01), fmaxf(v10, v11));
                    pmax[obase + pp] = mx;
                }
                qx += 1; qy += 1;
                if (qx >= 7) { qx -= 7; qy += 1; }
            }
        }
        __syncthreads();   // slab reuse + wred visibility for the final read
    }
    // --- bn2part from wred (all 64 co written across both halves) ---
    if (tid < 64) {
        float s = wred[tid] + wred[64 + tid] + wred[128 + tid] + wred[192 + tid];
        float q = wred[256 + tid] + wred[320 + tid] + wred[384 + tid] + wred[448 + tid];
        bn2part[(n * 64 + tid) * 2 + 0] = s;
        bn2part[(n * 64 + tid) * 2 + 1] = q;
    }
}

// k5: finalize bn2 -> expanded per-fc1-k scale/shift arrays (3136 each)
__global__ __launch_bounds__(TPB) void k5_bn2_final(const float* __restrict__ bn2part,
                                                    const float* __restrict__ g2,
                                                    const float* __restrict__ be2,
                                                    float* __restrict__ sck,
                                                    float* __restrict__ shk) {
    __shared__ float red[TPB][2];
    __shared__ float sAC[2];
    int tid = threadIdx.x, co = blockIdx.x;
    float s = 0.f, q = 0.f;
    for (int i = tid; i < 4096; i += TPB) {
        s += bn2part[(i * 64 + co) * 2 + 0];
        q += bn2part[(i * 64 + co) * 2 + 1];
    }
    red[tid][0] = s; red[tid][1] = q;
    __syncthreads();
    for (int off = TPB / 2; off; off >>= 1) {
        if (tid < off) { red[tid][0] += red[tid + off][0]; red[tid][1] += red[tid + off][1]; }
        __syncthreads();
    }
    if (tid == 0) {
        const float count = 4096.f * 196.f;
        float mean = red[0][0] / count;
        float var  = red[0][1] / count - mean * mean;
        float a    = g2[co] * rsqrtf(var + EPSBN);
        sAC[0] = a;
        sAC[1] = be2[co] - a * mean;
    }
    __syncthreads();
    if (tid < 49) {
        sck[co * 49 + tid] = sAC[0];
        shk[co * 49 + tid] = sAC[1];
    }
}

// k7: fc1 via MFMA. BN2+ReLU fused into A-staging.
// r25: K-split 7 -> 14. Theory: k7 was GRID-limited (448 blocks = 1.75/CU, a
// third of CUs running one 4-wave block) with 28 serial barriers/block — the
// barrier-dominated latency pattern r21 proved costly. Now 896 blocks = 3.5/CU
// (2x waves to hide each barrier) and 7 iters -> 14 barriers/block. Second set
// of 7 partials lives in the free ex-pminh region. MFMA count unchanged.
__global__ __launch_bounds__(TPB) void k7_fc1_mfma(const float* __restrict__ pmax,
                                                   const float* __restrict__ sck,
                                                   const float* __restrict__ shk,
                                                   const unsigned short* __restrict__ fwp,
                                                   float* __restrict__ fpartA,
                                                   float* __restrict__ fpartB) {
    __shared__ __align__(16) unsigned short K7S[7680];   // Ahi[64*40] Bsl[128*40]
    unsigned short* Ahi = K7S;
    unsigned short* Bsl = K7S + 2560;
    int tid = threadIdx.x;
    int mt = blockIdx.x & 63, ks = blockIdx.x >> 6;      // ks in [0,14)
    int m0 = mt * 64;
    int lane = tid & 63, wv = tid >> 6, quad = lane >> 4, l15 = lane & 15;
    f4v acc[8];
#pragma unroll
    for (int i = 0; i < 8; ++i) acc[i] = (f4v){0.f, 0.f, 0.f, 0.f};

    for (int it = 0; it < 7; ++it) {
        int g  = ks * 7 + it;
        int k0 = g * 32;
#pragma unroll
        for (int i = 0; i < 8; ++i) {
            int e  = tid + i * TPB;
            int r  = e >> 5, kk = e & 31;
            int k  = k0 + kk;
            float a = sck[k], c = shk[k];
            size_t src = (size_t)(m0 + r) * 3136 + k;
            float v = fmaxf(a * pmax[src] + c, 0.f);
            Ahi[r * 40 + kk] = f2bf(v);
        }
        {
            const uint4* src = (const uint4*)(fwp + (size_t)g * 4096 + tid * 16);
            uint4 w0 = src[0], w1 = src[1];
            int n = tid >> 1, kk0 = (tid & 1) * 16;
            *(uint4*)(Bsl + n * 40 + kk0)     = w0;
            *(uint4*)(Bsl + n * 40 + kk0 + 8) = w1;
        }
        __syncthreads();
        bf8v ahi = *(const bf8v*)(Ahi + (wv * 16 + l15) * 40 + quad * 8);
#pragma unroll
        for (int nt = 0; nt < 8; ++nt) {
            bf8v b = *(const bf8v*)(Bsl + (nt * 16 + l15) * 40 + quad * 8);
            acc[nt] = __builtin_amdgcn_mfma_f32_16x16x32_bf16(ahi, b, acc[nt], 0, 0, 0);
        }
        __syncthreads();
    }
    float* outp = (ks < 7) ? (fpartA + (size_t)ks * 524288)
                           : (fpartB + (size_t)(ks - 7) * 524288);
#pragma unroll
    for (int nt = 0; nt < 8; ++nt)
#pragma unroll
        for (int r = 0; r < 4; ++r) {
            int m = m0 + wv * 16 + quad * 4 + r;
            int nn = nt * 16 + l15;
            outp[m * 128 + nn] = acc[nt][r];
        }
}

// k7b: reduce 14 K-split partials + bias + ReLU -> Phi [4096][129]
__global__ __launch_bounds__(TPB) void k7b_relu(const float* __restrict__ fpartA,
                                                const float* __restrict__ fpartB,
                                                const float* __restrict__ fb,
                                                float* __restrict__ Phi) {
    int e = blockIdx.x * TPB + threadIdx.x;
    int n = e >> 7, f = e & 127;
    float s = fb[f];
#pragma unroll
    for (int c = 0; c < 7; ++c) s += fpartA[(size_t)c * 524288 + e];
#pragma unroll
    for (int c = 0; c < 7; ++c) s += fpartB[(size_t)c * 524288 + e];
    Phi[n * 129 + f] = fmaxf(s, 0.f);
    if (f == 0) Phi[n * 129 + 128] = 1.0f;
}

// k8: partial Gram + C, 32-sample chunks
__global__ __launch_bounds__(TPB) void k8_gram(const float* __restrict__ Phi,
                                               const float* __restrict__ y,
                                               float* __restrict__ Gpart,
                                               float* __restrict__ Cpart) {
    __shared__ __align__(16) float ph[32 * 132];
    __shared__ __align__(16) float yl[32 * 12];
    int tid = threadIdx.x;
    int cB  = blockIdx.x;
    int n0  = cB * 32;
    for (int i = tid; i < 32 * 132; i += TPB) ph[i] = 0.f;
    for (int i = tid; i < 32 * 12; i += TPB) yl[i] = 0.f;
    __syncthreads();
    for (int i = tid; i < 32 * 129; i += TPB) {
        int r = i / 129, d = i % 129;
        ph[r * 132 + d] = Phi[(n0 + r) * 129 + d];
    }
    for (int i = tid; i < 320; i += TPB) {
        int r = i / 10, j = i % 10;
        yl[r * 12 + j] = y[(n0 + r) * 10 + j];
    }
    __syncthreads();
    for (int g = tid; g < 129 * 33; g += TPB) {
        int i = g / 33, j0 = (g % 33) * 4;
        float4 s = make_float4(0.f, 0.f, 0.f, 0.f);
        for (int r = 0; r < 32; ++r) {
            float  vi = ph[r * 132 + i];
            float4 vj = *(const float4*)&ph[r * 132 + j0];
            s.x += vi * vj.x; s.y += vi * vj.y; s.z += vi * vj.z; s.w += vi * vj.w;
        }
        *(float4*)&Gpart[(size_t)cB * 17028 + i * 132 + j0] = s;
    }
    for (int g = tid; g < 129 * 3; g += TPB) {
        int i = g / 3, j0 = (g % 3) * 4;
        float4 s = make_float4(0.f, 0.f, 0.f, 0.f);
        for (int r = 0; r < 32; ++r) {
            float  vi = ph[r * 132 + i];
            float4 vj = *(const float4*)&yl[r * 12 + j0];
            s.x += vi * vj.x; s.y += vi * vj.y; s.z += vi * vj.z; s.w += vi * vj.w;
        }
        *(float4*)&Cpart[(size_t)cB * 1548 + i * 12 + j0] = s;
    }
}

// k9: reduce partials -> G [129*129], C [129*10]
__global__ __launch_bounds__(TPB) void k9_reduce(const float* __restrict__ Gpart,
                                                 const float* __restrict__ Cpart,
                                                 float* __restrict__ G,
                                                 float* __restrict__ C) {
    int e = blockIdx.x * TPB + threadIdx.x;
    if (e < 16641) {
        int i = e / 129, j = e % 129;
        float s = 0.f;
        for (int c = 0; c < 128; ++c) s += Gpart[(size_t)c * 17028 + i * 132 + j];
        G[e] = s;
    } else if (e < 16641 + 1290) {
        int e2 = e - 16641;
        int i = e2 / 10, j = e2 % 10;
        float s = 0.f;
        for (int c = 0; c < 128; ++c) s += Cpart[(size_t)c * 1548 + i * 12 + j];
        C[e2] = s;
    }
}

// k10: solve (I+G) W = W0 + C. Gauss-Jordan with fully-diagonalized panels (r16).
// Confirmed win: 145 -> ~60 (inferred from total delta). Do not touch.
__global__ __launch_bounds__(TPB) void k10_solve(const float* __restrict__ G,
                                                 const float* __restrict__ C,
                                                 const float* __restrict__ W0,
                                                 float* __restrict__ Wnew) {
    __shared__ __align__(16) float M[129 * 140];
    __shared__ __align__(16) float LpT[PW * 116];   // [k][compact row], 113 used
    __shared__ float L11s[PW * 16];                 // L11s[m*16+k] = L11[k][m], m<k
    __shared__ float invD[129];
    __shared__ float x128s[10];
    int tid = threadIdx.x;
    int lane = tid & 63, wv = tid >> 6;
    for (int e = tid; e < 129 * 129; e += TPB) {
        int i = e / 129, j = e % 129;
        M[i * 140 + j] = G[e] + (i == j ? 1.f : 0.f);
    }
    for (int i = tid; i < 129; i += TPB) M[i * 140 + 129] = 0.f;
    for (int e = tid; e < 1290; e += TPB) {
        int i = e / 10, c = e % 10;
        M[i * 140 + 130 + c] = W0[e] + C[e];
    }
    __syncthreads();

    for (int k0 = 0; k0 < 128; k0 += PW) {
        const int kend = k0 + PW;
        // --- A: 16x16 LU in registers (wave 0, lanes 0..15), readlane broadcasts ---
        if (wv == 0) {
            bool act = lane < PW;
            int r  = k0 + lane;
            int rc = act ? r : k0;
            float u[PW], Lr[PW];
#pragma unroll
            for (int j = 0; j < PW; ++j) u[j] = M[rc * 140 + k0 + j];
            float dval = u[0];
#pragma unroll
            for (int k = 0; k < PW; ++k) {
                if (lane == k) dval = u[k];
                float piv = rdl(u[k], k);
                float f   = u[k] * __builtin_amdgcn_rcpf(piv);
                float fm  = (act && lane > k) ? f : 0.f;
                Lr[k] = fm;
#pragma unroll
                for (int j = 0; j < PW; ++j)
                    if (j > k) u[j] -= fm * rdl(u[j], k);
            }
            if (act) {
#pragma unroll
                for (int j = 0; j < PW; ++j)
                    if (j >= lane) M[r * 140 + k0 + j] = u[j];   // U11 incl diag
#pragma unroll
                for (int k = 0; k < PW; ++k)
                    if (k < lane) L11s[k * 16 + lane] = Lr[k];   // L11[lane][k]
                invD[r] = __builtin_amdgcn_rcpf(dval);
            }
        }
        __syncthreads();
        if (tid < 128) {
            // --- B (waves 0-1): chain-free coefficients vs diagonalized panel ---
            int cidx = tid;                      // compact off-panel row index
            if (cidx < 113) {
                int r = cidx < k0 ? cidx : cidx + PW;
                float4 a4[4];
#pragma unroll
                for (int q = 0; q < 4; ++q) a4[q] = *(const float4*)&M[r * 140 + k0 + q * 4];
                float a[PW];
#pragma unroll
                for (int q = 0; q < 4; ++q) {
                    a[q * 4 + 0] = a4[q].x; a[q * 4 + 1] = a4[q].y;
                    a[q * 4 + 2] = a4[q].z; a[q * 4 + 3] = a4[q].w;
                }
#pragma unroll
                for (int k = 0; k < PW; ++k)
                    LpT[k * 116 + cidx] = a[k] * invD[k0 + k];
            }
        } else {
            // --- C (waves 2-3): within-panel Jordan on trailing cols (incl RHS) ---
            int j = kend + (tid - 128);
            if (j < 140) {
                float yv[PW];
#pragma unroll
                for (int kk = 0; kk < PW; ++kk) {
                    float v = M[(k0 + kk) * 140 + j];
#pragma unroll
                    for (int m = 0; m < PW; ++m)
                        if (m < kk) v -= L11s[m * 16 + kk] * yv[m];
                    yv[kk] = v;
                }
                float xv[PW];
#pragma unroll
                for (int kk = PW - 1; kk >= 0; --kk) {
                    float v = yv[kk];
#pragma unroll
                    for (int m = 0; m < PW; ++m)
                        if (m > kk) v -= M[(k0 + kk) * 140 + k0 + m] * xv[m];
                    M[(k0 + kk) * 140 + j] = v;       // T = D * A11^{-1} * col
                    xv[kk] = v * invD[k0 + kk];
                }
            }
        }
        __syncthreads();
        // --- D: rank-16 update of ALL 113 off-panel rows, trailing cols ---
        const int Jn = 140 - kend;
        const int nrt = 29, nct = Jn >> 2;       // 113 rows -> 29 4-row tiles
        for (int t = tid; t < nrt * nct; t += TPB) {
            int tr = t % nrt, tc = t / nrt;
            int c0 = tr * 4;
            int j0 = kend + tc * 4;
            float4 s0 = {0, 0, 0, 0}, s1 = {0, 0, 0, 0}, s2 = {0, 0, 0, 0}, s3 = {0, 0, 0, 0};
#pragma unroll
            for (int kk = 0; kk < PW; ++kk) {
                float4 L4 = *(const float4*)&LpT[kk * 116 + c0];
                float4 U4 = *(const float4*)&M[(k0 + kk) * 140 + j0];
                s0.x += L4.x * U4.x; s0.y += L4.x * U4.y; s0.z += L4.x * U4.z; s0.w += L4.x * U4.w;
                s1.x += L4.y * U4.x; s1.y += L4.y * U4.y; s1.z += L4.y * U4.z; s1.w += L4.y * U4.w;
                s2.x += L4.z * U4.x; s2.y += L4.z * U4.y; s2.z += L4.z * U4.z; s2.w += L4.z * U4.w;
                s3.x += L4.w * U4.x; s3.y += L4.w * U4.y; s3.z += L4.w * U4.z; s3.w += L4.w * U4.w;
            }
            float4 sv[4] = {s0, s1, s2, s3};
#pragma unroll
            for (int i = 0; i < 4; ++i) {
                int cidx = c0 + i;
                if (cidx < 113) {
                    int r = cidx < k0 ? cidx : cidx + PW;
                    float4 mv = *(const float4*)&M[r * 140 + j0];
                    mv.x -= sv[i].x; mv.y -= sv[i].y; mv.z -= sv[i].z; mv.w -= sv[i].w;
                    *(float4*)&M[r * 140 + j0] = mv;
                }
            }
        }
        __syncthreads();
    }
    // --- extraction: rows are diagonal + col128 + RHS; no back-substitution ---
    if (tid == 0) {
        float i128 = __builtin_amdgcn_rcpf(M[128 * 140 + 128]);
#pragma unroll
        for (int c = 0; c < 10; ++c) x128s[c] = M[128 * 140 + 130 + c] * i128;
    }
    __syncthreads();
    if (tid < 128) {
        int r = tid;
        float m128 = M[r * 140 + 128];
        float idr  = invD[r];
#pragma unroll
        for (int c = 0; c < 10; ++c)
            Wnew[r * 10 + c] = (M[r * 140 + 130 + c] - m128 * x128s[c]) * idr;
    } else if (tid == 128) {
#pragma unroll
        for (int c = 0; c < 10; ++c) Wnew[1280 + c] = x128s[c];
    }
}

// k11: out = Phi @ Wnew  ([4096][10])
__global__ __launch_bounds__(TPB) void k11_out(const float* __restrict__ Phi,
                                               const float* __restrict__ Wnew,
                                               float* __restrict__ out) {
    __shared__ float Wl[1290];
    int tid = threadIdx.x;
    for (int i = tid; i < 1290; i += TPB) Wl[i] = Wnew[i];
    __syncthreads();
    int idx = blockIdx.x * TPB + tid;
    int n = idx / 10, j = idx % 10;
    float s = 0.f;
    for (int d = 0; d < 129; ++d) s += Phi[n * 129 + d] * Wl[d * 10 + j];
    out[idx] = s;
}

extern "C" void kernel_launch(void* const* d_in, const int* in_sizes, int n_in,
                              void* d_out, int out_size, void* d_ws, size_t ws_size,
                              hipStream_t stream) {
    const float* x   = (const float*)d_in[0];
    const float* y   = (const float*)d_in[1];
    const float* w1  = (const float*)d_in[2];
    const float* g1  = (const float*)d_in[4];
    const float* be1 = (const float*)d_in[5];
    const float* w2  = (const float*)d_in[6];
    const float* b2  = (const float*)d_in[7];
    const float* g2  = (const float*)d_in[8];
    const float* be2 = (const float*)d_in[9];
    const float* fw  = (const float*)d_in[10];
    const float* fb  = (const float*)d_in[11];
    const float* W0  = (const float*)d_in[12];
    float* out = (float*)d_out;
    float* ws  = (float*)d_ws;
    if (ws_size < WS_TOTAL * 4ull) return;

    unsigned* wAg_u = (unsigned*)(ws + WS_WAG);
    unsigned* fwp_u = (unsigned*)(ws + WS_FWP);
    const unsigned short* wAg_h = (const unsigned short*)wAg_u;
    const unsigned short* fwp_h = (const unsigned short*)fwp_u;
    float* sc1     = ws + WS_SC1;
    float* sh1     = ws + WS_SH1;
    float* sck     = ws + WS_SCK;
    float* shk     = ws + WS_SHK;
    float* G       = ws + WS_G;
    float* C       = ws + WS_C;
    float* Wnew    = ws + WS_WNEW;
    float* qpart   = ws + WS_BN1PART;
    float* bn2part = ws + WS_BN2PART;
    float* Phi     = ws + WS_PHI;
    float* fpartA  = ws + WS_FPART;
    float* fpartB  = ws + WS_FPART2;
    float* Gpart   = ws + WS_GPART;
    float* Cpart   = ws + WS_CPART;
    float* pmax    = ws + WS_PMAX;

    kWk1<<<1076, TPB, 0, stream>>>(w2, fw, x, wAg_u, fwp_u, qpart);
    k2_bn1_final<<<1, 64, 0, stream>>>(qpart, w1, g1, be1, sc1, sh1);
    k34_conv2_mfma<<<4096, TPB, 0, stream>>>(x, w1, sc1, sh1, wAg_h, b2, pmax, bn2part);
    k5_bn2_final<<<64, TPB, 0, stream>>>(bn2part, g2, be2, sck, shk);
    k7_fc1_mfma<<<896, TPB, 0, stream>>>(pmax, sck, shk, fwp_h, fpartA, fpartB);
    k7b_relu<<<2048, TPB, 0, stream>>>(fpartA, fpartB, fb, Phi);
    k8_gram<<<128, TPB, 0, stream>>>(Phi, y, Gpart, Cpart);
    k9_reduce<<<71, TPB, 0, stream>>>(Gpart, Cpart, G, C);
    k10_solve<<<1, TPB, 0, stream>>>(G, C, W0, Wnew);
    k11_out<<<160, TPB, 0, stream>>>(Phi, Wnew, out);
}

// Round 15
// 338.056 us; speedup vs baseline: 1.2204x; 1.0186x over previous
//
#include <hip/hip_runtime.h>
#include <math.h>

#define TPB 256
#define EPSBN 1e-5f
#define PW 16

typedef __attribute__((ext_vector_type(8))) short bf8v;   // 8 x bf16 (4 VGPR)
typedef __attribute__((ext_vector_type(4))) float f4v;    // MFMA acc

static __device__ __forceinline__ unsigned short f2bf(float f) {
    union { float f; unsigned u; } v; v.f = f;
    unsigned r = v.u + 0x7fffu + ((v.u >> 16) & 1u);
    return (unsigned short)(r >> 16);
}
// HW packed f32->bf16 convert (RNE, same rounding as f2bf); 1 inst replaces ~8.
static __device__ __forceinline__ unsigned cvt_pk_bf16(float lo, float hi) {
    unsigned r;
    asm("v_cvt_pk_bf16_f32 %0, %1, %2" : "=v"(r) : "v"(lo), "v"(hi));
    return r;
}
static __device__ __forceinline__ unsigned short cvt1_bf16(float v) {
    return (unsigned short)cvt_pk_bf16(v, v);
}
// broadcast-from-lane via v_readlane (VALU, ~8cy) instead of ds_bpermute (~120cy)
static __device__ __forceinline__ float rdl(float v, int l) {
    return __int_as_float(__builtin_amdgcn_readlane(__float_as_int(v), l));
}

// ---- workspace layout (float element offsets); total 26,865,664 floats (~107.5 MB) ----
// r26: qpart grows to 512*54 (fits BN1PART region, 262144 floats).
#define WS_WAG      0u
#define WS_FWP      9216u
#define WS_SC1      209920u
#define WS_SH1      209952u
#define WS_SCK      209984u
#define WS_SHK      213120u
#define WS_G        216256u
#define WS_C        232897u
#define WS_WNEW     234187u
#define WS_BN1PART  235520u
#define WS_BN2PART  497664u
#define WS_PHI      1021952u
#define WS_FPART    1550336u
#define WS_GPART    5220352u
#define WS_CPART    7399936u
#define WS_PMAX     7598080u
#define WS_FPART2   20443136u
#define WS_TOTAL    26865664ull

// kWk1: fused weight-pack + BN1-stats.
// r26: stats section 256 -> 512 blocks (1 -> 2 blocks/CU), 8 images each —
// grid-limited fix, same per-element math; qpart now 512 partials.
__global__ __launch_bounds__(TPB) void kWk1(const float* __restrict__ w2,
                                            const float* __restrict__ fw,
                                            const float* __restrict__ x,
                                            unsigned* __restrict__ wAg_u,
                                            unsigned* __restrict__ fwp_u,
                                            float* __restrict__ qpart) {
    __shared__ float xs[900];
    __shared__ float red[4][54];
    if (blockIdx.x < 820) {
        int e = blockIdx.x * TPB + threadIdx.x;
        if (e < 9216) {
            int jj = e & 3, lane = (e >> 2) & 63, mt = (e >> 8) & 3, t = e >> 10;
            int j0 = jj * 2;
            int co = mt * 16 + (lane & 15);
            int ci = (lane >> 4) * 8 + j0;
            unsigned h0 = f2bf(w2[(co * 32 + ci) * 9 + t]);
            unsigned h1 = f2bf(w2[(co * 32 + ci + 1) * 9 + t]);
            wAg_u[e] = h0 | (h1 << 16);
        } else if (e < 9216 + 200704) {
            int f = e - 9216;
            int kk = (f & 15) * 2, n = (f >> 4) & 127, g = f >> 11;
            unsigned h0 = f2bf(fw[n * 3136 + g * 32 + kk]);
            unsigned h1 = f2bf(fw[n * 3136 + g * 32 + kk + 1]);
            fwp_u[f] = h0 | (h1 << 16);
        }
        return;
    }
    int bid = blockIdx.x - 820;                     // 0..511
    int tid = threadIdx.x;
    float acc[54];
#pragma unroll
    for (int i = 0; i < 54; ++i) acc[i] = 0.f;
    for (int img = 0; img < 8; ++img) {
        int n = bid * 8 + img;
        for (int i = tid; i < 900; i += TPB) xs[i] = 0.f;
        __syncthreads();
        for (int i = tid; i < 784; i += TPB) {
            int r = i / 28, c = i % 28;
            xs[(r + 1) * 30 + (c + 1)] = x[n * 784 + i];
        }
        __syncthreads();
        for (int p = tid; p < 784; p += TPB) {
            int oy = p / 28, ox = p % 28;
            float v[9];
#pragma unroll
            for (int t = 0; t < 9; ++t) v[t] = xs[(oy + t / 3) * 30 + ox + (t % 3)];
            int qi = 9;
#pragma unroll
            for (int t = 0; t < 9; ++t) {
                acc[t] += v[t];
#pragma unroll
                for (int u = t; u < 9; ++u) acc[qi++] += v[t] * v[u];
            }
        }
        __syncthreads();
    }
    int wv = tid >> 6, lane = tid & 63;
#pragma unroll
    for (int i = 0; i < 54; ++i) {
        float s = acc[i];
        for (int d = 1; d < 64; d <<= 1) s += __shfl_xor(s, d);
        if (lane == 0) red[wv][i] = s;
    }
    __syncthreads();
    if (tid < 54)
        qpart[bid * 54 + tid] = red[0][tid] + red[1][tid] + red[2][tid] + red[3][tid];
}

// k2: reduce qpart (512 partials) -> S,Q; per-channel mean/var from 9x9 moments
__global__ __launch_bounds__(64) void k2_bn1_final(const float* __restrict__ qpart,
                                                   const float* __restrict__ w1,
                                                   const float* __restrict__ g1,
                                                   const float* __restrict__ be1,
                                                   float* __restrict__ sc1,
                                                   float* __restrict__ sh1) {
    __shared__ float T[54];
    int tid = threadIdx.x;
    if (tid < 54) {
        float s = 0.f;
#pragma unroll 8
        for (int b = 0; b < 512; ++b) s += qpart[b * 54 + tid];
        T[tid] = s;
    }
    __syncthreads();
    if (tid < 32) {
        const float inv = 1.f / (4096.f * 784.f);
        float w[9];
#pragma unroll
        for (int t = 0; t < 9; ++t) w[t] = w1[tid * 9 + t];
        float mean = 0.f;
#pragma unroll
        for (int t = 0; t < 9; ++t) mean += w[t] * T[t];
        mean *= inv;
        float ex2 = 0.f;
        int qi = 9;
#pragma unroll
        for (int t = 0; t < 9; ++t)
#pragma unroll
            for (int u = t; u < 9; ++u) {
                float c = w[t] * w[u] * T[qi++];
                ex2 += (u == t) ? c : 2.f * c;
            }
        ex2 *= inv;
        float var = ex2 - mean * mean;
        float a = g1[tid] * rsqrtf(var + EPSBN);
        sc1[tid] = a;
        sh1[tid] = be1[tid] - a * mean;
    }
}

// k34: per image: conv1+BN1+ReLU+pool -> LDS bf16 -> conv2 via MFMA -> stats + pooled max
// Ledger closed (r24 bf16 slab = final config). Do not touch.
__global__ __launch_bounds__(TPB) void k34_conv2_mfma(const float* __restrict__ x,
                                                      const float* __restrict__ w1,
                                                      const float* __restrict__ sc1,
                                                      const float* __restrict__ sh1,
                                                      const unsigned short* __restrict__ wAg,
                                                      const float* __restrict__ b2,
                                                      float* __restrict__ pmax,
                                                      float* __restrict__ bn2part) {
    __shared__ __align__(16) unsigned short SH[17920];
    unsigned short* slabh = SH;
    float* xs   = (float*)SH;                     // alias slab (dead then)
    unsigned* H1u = (unsigned*)(SH + 6528);
    const char* h1hiB = (const char*)(SH + 6528);
    float* wred = (float*)(SH + 16768);
    float* b2l  = (float*)(SH + 17792);

    int tid = threadIdx.x;
    int n   = blockIdx.x;
    int lane = tid & 63, wv = tid >> 6, quad = lane >> 4, l15 = lane & 15;

    for (int i = tid; i < 5120; i += TPB) H1u[i] = 0u;
    for (int i = tid; i < 900; i += TPB) xs[i] = 0.f;
    if (tid < 64) b2l[tid] = b2[tid];
    __syncthreads();
    for (int i = tid; i < 784; i += TPB) {
        int r = i / 28, c = i % 28;
        xs[(r + 1) * 30 + (c + 1)] = x[n * 784 + i];
    }
    __syncthreads();

    if (tid < 196) {
        int py = tid / 14, px = tid % 14;
        int paddr = (py + 1) * 16 + (px + 1);
        float patch[4][4];
#pragma unroll
        for (int r = 0; r < 4; ++r)
#pragma unroll
            for (int c = 0; c < 4; ++c) patch[r][c] = xs[(2 * py + r) * 30 + 2 * px + c];
        unsigned hw0 = 0;
#pragma unroll
        for (int cp = 0; cp < 16; ++cp) {           // channel pair (2cp, 2cp+1)
            float mx0 = -1e30f, mx1 = -1e30f;
#pragma unroll
            for (int sy = 0; sy < 2; ++sy)
#pragma unroll
                for (int sx = 0; sx < 2; ++sx) {
                    float v0 = 0.f, v1 = 0.f;
#pragma unroll
                    for (int t = 0; t < 9; ++t) {
                        float pv = patch[sy + t / 3][sx + t % 3];
                        v0 += pv * w1[(2 * cp) * 9 + t];
                        v1 += pv * w1[(2 * cp + 1) * 9 + t];
                    }
                    mx0 = fmaxf(mx0, v0);
                    mx1 = fmaxf(mx1, v1);
                }
            float r0 = fmaxf(sc1[2 * cp] * mx0 + sh1[2 * cp], 0.f);
            float r1 = fmaxf(sc1[2 * cp + 1] * mx1 + sh1[2 * cp + 1], 0.f);
            unsigned hp = cvt_pk_bf16(r0, r1);      // lo = ch 2cp, hi = ch 2cp+1
            if ((cp & 1) == 0) hw0 = hp;
            else *(uint2*)(H1u + paddr * 20 + (cp - 1)) = make_uint2(hw0, hp);
        }
    }
    __syncthreads();

    int baseB[4];
    float vmsk[4];
    int pvals[4];
#pragma unroll
    for (int i = 0; i < 4; ++i) {
        int nt = wv + 4 * i;
        int p  = nt * 16 + l15;
        vmsk[i]  = (nt <= 12 && p < 196) ? 1.f : 0.f;
        pvals[i] = p;
        int pc = p < 196 ? p : 195;
        int py = pc / 14, px = pc - py * 14;
        baseB[i] = ((py + 1) * 16 + (px + 1)) * 80 + quad * 16;
    }

    int pk = tid >> 3, pj = tid & 7;   // pool decomposition

#pragma unroll
    for (int c2 = 0; c2 < 2; ++c2) {
        f4v acc2[4][2];
#pragma unroll
        for (int i = 0; i < 4; ++i)
#pragma unroll
            for (int mtl = 0; mtl < 2; ++mtl) acc2[i][mtl] = (f4v){0.f, 0.f, 0.f, 0.f};
#pragma unroll
        for (int t = 0; t < 9; ++t) {
            const int toff = ((t / 3) - 1) * 1280 + ((t % 3) - 1) * 80;
            bf8v wa0 = *(const bf8v*)(wAg + ((t * 4 + c2 * 2 + 0) * 64 + lane) * 8);
            bf8v wa1 = *(const bf8v*)(wAg + ((t * 4 + c2 * 2 + 1) * 64 + lane) * 8);
#pragma unroll
            for (int i = 0; i < 4; ++i) {
                if (wv + 4 * i > 12) continue;
                bf8v bhi = *(const bf8v*)(h1hiB + baseB[i] + toff);
                acc2[i][0] = __builtin_amdgcn_mfma_f32_16x16x32_bf16(wa0, bhi, acc2[i][0], 0, 0, 0);
                acc2[i][1] = __builtin_amdgcn_mfma_f32_16x16x32_bf16(wa1, bhi, acc2[i][1], 0, 0, 0);
            }
        }
#pragma unroll
        for (int mtl = 0; mtl < 2; ++mtl) {
            float bb[4];
#pragma unroll
            for (int r = 0; r < 4; ++r) bb[r] = b2l[(c2 * 2 + mtl) * 16 + quad * 4 + r];
#pragma unroll
            for (int i = 0; i < 4; ++i)
#pragma unroll
                for (int r = 0; r < 4; ++r) acc2[i][mtl][r] += bb[r];
        }
        float ss[2][4], qq[2][4];
#pragma unroll
        for (int mtl = 0; mtl < 2; ++mtl)
#pragma unroll
            for (int r = 0; r < 4; ++r) { ss[mtl][r] = 0.f; qq[mtl][r] = 0.f; }
#pragma unroll
        for (int i = 0; i < 4; ++i) {
            if (wv + 4 * i > 12) continue;
#pragma unroll
            for (int mtl = 0; mtl < 2; ++mtl)
#pragma unroll
                for (int r = 0; r < 4; ++r) {
                    float v = acc2[i][mtl][r] * vmsk[i];
                    ss[mtl][r] += v;
                    qq[mtl][r] += v * v;
                }
        }
#pragma unroll
        for (int d = 1; d < 16; d <<= 1)
#pragma unroll
            for (int mtl = 0; mtl < 2; ++mtl)
#pragma unroll
                for (int r = 0; r < 4; ++r) {
                    ss[mtl][r] += __shfl_xor(ss[mtl][r], d);
                    qq[mtl][r] += __shfl_xor(qq[mtl][r], d);
                }
        if (l15 == 0) {
#pragma unroll
            for (int mtl = 0; mtl < 2; ++mtl)
#pragma unroll
                for (int r = 0; r < 4; ++r) {
                    int co = (c2 * 2 + mtl) * 16 + quad * 4 + r;
                    wred[wv * 64 + co]       = ss[mtl][r];
                    wred[256 + wv * 64 + co] = qq[mtl][r];
                }
        }
#pragma unroll
        for (int mtl = 0; mtl < 2; ++mtl) {
#pragma unroll
            for (int i = 0; i < 4; ++i) {
                if (wv + 4 * i > 12) continue;
                if (vmsk[i] > 0.f) {
#pragma unroll
                    for (int r = 0; r < 4; ++r)
                        slabh[(mtl * 16 + quad * 4 + r) * 204 + pvals[i]] =
                            cvt1_bf16(acc2[i][mtl][r]);
                }
            }
        }
        __syncthreads();
        {
            int j7 = (pj >= 7) ? 1 : 0;
            int qy = j7, qx = pj - 7 * j7;
            size_t obase = (size_t)n * 3136 + (c2 * 32 + pk) * 49;
            const unsigned short* srow = slabh + pk * 204;
#pragma unroll
            for (int it = 0; it < 7; ++it) {
                int pp = pj + (it << 3);
                if (pp < 49) {
                    int p0 = qy * 28 + qx * 2;           // always even -> 4B aligned
                    unsigned a01 = *(const unsigned*)(srow + p0);
                    unsigned a23 = *(const unsigned*)(srow + p0 + 14);
                    float v00 = __uint_as_float(a01 << 16);
                    float v01 = __uint_as_float(a01 & 0xffff0000u);
                    float v10 = __uint_as_float(a23 << 16);
                    float v11 = __uint_as_float(a23 & 0xffff0000u);
                    float mx = fmaxf(fmaxf(v00, v01), fmaxf(v10, v11));
                    pmax[obase + pp] = mx;
                }
                qx += 1; qy += 1;
                if (qx >= 7) { qx -= 7; qy += 1; }
            }
        }
        __syncthreads();   // slab reuse + wred visibility for the final read
    }
    if (tid < 64) {
        float s = wred[tid] + wred[64 + tid] + wred[128 + tid] + wred[192 + tid];
        float q = wred[256 + tid] + wred[320 + tid] + wred[384 + tid] + wred[448 + tid];
        bn2part[(n * 64 + tid) * 2 + 0] = s;
        bn2part[(n * 64 + tid) * 2 + 1] = q;
    }
}

// k5: finalize bn2 -> expanded per-fc1-k scale/shift arrays (3136 each)
__global__ __launch_bounds__(TPB) void k5_bn2_final(const float* __restrict__ bn2part,
                                                    const float* __restrict__ g2,
                                                    const float* __restrict__ be2,
                                                    float* __restrict__ sck,
                                                    float* __restrict__ shk) {
    __shared__ float red[TPB][2];
    __shared__ float sAC[2];
    int tid = threadIdx.x, co = blockIdx.x;
    float s = 0.f, q = 0.f;
    for (int i = tid; i < 4096; i += TPB) {
        s += bn2part[(i * 64 + co) * 2 + 0];
        q += bn2part[(i * 64 + co) * 2 + 1];
    }
    red[tid][0] = s; red[tid][1] = q;
    __syncthreads();
    for (int off = TPB / 2; off; off >>= 1) {
        if (tid < off) { red[tid][0] += red[tid + off][0]; red[tid][1] += red[tid + off][1]; }
        __syncthreads();
    }
    if (tid == 0) {
        const float count = 4096.f * 196.f;
        float mean = red[0][0] / count;
        float var  = red[0][1] / count - mean * mean;
        float a    = g2[co] * rsqrtf(var + EPSBN);
        sAC[0] = a;
        sAC[1] = be2[co] - a * mean;
    }
    __syncthreads();
    if (tid < 49) {
        sck[co * 49 + tid] = sAC[0];
        shk[co * 49 + tid] = sAC[1];
    }
}

// k7: fc1 via MFMA, 14-way K-split (r25, ~neutral but kept: marginally better).
__global__ __launch_bounds__(TPB) void k7_fc1_mfma(const float* __restrict__ pmax,
                                                   const float* __restrict__ sck,
                                                   const float* __restrict__ shk,
                                                   const unsigned short* __restrict__ fwp,
                                                   float* __restrict__ fpartA,
                                                   float* __restrict__ fpartB) {
    __shared__ __align__(16) unsigned short K7S[7680];   // Ahi[64*40] Bsl[128*40]
    unsigned short* Ahi = K7S;
    unsigned short* Bsl = K7S + 2560;
    int tid = threadIdx.x;
    int mt = blockIdx.x & 63, ks = blockIdx.x >> 6;      // ks in [0,14)
    int m0 = mt * 64;
    int lane = tid & 63, wv = tid >> 6, quad = lane >> 4, l15 = lane & 15;
    f4v acc[8];
#pragma unroll
    for (int i = 0; i < 8; ++i) acc[i] = (f4v){0.f, 0.f, 0.f, 0.f};

    for (int it = 0; it < 7; ++it) {
        int g  = ks * 7 + it;
        int k0 = g * 32;
#pragma unroll
        for (int i = 0; i < 8; ++i) {
            int e  = tid + i * TPB;
            int r  = e >> 5, kk = e & 31;
            int k  = k0 + kk;
            float a = sck[k], c = shk[k];
            size_t src = (size_t)(m0 + r) * 3136 + k;
            float v = fmaxf(a * pmax[src] + c, 0.f);
            Ahi[r * 40 + kk] = f2bf(v);
        }
        {
            const uint4* src = (const uint4*)(fwp + (size_t)g * 4096 + tid * 16);
            uint4 w0 = src[0], w1 = src[1];
            int n = tid >> 1, kk0 = (tid & 1) * 16;
            *(uint4*)(Bsl + n * 40 + kk0)     = w0;
            *(uint4*)(Bsl + n * 40 + kk0 + 8) = w1;
        }
        __syncthreads();
        bf8v ahi = *(const bf8v*)(Ahi + (wv * 16 + l15) * 40 + quad * 8);
#pragma unroll
        for (int nt = 0; nt < 8; ++nt) {
            bf8v b = *(const bf8v*)(Bsl + (nt * 16 + l15) * 40 + quad * 8);
            acc[nt] = __builtin_amdgcn_mfma_f32_16x16x32_bf16(ahi, b, acc[nt], 0, 0, 0);
        }
        __syncthreads();
    }
    float* outp = (ks < 7) ? (fpartA + (size_t)ks * 524288)
                           : (fpartB + (size_t)(ks - 7) * 524288);
#pragma unroll
    for (int nt = 0; nt < 8; ++nt)
#pragma unroll
        for (int r = 0; r < 4; ++r) {
            int m = m0 + wv * 16 + quad * 4 + r;
            int nn = nt * 16 + l15;
            outp[m * 128 + nn] = acc[nt][r];
        }
}

// k7b: reduce 14 K-split partials + bias + ReLU -> Phi [4096][129]
__global__ __launch_bounds__(TPB) void k7b_relu(const float* __restrict__ fpartA,
                                                const float* __restrict__ fpartB,
                                                const float* __restrict__ fb,
                                                float* __restrict__ Phi) {
    int e = blockIdx.x * TPB + threadIdx.x;
    int n = e >> 7, f = e & 127;
    float s = fb[f];
#pragma unroll
    for (int c = 0; c < 7; ++c) s += fpartA[(size_t)c * 524288 + e];
#pragma unroll
    for (int c = 0; c < 7; ++c) s += fpartB[(size_t)c * 524288 + e];
    Phi[n * 129 + f] = fmaxf(s, 0.f);
    if (f == 0) Phi[n * 129 + 128] = 1.0f;
}

// k8: partial Gram + C, 32-sample chunks.
// r26: 128 -> 256 blocks (0.5 -> 1 block/CU; half the chip was idle by
// construction). Block pair shares a chunk, splits the Gram ROW range
// (h==0: rows 0..64 + Cpart; h==1: rows 65..128). Each Gpart element still
// written exactly once; per-element math unchanged.
__global__ __launch_bounds__(TPB) void k8_gram(const float* __restrict__ Phi,
                                               const float* __restrict__ y,
                                               float* __restrict__ Gpart,
                                               float* __restrict__ Cpart) {
    __shared__ __align__(16) float ph[32 * 132];
    __shared__ __align__(16) float yl[32 * 12];
    int tid = threadIdx.x;
    int cB  = blockIdx.x >> 1;
    int h   = blockIdx.x & 1;
    int n0  = cB * 32;
    for (int i = tid; i < 32 * 132; i += TPB) ph[i] = 0.f;
    if (h == 0)
        for (int i = tid; i < 32 * 12; i += TPB) yl[i] = 0.f;
    __syncthreads();
    for (int i = tid; i < 32 * 129; i += TPB) {
        int r = i / 129, d = i % 129;
        ph[r * 132 + d] = Phi[(n0 + r) * 129 + d];
    }
    if (h == 0)
        for (int i = tid; i < 320; i += TPB) {
            int r = i / 10, j = i % 10;
            yl[r * 12 + j] = y[(n0 + r) * 10 + j];
        }
    __syncthreads();
    const int i0 = h ? 65 : 0;
    const int nrows = h ? 64 : 65;
    for (int g = tid; g < nrows * 33; g += TPB) {
        int i = i0 + g / 33, j0 = (g % 33) * 4;
        float4 s = make_float4(0.f, 0.f, 0.f, 0.f);
        for (int r = 0; r < 32; ++r) {
            float  vi = ph[r * 132 + i];
            float4 vj = *(const float4*)&ph[r * 132 + j0];
            s.x += vi * vj.x; s.y += vi * vj.y; s.z += vi * vj.z; s.w += vi * vj.w;
        }
        *(float4*)&Gpart[(size_t)cB * 17028 + i * 132 + j0] = s;
    }
    if (h == 0)
        for (int g = tid; g < 129 * 3; g += TPB) {
            int i = g / 3, j0 = (g % 3) * 4;
            float4 s = make_float4(0.f, 0.f, 0.f, 0.f);
            for (int r = 0; r < 32; ++r) {
                float  vi = ph[r * 132 + i];
                float4 vj = *(const float4*)&yl[r * 12 + j0];
                s.x += vi * vj.x; s.y += vi * vj.y; s.z += vi * vj.z; s.w += vi * vj.w;
            }
            *(float4*)&Cpart[(size_t)cB * 1548 + i * 12 + j0] = s;
        }
}

// k9: reduce partials -> G [129*129], C [129*10]
__global__ __launch_bounds__(TPB) void k9_reduce(const float* __restrict__ Gpart,
                                                 const float* __restrict__ Cpart,
                                                 float* __restrict__ G,
                                                 float* __restrict__ C) {
    int e = blockIdx.x * TPB + threadIdx.x;
    if (e < 16641) {
        int i = e / 129, j = e % 129;
        float s = 0.f;
        for (int c = 0; c < 128; ++c) s += Gpart[(size_t)c * 17028 + i * 132 + j];
        G[e] = s;
    } else if (e < 16641 + 1290) {
        int e2 = e - 16641;
        int i = e2 / 10, j = e2 % 10;
        float s = 0.f;
        for (int c = 0; c < 128; ++c) s += Cpart[(size_t)c * 1548 + i * 12 + j];
        C[e2] = s;
    }
}

// k10: solve (I+G) W = W0 + C. Gauss-Jordan with fully-diagonalized panels (r16).
// Confirmed win: 145 -> ~60. Do not touch.
__global__ __launch_bounds__(TPB) void k10_solve(const float* __restrict__ G,
                                                 const float* __restrict__ C,
                                                 const float* __restrict__ W0,
                                                 float* __restrict__ Wnew) {
    __shared__ __align__(16) float M[129 * 140];
    __shared__ __align__(16) float LpT[PW * 116];   // [k][compact row], 113 used
    __shared__ float L11s[PW * 16];                 // L11s[m*16+k] = L11[k][m], m<k
    __shared__ float invD[129];
    __shared__ float x128s[10];
    int tid = threadIdx.x;
    int lane = tid & 63, wv = tid >> 6;
    for (int e = tid; e < 129 * 129; e += TPB) {
        int i = e / 129, j = e % 129;
        M[i * 140 + j] = G[e] + (i == j ? 1.f : 0.f);
    }
    for (int i = tid; i < 129; i += TPB) M[i * 140 + 129] = 0.f;
    for (int e = tid; e < 1290; e += TPB) {
        int i = e / 10, c = e % 10;
        M[i * 140 + 130 + c] = W0[e] + C[e];
    }
    __syncthreads();

    for (int k0 = 0; k0 < 128; k0 += PW) {
        const int kend = k0 + PW;
        if (wv == 0) {
            bool act = lane < PW;
            int r  = k0 + lane;
            int rc = act ? r : k0;
            float u[PW], Lr[PW];
#pragma unroll
            for (int j = 0; j < PW; ++j) u[j] = M[rc * 140 + k0 + j];
            float dval = u[0];
#pragma unroll
            for (int k = 0; k < PW; ++k) {
                if (lane == k) dval = u[k];
                float piv = rdl(u[k], k);
                float f   = u[k] * __builtin_amdgcn_rcpf(piv);
                float fm  = (act && lane > k) ? f : 0.f;
                Lr[k] = fm;
#pragma unroll
                for (int j = 0; j < PW; ++j)
                    if (j > k) u[j] -= fm * rdl(u[j], k);
            }
            if (act) {
#pragma unroll
                for (int j = 0; j < PW; ++j)
                    if (j >= lane) M[r * 140 + k0 + j] = u[j];   // U11 incl diag
#pragma unroll
                for (int k = 0; k < PW; ++k)
                    if (k < lane) L11s[k * 16 + lane] = Lr[k];   // L11[lane][k]
                invD[r] = __builtin_amdgcn_rcpf(dval);
            }
        }
        __syncthreads();
        if (tid < 128) {
            int cidx = tid;                      // compact off-panel row index
            if (cidx < 113) {
                int r = cidx < k0 ? cidx : cidx + PW;
                float4 a4[4];
#pragma unroll
                for (int q = 0; q < 4; ++q) a4[q] = *(const float4*)&M[r * 140 + k0 + q * 4];
                float a[PW];
#pragma unroll
                for (int q = 0; q < 4; ++q) {
                    a[q * 4 + 0] = a4[q].x; a[q * 4 + 1] = a4[q].y;
                    a[q * 4 + 2] = a4[q].z; a[q * 4 + 3] = a4[q].w;
                }
#pragma unroll
                for (int k = 0; k < PW; ++k)
                    LpT[k * 116 + cidx] = a[k] * invD[k0 + k];
            }
        } else {
            int j = kend + (tid - 128);
            if (j < 140) {
                float yv[PW];
#pragma unroll
                for (int kk = 0; kk < PW; ++kk) {
                    float v = M[(k0 + kk) * 140 + j];
#pragma unroll
                    for (int m = 0; m < PW; ++m)
                        if (m < kk) v -= L11s[m * 16 + kk] * yv[m];
                    yv[kk] = v;
                }
                float xv[PW];
#pragma unroll
                for (int kk = PW - 1; kk >= 0; --kk) {
                    float v = yv[kk];
#pragma unroll
                    for (int m = 0; m < PW; ++m)
                        if (m > kk) v -= M[(k0 + kk) * 140 + k0 + m] * xv[m];
                    M[(k0 + kk) * 140 + j] = v;       // T = D * A11^{-1} * col
                    xv[kk] = v * invD[k0 + kk];
                }
            }
        }
        __syncthreads();
        const int Jn = 140 - kend;
        const int nrt = 29, nct = Jn >> 2;       // 113 rows -> 29 4-row tiles
        for (int t = tid; t < nrt * nct; t += TPB) {
            int tr = t % nrt, tc = t / nrt;
            int c0 = tr * 4;
            int j0 = kend + tc * 4;
            float4 s0 = {0, 0, 0, 0}, s1 = {0, 0, 0, 0}, s2 = {0, 0, 0, 0}, s3 = {0, 0, 0, 0};
#pragma unroll
            for (int kk = 0; kk < PW; ++kk) {
                float4 L4 = *(const float4*)&LpT[kk * 116 + c0];
                float4 U4 = *(const float4*)&M[(k0 + kk) * 140 + j0];
                s0.x += L4.x * U4.x; s0.y += L4.x * U4.y; s0.z += L4.x * U4.z; s0.w += L4.x * U4.w;
                s1.x += L4.y * U4.x; s1.y += L4.y * U4.y; s1.z += L4.y * U4.z; s1.w += L4.y * U4.w;
                s2.x += L4.z * U4.x; s2.y += L4.z * U4.y; s2.z += L4.z * U4.z; s2.w += L4.z * U4.w;
                s3.x += L4.w * U4.x; s3.y += L4.w * U4.y; s3.z += L4.w * U4.z; s3.w += L4.w * U4.w;
            }
            float4 sv[4] = {s0, s1, s2, s3};
#pragma unroll
            for (int i = 0; i < 4; ++i) {
                int cidx = c0 + i;
                if (cidx < 113) {
                    int r = cidx < k0 ? cidx : cidx + PW;
                    float4 mv = *(const float4*)&M[r * 140 + j0];
                    mv.x -= sv[i].x; mv.y -= sv[i].y; mv.z -= sv[i].z; mv.w -= sv[i].w;
                    *(float4*)&M[r * 140 + j0] = mv;
                }
            }
        }
        __syncthreads();
    }
    if (tid == 0) {
        float i128 = __builtin_amdgcn_rcpf(M[128 * 140 + 128]);
#pragma unroll
        for (int c = 0; c < 10; ++c) x128s[c] = M[128 * 140 + 130 + c] * i128;
    }
    __syncthreads();
    if (tid < 128) {
        int r = tid;
        float m128 = M[r * 140 + 128];
        float idr  = invD[r];
#pragma unroll
        for (int c = 0; c < 10; ++c)
            Wnew[r * 10 + c] = (M[r * 140 + 130 + c] - m128 * x128s[c]) * idr;
    } else if (tid == 128) {
#pragma unroll
        for (int c = 0; c < 10; ++c) Wnew[1280 + c] = x128s[c];
    }
}

// k11: out = Phi @ Wnew  ([4096][10])
__global__ __launch_bounds__(TPB) void k11_out(const float* __restrict__ Phi,
                                               const float* __restrict__ Wnew,
                                               float* __restrict__ out) {
    __shared__ float Wl[1290];
    int tid = threadIdx.x;
    for (int i = tid; i < 1290; i += TPB) Wl[i] = Wnew[i];
    __syncthreads();
    int idx = blockIdx.x * TPB + tid;
    int n = idx / 10, j = idx % 10;
    float s = 0.f;
    for (int d = 0; d < 129; ++d) s += Phi[n * 129 + d] * Wl[d * 10 + j];
    out[idx] = s;
}

extern "C" void kernel_launch(void* const* d_in, const int* in_sizes, int n_in,
                              void* d_out, int out_size, void* d_ws, size_t ws_size,
                              hipStream_t stream) {
    const float* x   = (const float*)d_in[0];
    const float* y   = (const float*)d_in[1];
    const float* w1  = (const float*)d_in[2];
    const float* g1  = (const float*)d_in[4];
    const float* be1 = (const float*)d_in[5];
    const float* w2  = (const float*)d_in[6];
    const float* b2  = (const float*)d_in[7];
    const float* g2  = (const float*)d_in[8];
    const float* be2 = (const float*)d_in[9];
    const float* fw  = (const float*)d_in[10];
    const float* fb  = (const float*)d_in[11];
    const float* W0  = (const float*)d_in[12];
    float* out = (float*)d_out;
    float* ws  = (float*)d_ws;
    if (ws_size < WS_TOTAL * 4ull) return;

    unsigned* wAg_u = (unsigned*)(ws + WS_WAG);
    unsigned* fwp_u = (unsigned*)(ws + WS_FWP);
    const unsigned short* wAg_h = (const unsigned short*)wAg_u;
    const unsigned short* fwp_h = (const unsigned short*)fwp_u;
    float* sc1     = ws + WS_SC1;
    float* sh1     = ws + WS_SH1;
    float* sck     = ws + WS_SCK;
    float* shk     = ws + WS_SHK;
    float* G       = ws + WS_G;
    float* C       = ws + WS_C;
    float* Wnew    = ws + WS_WNEW;
    float* qpart   = ws + WS_BN1PART;
    float* bn2part = ws + WS_BN2PART;
    float* Phi     = ws + WS_PHI;
    float* fpartA  = ws + WS_FPART;
    float* fpartB  = ws + WS_FPART2;
    float* Gpart   = ws + WS_GPART;
    float* Cpart   = ws + WS_CPART;
    float* pmax    = ws + WS_PMAX;

    kWk1<<<1332, TPB, 0, stream>>>(w2, fw, x, wAg_u, fwp_u, qpart);
    k2_bn1_final<<<1, 64, 0, stream>>>(qpart, w1, g1, be1, sc1, sh1);
    k34_conv2_mfma<<<4096, TPB, 0, stream>>>(x, w1, sc1, sh1, wAg_h, b2, pmax, bn2part);
    k5_bn2_final<<<64, TPB, 0, stream>>>(bn2part, g2, be2, sck, shk);
    k7_fc1_mfma<<<896, TPB, 0, stream>>>(pmax, sck, shk, fwp_h, fpartA, fpartB);
    k7b_relu<<<2048, TPB, 0, stream>>>(fpartA, fpartB, fb, Phi);
    k8_gram<<<256, TPB, 0, stream>>>(Phi, y, Gpart, Cpart);
    k9_reduce<<<71, TPB, 0, stream>>>(Gpart, Cpart, G, C);
    k10_solve<<<1, TPB, 0, stream>>>(G, C, W0, Wnew);
    k11_out<<<160, TPB, 0, stream>>>(Phi, Wnew, out);
}

// Round 16
// 321.062 us; speedup vs baseline: 1.2850x; 1.0529x over previous
//
#include <hip/hip_runtime.h>
#include <math.h>

#define TPB 256
#define EPSBN 1e-5f
#define PW 16

typedef __attribute__((ext_vector_type(8))) short bf8v;   // 8 x bf16 (4 VGPR)
typedef __attribute__((ext_vector_type(4))) float f4v;    // MFMA acc

static __device__ __forceinline__ unsigned short f2bf(float f) {
    union { float f; unsigned u; } v; v.f = f;
    unsigned r = v.u + 0x7fffu + ((v.u >> 16) & 1u);
    return (unsigned short)(r >> 16);
}
// HW packed f32->bf16 convert (RNE, same rounding as f2bf); 1 inst replaces ~8.
static __device__ __forceinline__ unsigned cvt_pk_bf16(float lo, float hi) {
    unsigned r;
    asm("v_cvt_pk_bf16_f32 %0, %1, %2" : "=v"(r) : "v"(lo), "v"(hi));
    return r;
}
static __device__ __forceinline__ unsigned short cvt1_bf16(float v) {
    return (unsigned short)cvt_pk_bf16(v, v);
}
// broadcast-from-lane via v_readlane (VALU, ~8cy) instead of ds_bpermute (~120cy)
static __device__ __forceinline__ float rdl(float v, int l) {
    return __int_as_float(__builtin_amdgcn_readlane(__float_as_int(v), l));
}

// ---- workspace layout (float element offsets); total 26,865,664 floats (~107.5 MB) ----
#define WS_WAG      0u
#define WS_FWP      9216u
#define WS_SC1      209920u
#define WS_SH1      209952u
#define WS_SCK      209984u
#define WS_SHK      213120u
#define WS_G        216256u
#define WS_C        232897u
#define WS_WNEW     234187u
#define WS_BN1PART  235520u
#define WS_BN2PART  497664u
#define WS_PHI      1021952u
#define WS_FPART    1550336u
#define WS_GPART    5220352u
#define WS_CPART    7399936u
#define WS_PMAX     7598080u
#define WS_FPART2   20443136u
#define WS_TOTAL    26865664ull

// kWk1: fused weight-pack + BN1-stats (512 stat blocks, r26 split — confirmed).
__global__ __launch_bounds__(TPB) void kWk1(const float* __restrict__ w2,
                                            const float* __restrict__ fw,
                                            const float* __restrict__ x,
                                            unsigned* __restrict__ wAg_u,
                                            unsigned* __restrict__ fwp_u,
                                            float* __restrict__ qpart) {
    __shared__ float xs[900];
    __shared__ float red[4][54];
    if (blockIdx.x < 820) {
        int e = blockIdx.x * TPB + threadIdx.x;
        if (e < 9216) {
            int jj = e & 3, lane = (e >> 2) & 63, mt = (e >> 8) & 3, t = e >> 10;
            int j0 = jj * 2;
            int co = mt * 16 + (lane & 15);
            int ci = (lane >> 4) * 8 + j0;
            unsigned h0 = f2bf(w2[(co * 32 + ci) * 9 + t]);
            unsigned h1 = f2bf(w2[(co * 32 + ci + 1) * 9 + t]);
            wAg_u[e] = h0 | (h1 << 16);
        } else if (e < 9216 + 200704) {
            int f = e - 9216;
            int kk = (f & 15) * 2, n = (f >> 4) & 127, g = f >> 11;
            unsigned h0 = f2bf(fw[n * 3136 + g * 32 + kk]);
            unsigned h1 = f2bf(fw[n * 3136 + g * 32 + kk + 1]);
            fwp_u[f] = h0 | (h1 << 16);
        }
        return;
    }
    int bid = blockIdx.x - 820;                     // 0..511
    int tid = threadIdx.x;
    float acc[54];
#pragma unroll
    for (int i = 0; i < 54; ++i) acc[i] = 0.f;
    for (int img = 0; img < 8; ++img) {
        int n = bid * 8 + img;
        for (int i = tid; i < 900; i += TPB) xs[i] = 0.f;
        __syncthreads();
        for (int i = tid; i < 784; i += TPB) {
            int r = i / 28, c = i % 28;
            xs[(r + 1) * 30 + (c + 1)] = x[n * 784 + i];
        }
        __syncthreads();
        for (int p = tid; p < 784; p += TPB) {
            int oy = p / 28, ox = p % 28;
            float v[9];
#pragma unroll
            for (int t = 0; t < 9; ++t) v[t] = xs[(oy + t / 3) * 30 + ox + (t % 3)];
            int qi = 9;
#pragma unroll
            for (int t = 0; t < 9; ++t) {
                acc[t] += v[t];
#pragma unroll
                for (int u = t; u < 9; ++u) acc[qi++] += v[t] * v[u];
            }
        }
        __syncthreads();
    }
    int wv = tid >> 6, lane = tid & 63;
#pragma unroll
    for (int i = 0; i < 54; ++i) {
        float s = acc[i];
        for (int d = 1; d < 64; d <<= 1) s += __shfl_xor(s, d);
        if (lane == 0) red[wv][i] = s;
    }
    __syncthreads();
    if (tid < 54)
        qpart[bid * 54 + tid] = red[0][tid] + red[1][tid] + red[2][tid] + red[3][tid];
}

// k2: reduce qpart (512 partials) -> S,Q -> per-channel scale/shift.
// r27: 1-WG kernels run in the inflated-latency regime (r1-r3 ledger); the
// 512-iteration serial reduce is the cost. 216 threads x 128-partial segments
// + LDS reduce: 4x shorter chain, same math up to fp32 reorder.
__global__ __launch_bounds__(TPB) void k2_bn1_final(const float* __restrict__ qpart,
                                                    const float* __restrict__ w1,
                                                    const float* __restrict__ g1,
                                                    const float* __restrict__ be1,
                                                    float* __restrict__ sc1,
                                                    float* __restrict__ sh1) {
    __shared__ float Tp[4][54];
    __shared__ float T[54];
    int tid = threadIdx.x;
    if (tid < 216) {
        int col = tid % 54, seg = tid / 54;        // seg 0..3
        float s = 0.f;
        int b0 = seg * 128;
#pragma unroll 8
        for (int b = 0; b < 128; ++b) s += qpart[(b0 + b) * 54 + col];
        Tp[seg][col] = s;
    }
    __syncthreads();
    if (tid < 54) T[tid] = (Tp[0][tid] + Tp[1][tid]) + (Tp[2][tid] + Tp[3][tid]);
    __syncthreads();
    if (tid < 32) {
        const float inv = 1.f / (4096.f * 784.f);
        float w[9];
#pragma unroll
        for (int t = 0; t < 9; ++t) w[t] = w1[tid * 9 + t];
        float mean = 0.f;
#pragma unroll
        for (int t = 0; t < 9; ++t) mean += w[t] * T[t];
        mean *= inv;
        float ex2 = 0.f;
        int qi = 9;
#pragma unroll
        for (int t = 0; t < 9; ++t)
#pragma unroll
            for (int u = t; u < 9; ++u) {
                float c = w[t] * w[u] * T[qi++];
                ex2 += (u == t) ? c : 2.f * c;
            }
        ex2 *= inv;
        float var = ex2 - mean * mean;
        float a = g1[tid] * rsqrtf(var + EPSBN);
        sc1[tid] = a;
        sh1[tid] = be1[tid] - a * mean;
    }
}

// k34: conv1+BN1+ReLU+pool -> LDS bf16 -> conv2 via MFMA -> stats + pooled max.
// Ledger closed (r24 bf16 slab = final config). Do not touch.
__global__ __launch_bounds__(TPB) void k34_conv2_mfma(const float* __restrict__ x,
                                                      const float* __restrict__ w1,
                                                      const float* __restrict__ sc1,
                                                      const float* __restrict__ sh1,
                                                      const unsigned short* __restrict__ wAg,
                                                      const float* __restrict__ b2,
                                                      float* __restrict__ pmax,
                                                      float* __restrict__ bn2part) {
    __shared__ __align__(16) unsigned short SH[17920];
    unsigned short* slabh = SH;
    float* xs   = (float*)SH;                     // alias slab (dead then)
    unsigned* H1u = (unsigned*)(SH + 6528);
    const char* h1hiB = (const char*)(SH + 6528);
    float* wred = (float*)(SH + 16768);
    float* b2l  = (float*)(SH + 17792);

    int tid = threadIdx.x;
    int n   = blockIdx.x;
    int lane = tid & 63, wv = tid >> 6, quad = lane >> 4, l15 = lane & 15;

    for (int i = tid; i < 5120; i += TPB) H1u[i] = 0u;
    for (int i = tid; i < 900; i += TPB) xs[i] = 0.f;
    if (tid < 64) b2l[tid] = b2[tid];
    __syncthreads();
    for (int i = tid; i < 784; i += TPB) {
        int r = i / 28, c = i % 28;
        xs[(r + 1) * 30 + (c + 1)] = x[n * 784 + i];
    }
    __syncthreads();

    if (tid < 196) {
        int py = tid / 14, px = tid % 14;
        int paddr = (py + 1) * 16 + (px + 1);
        float patch[4][4];
#pragma unroll
        for (int r = 0; r < 4; ++r)
#pragma unroll
            for (int c = 0; c < 4; ++c) patch[r][c] = xs[(2 * py + r) * 30 + 2 * px + c];
        unsigned hw0 = 0;
#pragma unroll
        for (int cp = 0; cp < 16; ++cp) {           // channel pair (2cp, 2cp+1)
            float mx0 = -1e30f, mx1 = -1e30f;
#pragma unroll
            for (int sy = 0; sy < 2; ++sy)
#pragma unroll
                for (int sx = 0; sx < 2; ++sx) {
                    float v0 = 0.f, v1 = 0.f;
#pragma unroll
                    for (int t = 0; t < 9; ++t) {
                        float pv = patch[sy + t / 3][sx + t % 3];
                        v0 += pv * w1[(2 * cp) * 9 + t];
                        v1 += pv * w1[(2 * cp + 1) * 9 + t];
                    }
                    mx0 = fmaxf(mx0, v0);
                    mx1 = fmaxf(mx1, v1);
                }
            float r0 = fmaxf(sc1[2 * cp] * mx0 + sh1[2 * cp], 0.f);
            float r1 = fmaxf(sc1[2 * cp + 1] * mx1 + sh1[2 * cp + 1], 0.f);
            unsigned hp = cvt_pk_bf16(r0, r1);      // lo = ch 2cp, hi = ch 2cp+1
            if ((cp & 1) == 0) hw0 = hp;
            else *(uint2*)(H1u + paddr * 20 + (cp - 1)) = make_uint2(hw0, hp);
        }
    }
    __syncthreads();

    int baseB[4];
    float vmsk[4];
    int pvals[4];
#pragma unroll
    for (int i = 0; i < 4; ++i) {
        int nt = wv + 4 * i;
        int p  = nt * 16 + l15;
        vmsk[i]  = (nt <= 12 && p < 196) ? 1.f : 0.f;
        pvals[i] = p;
        int pc = p < 196 ? p : 195;
        int py = pc / 14, px = pc - py * 14;
        baseB[i] = ((py + 1) * 16 + (px + 1)) * 80 + quad * 16;
    }

    int pk = tid >> 3, pj = tid & 7;   // pool decomposition

#pragma unroll
    for (int c2 = 0; c2 < 2; ++c2) {
        f4v acc2[4][2];
#pragma unroll
        for (int i = 0; i < 4; ++i)
#pragma unroll
            for (int mtl = 0; mtl < 2; ++mtl) acc2[i][mtl] = (f4v){0.f, 0.f, 0.f, 0.f};
#pragma unroll
        for (int t = 0; t < 9; ++t) {
            const int toff = ((t / 3) - 1) * 1280 + ((t % 3) - 1) * 80;
            bf8v wa0 = *(const bf8v*)(wAg + ((t * 4 + c2 * 2 + 0) * 64 + lane) * 8);
            bf8v wa1 = *(const bf8v*)(wAg + ((t * 4 + c2 * 2 + 1) * 64 + lane) * 8);
#pragma unroll
            for (int i = 0; i < 4; ++i) {
                if (wv + 4 * i > 12) continue;
                bf8v bhi = *(const bf8v*)(h1hiB + baseB[i] + toff);
                acc2[i][0] = __builtin_amdgcn_mfma_f32_16x16x32_bf16(wa0, bhi, acc2[i][0], 0, 0, 0);
                acc2[i][1] = __builtin_amdgcn_mfma_f32_16x16x32_bf16(wa1, bhi, acc2[i][1], 0, 0, 0);
            }
        }
#pragma unroll
        for (int mtl = 0; mtl < 2; ++mtl) {
            float bb[4];
#pragma unroll
            for (int r = 0; r < 4; ++r) bb[r] = b2l[(c2 * 2 + mtl) * 16 + quad * 4 + r];
#pragma unroll
            for (int i = 0; i < 4; ++i)
#pragma unroll
                for (int r = 0; r < 4; ++r) acc2[i][mtl][r] += bb[r];
        }
        float ss[2][4], qq[2][4];
#pragma unroll
        for (int mtl = 0; mtl < 2; ++mtl)
#pragma unroll
            for (int r = 0; r < 4; ++r) { ss[mtl][r] = 0.f; qq[mtl][r] = 0.f; }
#pragma unroll
        for (int i = 0; i < 4; ++i) {
            if (wv + 4 * i > 12) continue;
#pragma unroll
            for (int mtl = 0; mtl < 2; ++mtl)
#pragma unroll
                for (int r = 0; r < 4; ++r) {
                    float v = acc2[i][mtl][r] * vmsk[i];
                    ss[mtl][r] += v;
                    qq[mtl][r] += v * v;
                }
        }
#pragma unroll
        for (int d = 1; d < 16; d <<= 1)
#pragma unroll
            for (int mtl = 0; mtl < 2; ++mtl)
#pragma unroll
                for (int r = 0; r < 4; ++r) {
                    ss[mtl][r] += __shfl_xor(ss[mtl][r], d);
                    qq[mtl][r] += __shfl_xor(qq[mtl][r], d);
                }
        if (l15 == 0) {
#pragma unroll
            for (int mtl = 0; mtl < 2; ++mtl)
#pragma unroll
                for (int r = 0; r < 4; ++r) {
                    int co = (c2 * 2 + mtl) * 16 + quad * 4 + r;
                    wred[wv * 64 + co]       = ss[mtl][r];
                    wred[256 + wv * 64 + co] = qq[mtl][r];
                }
        }
#pragma unroll
        for (int mtl = 0; mtl < 2; ++mtl) {
#pragma unroll
            for (int i = 0; i < 4; ++i) {
                if (wv + 4 * i > 12) continue;
                if (vmsk[i] > 0.f) {
#pragma unroll
                    for (int r = 0; r < 4; ++r)
                        slabh[(mtl * 16 + quad * 4 + r) * 204 + pvals[i]] =
                            cvt1_bf16(acc2[i][mtl][r]);
                }
            }
        }
        __syncthreads();
        {
            int j7 = (pj >= 7) ? 1 : 0;
            int qy = j7, qx = pj - 7 * j7;
            size_t obase = (size_t)n * 3136 + (c2 * 32 + pk) * 49;
            const unsigned short* srow = slabh + pk * 204;
#pragma unroll
            for (int it = 0; it < 7; ++it) {
                int pp = pj + (it << 3);
                if (pp < 49) {
                    int p0 = qy * 28 + qx * 2;           // always even -> 4B aligned
                    unsigned a01 = *(const unsigned*)(srow + p0);
                    unsigned a23 = *(const unsigned*)(srow + p0 + 14);
                    float v00 = __uint_as_float(a01 << 16);
                    float v01 = __uint_as_float(a01 & 0xffff0000u);
                    float v10 = __uint_as_float(a23 << 16);
                    float v11 = __uint_as_float(a23 & 0xffff0000u);
                    float mx = fmaxf(fmaxf(v00, v01), fmaxf(v10, v11));
                    pmax[obase + pp] = mx;
                }
                qx += 1; qy += 1;
                if (qx >= 7) { qx -= 7; qy += 1; }
            }
        }
        __syncthreads();   // slab reuse + wred visibility for the final read
    }
    if (tid < 64) {
        float s = wred[tid] + wred[64 + tid] + wred[128 + tid] + wred[192 + tid];
        float q = wred[256 + tid] + wred[320 + tid] + wred[384 + tid] + wred[448 + tid];
        bn2part[(n * 64 + tid) * 2 + 0] = s;
        bn2part[(n * 64 + tid) * 2 + 1] = q;
    }
}

// k5: finalize bn2 -> expanded per-fc1-k scale/shift arrays (3136 each)
__global__ __launch_bounds__(TPB) void k5_bn2_final(const float* __restrict__ bn2part,
                                                    const float* __restrict__ g2,
                                                    const float* __restrict__ be2,
                                                    float* __restrict__ sck,
                                                    float* __restrict__ shk) {
    __shared__ float red[TPB][2];
    __shared__ float sAC[2];
    int tid = threadIdx.x, co = blockIdx.x;
    float s = 0.f, q = 0.f;
    for (int i = tid; i < 4096; i += TPB) {
        s += bn2part[(i * 64 + co) * 2 + 0];
        q += bn2part[(i * 64 + co) * 2 + 1];
    }
    red[tid][0] = s; red[tid][1] = q;
    __syncthreads();
    for (int off = TPB / 2; off; off >>= 1) {
        if (tid < off) { red[tid][0] += red[tid + off][0]; red[tid][1] += red[tid + off][1]; }
        __syncthreads();
    }
    if (tid == 0) {
        const float count = 4096.f * 196.f;
        float mean = red[0][0] / count;
        float var  = red[0][1] / count - mean * mean;
        float a    = g2[co] * rsqrtf(var + EPSBN);
        sAC[0] = a;
        sAC[1] = be2[co] - a * mean;
    }
    __syncthreads();
    if (tid < 49) {
        sck[co * 49 + tid] = sAC[0];
        shk[co * 49 + tid] = sAC[1];
    }
}

// k7: fc1 via MFMA, 14-way K-split (r25).
__global__ __launch_bounds__(TPB) void k7_fc1_mfma(const float* __restrict__ pmax,
                                                   const float* __restrict__ sck,
                                                   const float* __restrict__ shk,
                                                   const unsigned short* __restrict__ fwp,
                                                   float* __restrict__ fpartA,
                                                   float* __restrict__ fpartB) {
    __shared__ __align__(16) unsigned short K7S[7680];   // Ahi[64*40] Bsl[128*40]
    unsigned short* Ahi = K7S;
    unsigned short* Bsl = K7S + 2560;
    int tid = threadIdx.x;
    int mt = blockIdx.x & 63, ks = blockIdx.x >> 6;      // ks in [0,14)
    int m0 = mt * 64;
    int lane = tid & 63, wv = tid >> 6, quad = lane >> 4, l15 = lane & 15;
    f4v acc[8];
#pragma unroll
    for (int i = 0; i < 8; ++i) acc[i] = (f4v){0.f, 0.f, 0.f, 0.f};

    for (int it = 0; it < 7; ++it) {
        int g  = ks * 7 + it;
        int k0 = g * 32;
#pragma unroll
        for (int i = 0; i < 8; ++i) {
            int e  = tid + i * TPB;
            int r  = e >> 5, kk = e & 31;
            int k  = k0 + kk;
            float a = sck[k], c = shk[k];
            size_t src = (size_t)(m0 + r) * 3136 + k;
            float v = fmaxf(a * pmax[src] + c, 0.f);
            Ahi[r * 40 + kk] = f2bf(v);
        }
        {
            const uint4* src = (const uint4*)(fwp + (size_t)g * 4096 + tid * 16);
            uint4 w0 = src[0], w1 = src[1];
            int n = tid >> 1, kk0 = (tid & 1) * 16;
            *(uint4*)(Bsl + n * 40 + kk0)     = w0;
            *(uint4*)(Bsl + n * 40 + kk0 + 8) = w1;
        }
        __syncthreads();
        bf8v ahi = *(const bf8v*)(Ahi + (wv * 16 + l15) * 40 + quad * 8);
#pragma unroll
        for (int nt = 0; nt < 8; ++nt) {
            bf8v b = *(const bf8v*)(Bsl + (nt * 16 + l15) * 40 + quad * 8);
            acc[nt] = __builtin_amdgcn_mfma_f32_16x16x32_bf16(ahi, b, acc[nt], 0, 0, 0);
        }
        __syncthreads();
    }
    float* outp = (ks < 7) ? (fpartA + (size_t)ks * 524288)
                           : (fpartB + (size_t)(ks - 7) * 524288);
#pragma unroll
    for (int nt = 0; nt < 8; ++nt)
#pragma unroll
        for (int r = 0; r < 4; ++r) {
            int m = m0 + wv * 16 + quad * 4 + r;
            int nn = nt * 16 + l15;
            outp[m * 128 + nn] = acc[nt][r];
        }
}

// k7b: reduce 14 K-split partials + bias + ReLU -> Phi [4096][129]
__global__ __launch_bounds__(TPB) void k7b_relu(const float* __restrict__ fpartA,
                                                const float* __restrict__ fpartB,
                                                const float* __restrict__ fb,
                                                float* __restrict__ Phi) {
    int e = blockIdx.x * TPB + threadIdx.x;
    int n = e >> 7, f = e & 127;
    float s = fb[f];
#pragma unroll
    for (int c = 0; c < 7; ++c) s += fpartA[(size_t)c * 524288 + e];
#pragma unroll
    for (int c = 0; c < 7; ++c) s += fpartB[(size_t)c * 524288 + e];
    Phi[n * 129 + f] = fmaxf(s, 0.f);
    if (f == 0) Phi[n * 129 + 128] = 1.0f;
}

// k8: partial Gram + C, 32-sample chunks; 256 blocks (r26 row-split — confirmed).
__global__ __launch_bounds__(TPB) void k8_gram(const float* __restrict__ Phi,
                                               const float* __restrict__ y,
                                               float* __restrict__ Gpart,
                                               float* __restrict__ Cpart) {
    __shared__ __align__(16) float ph[32 * 132];
    __shared__ __align__(16) float yl[32 * 12];
    int tid = threadIdx.x;
    int cB  = blockIdx.x >> 1;
    int h   = blockIdx.x & 1;
    int n0  = cB * 32;
    for (int i = tid; i < 32 * 132; i += TPB) ph[i] = 0.f;
    if (h == 0)
        for (int i = tid; i < 32 * 12; i += TPB) yl[i] = 0.f;
    __syncthreads();
    for (int i = tid; i < 32 * 129; i += TPB) {
        int r = i / 129, d = i % 129;
        ph[r * 132 + d] = Phi[(n0 + r) * 129 + d];
    }
    if (h == 0)
        for (int i = tid; i < 320; i += TPB) {
            int r = i / 10, j = i % 10;
            yl[r * 12 + j] = y[(n0 + r) * 10 + j];
        }
    __syncthreads();
    const int i0 = h ? 65 : 0;
    const int nrows = h ? 64 : 65;
    for (int g = tid; g < nrows * 33; g += TPB) {
        int i = i0 + g / 33, j0 = (g % 33) * 4;
        float4 s = make_float4(0.f, 0.f, 0.f, 0.f);
        for (int r = 0; r < 32; ++r) {
            float  vi = ph[r * 132 + i];
            float4 vj = *(const float4*)&ph[r * 132 + j0];
            s.x += vi * vj.x; s.y += vi * vj.y; s.z += vi * vj.z; s.w += vi * vj.w;
        }
        *(float4*)&Gpart[(size_t)cB * 17028 + i * 132 + j0] = s;
    }
    if (h == 0)
        for (int g = tid; g < 129 * 3; g += TPB) {
            int i = g / 3, j0 = (g % 3) * 4;
            float4 s = make_float4(0.f, 0.f, 0.f, 0.f);
            for (int r = 0; r < 32; ++r) {
                float  vi = ph[r * 132 + i];
                float4 vj = *(const float4*)&yl[r * 12 + j0];
                s.x += vi * vj.x; s.y += vi * vj.y; s.z += vi * vj.z; s.w += vi * vj.w;
            }
            *(float4*)&Cpart[(size_t)cB * 1548 + i * 12 + j0] = s;
        }
}

// k9: reduce partials -> G [129*129], C [129*10].
// r27: was 71 blocks = 0.28 blocks/CU (185 CUs idle) with a 128-load serial
// chain per output. Now 8 threads per output (16 c-values each, aligned 8-lane
// __shfl_xor tree): 561 blocks = 2.2/CU, 8x shorter chain. Deterministic
// (fixed tree order within a wave); fp32 reorder only.
__global__ __launch_bounds__(TPB) void k9_reduce(const float* __restrict__ Gpart,
                                                 const float* __restrict__ Cpart,
                                                 float* __restrict__ G,
                                                 float* __restrict__ C) {
    int gt = blockIdx.x * TPB + threadIdx.x;
    int e  = gt >> 3;
    int sl = gt & 7;
    float s = 0.f;
    if (e < 16641) {
        int i = e / 129, j = e % 129;
        const float* p = Gpart + (size_t)sl * 16 * 17028 + i * 132 + j;
#pragma unroll 4
        for (int c = 0; c < 16; ++c) s += p[(size_t)c * 17028];
    } else if (e < 16641 + 1290) {
        int e2 = e - 16641;
        int i = e2 / 10, j = e2 % 10;
        const float* p = Cpart + (size_t)sl * 16 * 1548 + i * 12 + j;
#pragma unroll 4
        for (int c = 0; c < 16; ++c) s += p[(size_t)c * 1548];
    }
    s += __shfl_xor(s, 1);
    s += __shfl_xor(s, 2);
    s += __shfl_xor(s, 4);
    if (sl == 0) {
        if (e < 16641)            G[e] = s;
        else if (e < 16641 + 1290) C[e - 16641] = s;
    }
}

// k10: solve (I+G) W = W0 + C. Gauss-Jordan with fully-diagonalized panels (r16).
// Confirmed win: 145 -> ~60. Do not touch.
__global__ __launch_bounds__(TPB) void k10_solve(const float* __restrict__ G,
                                                 const float* __restrict__ C,
                                                 const float* __restrict__ W0,
                                                 float* __restrict__ Wnew) {
    __shared__ __align__(16) float M[129 * 140];
    __shared__ __align__(16) float LpT[PW * 116];   // [k][compact row], 113 used
    __shared__ float L11s[PW * 16];                 // L11s[m*16+k] = L11[k][m], m<k
    __shared__ float invD[129];
    __shared__ float x128s[10];
    int tid = threadIdx.x;
    int lane = tid & 63, wv = tid >> 6;
    for (int e = tid; e < 129 * 129; e += TPB) {
        int i = e / 129, j = e % 129;
        M[i * 140 + j] = G[e] + (i == j ? 1.f : 0.f);
    }
    for (int i = tid; i < 129; i += TPB) M[i * 140 + 129] = 0.f;
    for (int e = tid; e < 1290; e += TPB) {
        int i = e / 10, c = e % 10;
        M[i * 140 + 130 + c] = W0[e] + C[e];
    }
    __syncthreads();

    for (int k0 = 0; k0 < 128; k0 += PW) {
        const int kend = k0 + PW;
        if (wv == 0) {
            bool act = lane < PW;
            int r  = k0 + lane;
            int rc = act ? r : k0;
            float u[PW], Lr[PW];
#pragma unroll
            for (int j = 0; j < PW; ++j) u[j] = M[rc * 140 + k0 + j];
            float dval = u[0];
#pragma unroll
            for (int k = 0; k < PW; ++k) {
                if (lane == k) dval = u[k];
                float piv = rdl(u[k], k);
                float f   = u[k] * __builtin_amdgcn_rcpf(piv);
                float fm  = (act && lane > k) ? f : 0.f;
                Lr[k] = fm;
#pragma unroll
                for (int j = 0; j < PW; ++j)
                    if (j > k) u[j] -= fm * rdl(u[j], k);
            }
            if (act) {
#pragma unroll
                for (int j = 0; j < PW; ++j)
                    if (j >= lane) M[r * 140 + k0 + j] = u[j];   // U11 incl diag
#pragma unroll
                for (int k = 0; k < PW; ++k)
                    if (k < lane) L11s[k * 16 + lane] = Lr[k];   // L11[lane][k]
                invD[r] = __builtin_amdgcn_rcpf(dval);
            }
        }
        __syncthreads();
        if (tid < 128) {
            int cidx = tid;                      // compact off-panel row index
            if (cidx < 113) {
                int r = cidx < k0 ? cidx : cidx + PW;
                float4 a4[4];
#pragma unroll
                for (int q = 0; q < 4; ++q) a4[q] = *(const float4*)&M[r * 140 + k0 + q * 4];
                float a[PW];
#pragma unroll
                for (int q = 0; q < 4; ++q) {
                    a[q * 4 + 0] = a4[q].x; a[q * 4 + 1] = a4[q].y;
                    a[q * 4 + 2] = a4[q].z; a[q * 4 + 3] = a4[q].w;
                }
#pragma unroll
                for (int k = 0; k < PW; ++k)
                    LpT[k * 116 + cidx] = a[k] * invD[k0 + k];
            }
        } else {
            int j = kend + (tid - 128);
            if (j < 140) {
                float yv[PW];
#pragma unroll
                for (int kk = 0; kk < PW; ++kk) {
                    float v = M[(k0 + kk) * 140 + j];
#pragma unroll
                    for (int m = 0; m < PW; ++m)
                        if (m < kk) v -= L11s[m * 16 + kk] * yv[m];
                    yv[kk] = v;
                }
                float xv[PW];
#pragma unroll
                for (int kk = PW - 1; kk >= 0; --kk) {
                    float v = yv[kk];
#pragma unroll
                    for (int m = 0; m < PW; ++m)
                        if (m > kk) v -= M[(k0 + kk) * 140 + k0 + m] * xv[m];
                    M[(k0 + kk) * 140 + j] = v;       // T = D * A11^{-1} * col
                    xv[kk] = v * invD[k0 + kk];
                }
            }
        }
        __syncthreads();
        const int Jn = 140 - kend;
        const int nrt = 29, nct = Jn >> 2;       // 113 rows -> 29 4-row tiles
        for (int t = tid; t < nrt * nct; t += TPB) {
            int tr = t % nrt, tc = t / nrt;
            int c0 = tr * 4;
            int j0 = kend + tc * 4;
            float4 s0 = {0, 0, 0, 0}, s1 = {0, 0, 0, 0}, s2 = {0, 0, 0, 0}, s3 = {0, 0, 0, 0};
#pragma unroll
            for (int kk = 0; kk < PW; ++kk) {
                float4 L4 = *(const float4*)&LpT[kk * 116 + c0];
                float4 U4 = *(const float4*)&M[(k0 + kk) * 140 + j0];
                s0.x += L4.x * U4.x; s0.y += L4.x * U4.y; s0.z += L4.x * U4.z; s0.w += L4.x * U4.w;
                s1.x += L4.y * U4.x; s1.y += L4.y * U4.y; s1.z += L4.y * U4.z; s1.w += L4.y * U4.w;
                s2.x += L4.z * U4.x; s2.y += L4.z * U4.y; s2.z += L4.z * U4.z; s2.w += L4.z * U4.w;
                s3.x += L4.w * U4.x; s3.y += L4.w * U4.y; s3.z += L4.w * U4.z; s3.w += L4.w * U4.w;
            }
            float4 sv[4] = {s0, s1, s2, s3};
#pragma unroll
            for (int i = 0; i < 4; ++i) {
                int cidx = c0 + i;
                if (cidx < 113) {
                    int r = cidx < k0 ? cidx : cidx + PW;
                    float4 mv = *(const float4*)&M[r * 140 + j0];
                    mv.x -= sv[i].x; mv.y -= sv[i].y; mv.z -= sv[i].z; mv.w -= sv[i].w;
                    *(float4*)&M[r * 140 + j0] = mv;
                }
            }
        }
        __syncthreads();
    }
    if (tid == 0) {
        float i128 = __builtin_amdgcn_rcpf(M[128 * 140 + 128]);
#pragma unroll
        for (int c = 0; c < 10; ++c) x128s[c] = M[128 * 140 + 130 + c] * i128;
    }
    __syncthreads();
    if (tid < 128) {
        int r = tid;
        float m128 = M[r * 140 + 128];
        float idr  = invD[r];
#pragma unroll
        for (int c = 0; c < 10; ++c)
            Wnew[r * 10 + c] = (M[r * 140 + 130 + c] - m128 * x128s[c]) * idr;
    } else if (tid == 128) {
#pragma unroll
        for (int c = 0; c < 10; ++c) Wnew[1280 + c] = x128s[c];
    }
}

// k11: out = Phi @ Wnew  ([4096][10]).
// r27: 160x256 -> 320x128 (0.625 -> 1.25 blocks/CU; 96 CUs were idle).
// Same thread count, spread over all CUs; Wl load redundancy 2x (1.3KB/block).
__global__ __launch_bounds__(128) void k11_out(const float* __restrict__ Phi,
                                               const float* __restrict__ Wnew,
                                               float* __restrict__ out) {
    __shared__ float Wl[1290];
    int tid = threadIdx.x;
    for (int i = tid; i < 1290; i += 128) Wl[i] = Wnew[i];
    __syncthreads();
    int idx = blockIdx.x * 128 + tid;
    int n = idx / 10, j = idx % 10;
    float s = 0.f;
    for (int d = 0; d < 129; ++d) s += Phi[n * 129 + d] * Wl[d * 10 + j];
    out[idx] = s;
}

extern "C" void kernel_launch(void* const* d_in, const int* in_sizes, int n_in,
                              void* d_out, int out_size, void* d_ws, size_t ws_size,
                              hipStream_t stream) {
    const float* x   = (const float*)d_in[0];
    const float* y   = (const float*)d_in[1];
    const float* w1  = (const float*)d_in[2];
    const float* g1  = (const float*)d_in[4];
    const float* be1 = (const float*)d_in[5];
    const float* w2  = (const float*)d_in[6];
    const float* b2  = (const float*)d_in[7];
    const float* g2  = (const float*)d_in[8];
    const float* be2 = (const float*)d_in[9];
    const float* fw  = (const float*)d_in[10];
    const float* fb  = (const float*)d_in[11];
    const float* W0  = (const float*)d_in[12];
    float* out = (float*)d_out;
    float* ws  = (float*)d_ws;
    if (ws_size < WS_TOTAL * 4ull) return;

    unsigned* wAg_u = (unsigned*)(ws + WS_WAG);
    unsigned* fwp_u = (unsigned*)(ws + WS_FWP);
    const unsigned short* wAg_h = (const unsigned short*)wAg_u;
    const unsigned short* fwp_h = (const unsigned short*)fwp_u;
    float* sc1     = ws + WS_SC1;
    float* sh1     = ws + WS_SH1;
    float* sck     = ws + WS_SCK;
    float* shk     = ws + WS_SHK;
    float* G       = ws + WS_G;
    float* C       = ws + WS_C;
    float* Wnew    = ws + WS_WNEW;
    float* qpart   = ws + WS_BN1PART;
    float* bn2part = ws + WS_BN2PART;
    float* Phi     = ws + WS_PHI;
    float* fpartA  = ws + WS_FPART;
    float* fpartB  = ws + WS_FPART2;
    float* Gpart   = ws + WS_GPART;
    float* Cpart   = ws + WS_CPART;
    float* pmax    = ws + WS_PMAX;

    kWk1<<<1332, TPB, 0, stream>>>(w2, fw, x, wAg_u, fwp_u, qpart);
    k2_bn1_final<<<1, TPB, 0, stream>>>(qpart, w1, g1, be1, sc1, sh1);
    k34_conv2_mfma<<<4096, TPB, 0, stream>>>(x, w1, sc1, sh1, wAg_h, b2, pmax, bn2part);
    k5_bn2_final<<<64, TPB, 0, stream>>>(bn2part, g2, be2, sck, shk);
    k7_fc1_mfma<<<896, TPB, 0, stream>>>(pmax, sck, shk, fwp_h, fpartA, fpartB);
    k7b_relu<<<2048, TPB, 0, stream>>>(fpartA, fpartB, fb, Phi);
    k8_gram<<<256, TPB, 0, stream>>>(Phi, y, Gpart, Cpart);
    k9_reduce<<<561, TPB, 0, stream>>>(Gpart, Cpart, G, C);
    k10_solve<<<1, TPB, 0, stream>>>(G, C, W0, Wnew);
    k11_out<<<320, 128, 0, stream>>>(Phi, Wnew, out);
}